// Round 4
// baseline (24798.512 us; speedup 1.0000x reference)
//
#include <hip/hip_runtime.h>

#define Bb 8
#define Nn 2048
#define Kk 40
#define HS (128*Nn)   // h stride per batch (channel-major [b,128,2048])

// streaming top-K under total order (val desc, idx asc). Keeps exact top_k set.
// Sentinels: (-inf, idx 0) — real candidates always beat them on value; idx 0
// keeps any pathological no-insert case in-bounds (defensive, see round-3 PM).
__device__ __forceinline__ void topk_ins(float val, int idx, float* tv, int* ti,
                                         float& vv, int& vt, int& vp){
  if (val > vv || (val == vv && idx < vt)) {
    tv[vp] = val; ti[vp] = idx;
    float cv = tv[0]; int ct = ti[0]; int cp = 0;
    for (int j = 1; j < Kk; ++j) {
      float t = tv[j];
      if (t < cv || (t == cv && ti[j] > ct)) { cv = t; ct = ti[j]; cp = j; }
    }
    vv = cv; vt = ct; vp = cp;
  }
}

// ---------------- prep ----------------
__global__ __launch_bounds__(256) void k_xx1(const float* __restrict__ x, float* __restrict__ XX){
  int e = blockIdx.x*256 + threadIdx.x;
  if (e >= Bb*Nn) return;
  float p0 = x[e*3+0], p1 = x[e*3+1], p2 = x[e*3+2];
  XX[e] = __fadd_rn(__fadd_rn(__fmul_rn(p0,p0), __fmul_rn(p1,p1)), __fmul_rn(p2,p2));
}

__global__ __launch_bounds__(256) void k_prep_wt(const float* __restrict__ w1, const float* __restrict__ w2,
                                                 const float* __restrict__ w3, const float* __restrict__ w4,
                                                 const float* __restrict__ fw,
                                                 float* __restrict__ W1T, float* __restrict__ W2T,
                                                 float* __restrict__ W3T, float* __restrict__ W4T,
                                                 float* __restrict__ FWT){
  int e = blockIdx.x*256 + threadIdx.x;
  if (e < 384)   { int i=e/64,  c=e%64;  W1T[e] = w1[c*6+i];    return; } e -= 384;
  if (e < 4096)  { int i=e/64,  c=e%64;  W2T[e] = w2[c*64+i];   return; } e -= 4096;
  if (e < 8192)  { int i=e/64,  c=e%64;  W3T[e] = w3[c*128+i];  return; } e -= 8192;
  if (e < 4096)  { int i=e/64,  c=e%64;  W4T[e] = w4[c*64+i];   return; } e -= 4096;
  if (e < 131072){ int i=e/256, o=e%256; FWT[e] = fw[o*512+i];  return; }
}

// ---------------- knn on 3-D points ----------------
__global__ __launch_bounds__(256) void k_knn1(const float* __restrict__ P, const float* __restrict__ XX,
                                              int* __restrict__ IDX){
  int b = blockIdx.x >> 3;
  int n = ((blockIdx.x & 7) << 8) + threadIdx.x;
  const float* Pb = P + b*Nn*3;
  const float* xb = XX + b*Nn;
  float c0 = Pb[n*3+0], c1 = Pb[n*3+1], c2 = Pb[n*3+2];
  float xn = xb[n];
  float tv[Kk]; int ti[Kk];
  for (int j=0;j<Kk;++j){ tv[j]=-__builtin_inff(); ti[j]=0; }
  float vv=-__builtin_inff(); int vt=0; int vp=0;
  for (int m = 0; m < Nn; ++m) {
    float a0 = Pb[m*3+0], a1 = Pb[m*3+1], a2 = Pb[m*3+2];
    float in_ = __fadd_rn(__fadd_rn(__fmul_rn(c0,a0), __fmul_rn(c1,a1)), __fmul_rn(c2,a2));
    float val = __fsub_rn(__fsub_rn(__fmul_rn(2.0f,in_), xn), xb[m]);
    topk_ins(val, m, tv, ti, vv, vt, vp);
  }
  int* op = IDX + (b*Nn+n)*Kk;
  for (int j=0;j<Kk;++j) op[j] = ti[j];
}

// ---------------- edge conv 1+2 + maxpool (bit-exact _rn path) ----------------
__global__ __launch_bounds__(64) void k_ec1(const float* __restrict__ P, const int* __restrict__ IDX,
                                            const float* __restrict__ W1T, const float* __restrict__ W2T,
                                            const float* __restrict__ g1, const float* __restrict__ b1,
                                            const float* __restrict__ g2, const float* __restrict__ b2,
                                            float* __restrict__ X1T){
  int e = blockIdx.x;           // global point row 0..16383
  int b = e >> 11;
  int lane = threadIdx.x;
  __shared__ float dC[Kk*4];
  __shared__ __align__(16) float y1L[64*44];
  float c0 = P[e*3+0], c1 = P[e*3+1], c2 = P[e*3+2];
  if (lane < Kk) {
    int idx = IDX[e*Kk + lane] & (Nn-1);
    const float* pn = P + (b*Nn + idx)*3;
    dC[lane*4+0] = __fsub_rn(pn[0], c0);
    dC[lane*4+1] = __fsub_rn(pn[1], c1);
    dC[lane*4+2] = __fsub_rn(pn[2], c2);
  }
  __syncthreads();
  float w10 = W1T[0*64+lane], w11 = W1T[1*64+lane], w12 = W1T[2*64+lane];
  float w13 = W1T[3*64+lane], w14 = W1T[4*64+lane], w15 = W1T[5*64+lane];
  float p3 = __fmul_rn(w13,c0), p4 = __fmul_rn(w14,c1), p5 = __fmul_rn(w15,c2);
  float s1 = __fdiv_rn(g1[lane], __fsqrt_rn(1.0f + 1e-5f));
  float o1 = b1[lane];
  for (int k=0;k<Kk;++k){
    float t = __fmul_rn(w10, dC[k*4+0]);
    t = __fadd_rn(t, __fmul_rn(w11, dC[k*4+1]));
    t = __fadd_rn(t, __fmul_rn(w12, dC[k*4+2]));
    t = __fadd_rn(t, p3); t = __fadd_rn(t, p4); t = __fadd_rn(t, p5);
    float y = __fadd_rn(__fmul_rn(t, s1), o1);
    y = (y >= 0.0f) ? y : __fmul_rn(0.2f, y);
    y1L[lane*44+k] = y;
  }
  __syncthreads();
  float4 q[10];
  #pragma unroll
  for (int k4=0;k4<10;++k4) q[k4] = make_float4(0.f,0.f,0.f,0.f);
  for (int i=0;i<64;++i){
    float w = W2T[i*64+lane];
    const float4* yp = (const float4*)&y1L[i*44];
    #pragma unroll
    for (int k4=0;k4<10;++k4){
      float4 yv = yp[k4];
      q[k4].x = __fadd_rn(q[k4].x, __fmul_rn(w, yv.x));
      q[k4].y = __fadd_rn(q[k4].y, __fmul_rn(w, yv.y));
      q[k4].z = __fadd_rn(q[k4].z, __fmul_rn(w, yv.z));
      q[k4].w = __fadd_rn(q[k4].w, __fmul_rn(w, yv.w));
    }
  }
  float s2 = __fdiv_rn(g2[lane], __fsqrt_rn(1.0f + 1e-5f));
  float o2 = b2[lane];
  float mx = -__builtin_inff();
  #pragma unroll
  for (int k4=0;k4<10;++k4){
    float vs[4] = {q[k4].x, q[k4].y, q[k4].z, q[k4].w};
    #pragma unroll
    for (int j=0;j<4;++j){
      float y = __fadd_rn(__fmul_rn(vs[j], s2), o2);
      y = (y >= 0.0f) ? y : __fmul_rn(0.2f, y);
      mx = fmaxf(mx, y);
    }
  }
  X1T[e*64 + lane] = mx;
}

__global__ __launch_bounds__(256) void k_xx2(const float* __restrict__ X1T, float* __restrict__ XX2){
  int e = blockIdx.x*256 + threadIdx.x;
  const float* r = X1T + e*64;
  float a = 0.f;
  for (int c=0;c<64;++c) a = __fadd_rn(a, __fmul_rn(r[c], r[c]));
  XX2[e] = a;
}

// ---------------- knn on 64-D features (full scan) ----------------
__global__ __launch_bounds__(256) void k_knn2(const float* __restrict__ X1T, const float* __restrict__ XX2,
                                              int* __restrict__ IDX){
  int b = blockIdx.x >> 3;
  int n = ((blockIdx.x & 7) << 8) + threadIdx.x;
  const float* Xb = X1T + b*Nn*64;
  const float* xb = XX2 + b*Nn;
  float4 ow[16];
  { const float4* rp = (const float4*)(Xb + n*64);
    #pragma unroll
    for (int c4=0;c4<16;++c4) ow[c4] = rp[c4]; }
  float xn = xb[n];
  float tv[Kk]; int ti[Kk];
  for (int j=0;j<Kk;++j){ tv[j]=-__builtin_inff(); ti[j]=0; }
  float vv=-__builtin_inff(); int vt=0; int vp=0;
  for (int m = 0; m < Nn; m += 2) {
    const float4* r0 = (const float4*)(Xb + m*64);
    const float4* r1 = (const float4*)(Xb + (m+1)*64);
    float a0=0.f, a1=0.f;
    #pragma unroll
    for (int c4=0;c4<16;++c4){
      float4 o = ow[c4]; float4 v0 = r0[c4]; float4 v1 = r1[c4];
      a0 = __fadd_rn(a0, __fmul_rn(o.x, v0.x)); a1 = __fadd_rn(a1, __fmul_rn(o.x, v1.x));
      a0 = __fadd_rn(a0, __fmul_rn(o.y, v0.y)); a1 = __fadd_rn(a1, __fmul_rn(o.y, v1.y));
      a0 = __fadd_rn(a0, __fmul_rn(o.z, v0.z)); a1 = __fadd_rn(a1, __fmul_rn(o.z, v1.z));
      a0 = __fadd_rn(a0, __fmul_rn(o.w, v0.w)); a1 = __fadd_rn(a1, __fmul_rn(o.w, v1.w));
    }
    float val0 = __fsub_rn(__fsub_rn(__fmul_rn(2.0f,a0), xn), xb[m]);
    float val1 = __fsub_rn(__fsub_rn(__fmul_rn(2.0f,a1), xn), xb[m+1]);
    topk_ins(val0, m,   tv, ti, vv, vt, vp);
    topk_ins(val1, m+1, tv, ti, vv, vt, vp);
  }
  int* op = IDX + (b*Nn+n)*Kk;
  for (int j=0;j<Kk;++j) op[j] = ti[j];
}

// ---------------- edge conv 3+4 + maxpool (fma ok) ----------------
__global__ __launch_bounds__(64) void k_ec2(const float* __restrict__ X1T, const int* __restrict__ IDX,
                                            const float* __restrict__ W3T, const float* __restrict__ W4T,
                                            const float* __restrict__ g3, const float* __restrict__ b3,
                                            const float* __restrict__ g4, const float* __restrict__ b4,
                                            float* __restrict__ X2T){
  int e = blockIdx.x; int b = e >> 11; int lane = threadIdx.x;
  __shared__ __align__(16) float dL[64*44];
  __shared__ float ctrL[64];
  float ctr = X1T[e*64 + lane];
  ctrL[lane] = ctr;
  __syncthreads();
  for (int k=0;k<Kk;++k){
    int idx = IDX[e*Kk + k] & (Nn-1);
    dL[lane*44 + k] = X1T[(b*Nn+idx)*64 + lane] - ctr;
  }
  __syncthreads();
  float base = 0.f;
  for (int i=0;i<64;++i) base = fmaf(W3T[(64+i)*64 + lane], ctrL[i], base);
  float4 q[10];
  #pragma unroll
  for (int k4=0;k4<10;++k4) q[k4] = make_float4(base,base,base,base);
  for (int i=0;i<64;++i){
    float w = W3T[i*64 + lane];
    const float4* dp = (const float4*)&dL[i*44];
    #pragma unroll
    for (int k4=0;k4<10;++k4){
      float4 d = dp[k4];
      q[k4].x = fmaf(w, d.x, q[k4].x);
      q[k4].y = fmaf(w, d.y, q[k4].y);
      q[k4].z = fmaf(w, d.z, q[k4].z);
      q[k4].w = fmaf(w, d.w, q[k4].w);
    }
  }
  float s3 = g3[lane] / sqrtf(1.0f+1e-5f);
  float o3 = b3[lane];
  __syncthreads();
  #pragma unroll
  for (int k4=0;k4<10;++k4){
    float4 y;
    y.x = q[k4].x*s3 + o3; y.x = (y.x>=0.f)?y.x:0.2f*y.x;
    y.y = q[k4].y*s3 + o3; y.y = (y.y>=0.f)?y.y:0.2f*y.y;
    y.z = q[k4].z*s3 + o3; y.z = (y.z>=0.f)?y.z:0.2f*y.z;
    y.w = q[k4].w*s3 + o3; y.w = (y.w>=0.f)?y.w:0.2f*y.w;
    *(float4*)&dL[lane*44 + k4*4] = y;
  }
  __syncthreads();
  float4 p[10];
  #pragma unroll
  for (int k4=0;k4<10;++k4) p[k4] = make_float4(0.f,0.f,0.f,0.f);
  for (int i=0;i<64;++i){
    float w = W4T[i*64 + lane];
    const float4* yp = (const float4*)&dL[i*44];
    #pragma unroll
    for (int k4=0;k4<10;++k4){
      float4 yv = yp[k4];
      p[k4].x = fmaf(w, yv.x, p[k4].x);
      p[k4].y = fmaf(w, yv.y, p[k4].y);
      p[k4].z = fmaf(w, yv.z, p[k4].z);
      p[k4].w = fmaf(w, yv.w, p[k4].w);
    }
  }
  float s4 = g4[lane] / sqrtf(1.0f+1e-5f);
  float o4 = b4[lane];
  float mx = -__builtin_inff();
  #pragma unroll
  for (int k4=0;k4<10;++k4){
    float vs[4] = {p[k4].x, p[k4].y, p[k4].z, p[k4].w};
    #pragma unroll
    for (int j=0;j<4;++j){
      float y = vs[j]*s4 + o4;
      y = (y>=0.f)?y:0.2f*y;
      mx = fmaxf(mx, y);
    }
  }
  X2T[e*64 + lane] = mx;
}

// (b,n,64) -> (b,c,n); dst pre-offset by channel base; dst batch stride = HS
__global__ __launch_bounds__(256) void k_tr(const float* __restrict__ src, float* __restrict__ dst){
  int b = blockIdx.x >> 5; int n0 = (blockIdx.x & 31) << 6;
  __shared__ float t[64*65];
  for (int e=threadIdx.x; e<4096; e+=256){
    int r = e >> 6, c = e & 63;
    t[r*65+c] = src[(b*Nn + n0 + r)*64 + c];
  }
  __syncthreads();
  for (int e=threadIdx.x; e<4096; e+=256){
    int c = e >> 6, r = e & 63;
    dst[b*HS + c*Nn + n0 + r] = t[r*65+c];
  }
}

// ---------------- SA layer ----------------
__global__ __launch_bounds__(256) void k_sa_a(const float* __restrict__ IN,
                                              const float* __restrict__ QKw, const float* __restrict__ Vw,
                                              const float* __restrict__ Vb,
                                              float* __restrict__ QX, float* __restrict__ XV){
  int b = blockIdx.x >> 5; int n0 = (blockIdx.x & 31) << 6;
  int w = threadIdx.x >> 6, lane = threadIdx.x & 63;
  __shared__ float xl[128*64];
  for (int e=threadIdx.x; e<8192; e+=256){
    int c = e >> 6, j = e & 63;
    xl[e] = IN[b*HS + c*Nn + n0 + j];
  }
  __syncthreads();
  for (int jj=0;jj<8;++jj){
    int o = w*8 + jj;
    const float4* wp = (const float4*)(QKw + o*128);
    float a = 0.f;
    #pragma unroll
    for (int c4=0;c4<32;++c4){
      float4 wv = wp[c4];
      a = fmaf(wv.x, xl[(c4*4+0)*64 + lane], a);
      a = fmaf(wv.y, xl[(c4*4+1)*64 + lane], a);
      a = fmaf(wv.z, xl[(c4*4+2)*64 + lane], a);
      a = fmaf(wv.w, xl[(c4*4+3)*64 + lane], a);
    }
    QX[(b*32+o)*Nn + n0 + lane] = a;
  }
  for (int jj=0;jj<32;++jj){
    int o = w*32 + jj;
    const float4* wp = (const float4*)(Vw + o*128);
    float a = 0.f;
    #pragma unroll
    for (int c4=0;c4<32;++c4){
      float4 wv = wp[c4];
      a = fmaf(wv.x, xl[(c4*4+0)*64 + lane], a);
      a = fmaf(wv.y, xl[(c4*4+1)*64 + lane], a);
      a = fmaf(wv.z, xl[(c4*4+2)*64 + lane], a);
      a = fmaf(wv.w, xl[(c4*4+3)*64 + lane], a);
    }
    XV[(b*128+o)*Nn + n0 + lane] = a + Vb[o];
  }
}

__global__ __launch_bounds__(256) void k_sa_b(const float* __restrict__ QX,
                                              float* __restrict__ RMP, float* __restrict__ RSP){
  int blk = blockIdx.x;
  int b = blk >> 5, sub = blk & 31;
  int ncn = sub >> 2, mcn = sub & 3;
  int n = ncn*256 + threadIdx.x;
  float q[32];
  #pragma unroll
  for (int o=0;o<32;++o) q[o] = QX[(b*32+o)*Nn + n];
  __shared__ float qt[32*128];
  float mr = -__builtin_inff(), lr = 0.f;
  int m0 = mcn*512;
  for (int t=0;t<4;++t){
    for (int e=threadIdx.x; e<4096; e+=256){
      int o = e >> 7, mm = e & 127;
      qt[e] = QX[(b*32+o)*Nn + m0 + t*128 + mm];
    }
    __syncthreads();
    for (int mm=0;mm<128;mm+=2){
      float e0=0.f, e1=0.f;
      #pragma unroll
      for (int o=0;o<32;++o){ float qo=q[o]; e0=fmaf(qo, qt[o*128+mm], e0); e1=fmaf(qo, qt[o*128+mm+1], e1); }
      if (e0 > mr){ lr = lr*expf(mr-e0) + 1.f; mr = e0; } else lr += expf(e0-mr);
      if (e1 > mr){ lr = lr*expf(mr-e1) + 1.f; mr = e1; } else lr += expf(e1-mr);
    }
    __syncthreads();
  }
  RMP[(b*Nn+n)*4 + mcn] = mr;
  RSP[(b*Nn+n)*4 + mcn] = lr;
}

__global__ __launch_bounds__(256) void k_sa_b2(const float* __restrict__ RMP, const float* __restrict__ RSP,
                                               float* __restrict__ RMX, float* __restrict__ RSM){
  int e = blockIdx.x*256 + threadIdx.x;
  float m0 = RMP[e*4+0], m1 = RMP[e*4+1], m2 = RMP[e*4+2], m3 = RMP[e*4+3];
  float l0 = RSP[e*4+0], l1 = RSP[e*4+1], l2 = RSP[e*4+2], l3 = RSP[e*4+3];
  float M = fmaxf(fmaxf(m0,m1), fmaxf(m2,m3));
  float l = l0*expf(m0-M) + l1*expf(m1-M) + l2*expf(m2-M) + l3*expf(m3-M);
  RMX[e] = M; RSM[e] = l;
}

#define SM_QM 0
#define SM_QN 2048
#define SM_XV 3072
#define SM_SL 7296
#define SM_MX 9344
#define SM_RL 9376
#define SM_CS 9408
#define SM_DL 0

// In-place: IN and OUT alias the same h buffer (so NOT __restrict__).
// Each block reads/writes only its own m-columns; writes happen after the
// __syncthreads that follows all IN reads.
__global__ __launch_bounds__(256) void k_sa_c(const float* IN,
                                              const float* __restrict__ QX, const float* __restrict__ XV,
                                              const float* __restrict__ RMAX, const float* __restrict__ RSUM,
                                              const float* __restrict__ Tw, const float* __restrict__ Tb,
                                              const float* __restrict__ Gs, const float* __restrict__ Bs,
                                              float* OUT){
  int b = blockIdx.x >> 5; int m0 = (blockIdx.x & 31) << 6;
  int tid = threadIdx.x;
  int tc = tid >> 3, tm8 = tid & 7;
  __shared__ __align__(16) float sm[9472];
  for (int e=tid; e<2048; e+=256){
    int o = e >> 6, mm = e & 63;
    sm[SM_QM + e] = QX[(b*32+o)*Nn + m0 + mm];
  }
  float acc[4][8];
  #pragma unroll
  for (int ci=0;ci<4;++ci){
    #pragma unroll
    for (int mi=0;mi<8;++mi) acc[ci][mi] = 0.f;
  }
  float csr = 0.f;
  for (int it=0; it<64; ++it){
    int nb = it*32;
    __syncthreads();
    for (int e=tid; e<1024; e+=256){ int o=e>>5, nn=e&31; sm[SM_QN+e] = QX[(b*32+o)*Nn + nb + nn]; }
    for (int e=tid; e<4096; e+=256){ int c=e>>5, nn=e&31; sm[SM_XV + c*33 + nn] = XV[(b*128+c)*Nn + nb + nn]; }
    if (tid < 32){ sm[SM_MX+tid] = RMAX[b*Nn + nb + tid]; sm[SM_RL+tid] = 1.0f / RSUM[b*Nn + nb + tid]; }
    __syncthreads();
    for (int e=tid; e<2048; e+=256){
      int nn = e >> 6, mm = e & 63;
      float en = 0.f;
      #pragma unroll
      for (int o=0;o<32;++o) en = fmaf(sm[SM_QN + o*32 + nn], sm[SM_QM + o*64 + mm], en);
      sm[SM_SL + nn*64 + mm] = expf(en - sm[SM_MX+nn]) * sm[SM_RL+nn];
    }
    __syncthreads();
    if (tid < 64){
      #pragma unroll
      for (int nn=0;nn<32;++nn) csr += sm[SM_SL + nn*64 + tid];
    }
    #pragma unroll 4
    for (int nn=0;nn<32;++nn){
      float4 s0 = *(const float4*)&sm[SM_SL + nn*64 + tm8*8];
      float4 s1 = *(const float4*)&sm[SM_SL + nn*64 + tm8*8 + 4];
      #pragma unroll
      for (int ci=0;ci<4;++ci){
        float xv = sm[SM_XV + (tc*4+ci)*33 + nn];
        acc[ci][0] = fmaf(xv, s0.x, acc[ci][0]);
        acc[ci][1] = fmaf(xv, s0.y, acc[ci][1]);
        acc[ci][2] = fmaf(xv, s0.z, acc[ci][2]);
        acc[ci][3] = fmaf(xv, s0.w, acc[ci][3]);
        acc[ci][4] = fmaf(xv, s1.x, acc[ci][4]);
        acc[ci][5] = fmaf(xv, s1.y, acc[ci][5]);
        acc[ci][6] = fmaf(xv, s1.z, acc[ci][6]);
        acc[ci][7] = fmaf(xv, s1.w, acc[ci][7]);
      }
    }
  }
  __syncthreads();
  if (tid < 64) sm[SM_CS + tid] = csr;
  __syncthreads();
  #pragma unroll
  for (int ci=0;ci<4;++ci){
    int c = tc*4 + ci;
    #pragma unroll
    for (int mi=0;mi<8;++mi){
      int ml = tm8*8 + mi;
      float cs = sm[SM_CS + ml];
      float xr = acc[ci][mi] / (1e-9f + cs);
      float dv = IN[b*HS + c*Nn + m0 + ml] - xr;
      sm[SM_DL + c*64 + ml] = dv;
    }
  }
  __syncthreads();
  int w = tid >> 6, lane = tid & 63;
  float sroot = sqrtf(1.0f + 1e-5f);
  for (int jj=0;jj<32;++jj){
    int o = w*32 + jj;
    const float4* tw = (const float4*)(Tw + o*128);
    float a = 0.f;
    #pragma unroll
    for (int c4=0;c4<32;++c4){
      float4 wv = tw[c4];
      a = fmaf(wv.x, sm[SM_DL + (c4*4+0)*64 + lane], a);
      a = fmaf(wv.y, sm[SM_DL + (c4*4+1)*64 + lane], a);
      a = fmaf(wv.z, sm[SM_DL + (c4*4+2)*64 + lane], a);
      a = fmaf(wv.w, sm[SM_DL + (c4*4+3)*64 + lane], a);
    }
    a += Tb[o];
    float y = a * (Gs[o] / sroot) + Bs[o];
    y = fmaxf(y, 0.f);
    OUT[b*HS + o*Nn + m0 + lane] = IN[b*HS + o*Nn + m0 + lane] + y;
  }
}

// ---------------- progressive fuse: ACC += FW[:, l*128:(l+1)*128] * h_l ----------------
// ACC = d_out as fp32 [b,256,2048]; wave w computes out-channels [w*64,(w+1)*64).
__global__ __launch_bounds__(256) void k_fuse_part(const float* __restrict__ Hc, const float* __restrict__ FWT,
                                                   float* __restrict__ ACC, int l, int init){
  int b = blockIdx.x >> 5; int n0 = (blockIdx.x & 31) << 6;
  int w = threadIdx.x >> 6, lane = threadIdx.x & 63;
  __shared__ float xt[128*64];
  for (int e=threadIdx.x; e<8192; e+=256){
    int c = e >> 6, j = e & 63;
    xt[e] = Hc[(b*128 + c)*Nn + n0 + j];
  }
  __syncthreads();
  float4 a[16];
  #pragma unroll
  for (int j=0;j<16;++j) a[j] = make_float4(0.f,0.f,0.f,0.f);
  for (int c=0;c<128;++c){
    float xv = xt[c*64 + lane];
    const float4* wr = (const float4*)(FWT + (l*128+c)*256 + w*64);
    #pragma unroll
    for (int j4=0;j4<16;++j4){
      float4 wv = wr[j4];
      a[j4].x = fmaf(wv.x, xv, a[j4].x);
      a[j4].y = fmaf(wv.y, xv, a[j4].y);
      a[j4].z = fmaf(wv.z, xv, a[j4].z);
      a[j4].w = fmaf(wv.w, xv, a[j4].w);
    }
  }
  #pragma unroll
  for (int j4=0;j4<16;++j4){
    float vs[4] = {a[j4].x, a[j4].y, a[j4].z, a[j4].w};
    #pragma unroll
    for (int qq=0;qq<4;++qq){
      int o = w*64 + j4*4 + qq;
      int idx = (b*256 + o)*Nn + n0 + lane;
      if (init) ACC[idx] = vs[qq];
      else      ACC[idx] = ACC[idx] + vs[qq];
    }
  }
}

// ---------------- final epilogue: in-place BN + leaky-ReLU on d_out ----------------
__global__ __launch_bounds__(256) void k_fin(float* __restrict__ ACC,
                                             const float* __restrict__ FGF, const float* __restrict__ FBF){
  int e = blockIdx.x*256 + threadIdx.x;    // 4,194,304 entries
  int o = (e >> 11) & 255;
  float sroot = sqrtf(1.0f + 1e-5f);
  float y = ACC[e] * (FGF[o] / sroot) + FBF[o];
  y = (y >= 0.f) ? y : 0.2f*y;
  ACC[e] = y;
}

extern "C" void kernel_launch(void* const* d_in, const int* in_sizes, int n_in,
                              void* d_out, int out_size, void* d_ws, size_t ws_size,
                              hipStream_t stream) {
  // ALL inputs are float32 per the reference (setup_inputs uses jnp.float32).
  const float* X   = (const float*)d_in[0];
  const float* w1  = (const float*)d_in[1];
  const float* g1  = (const float*)d_in[2];
  const float* b1  = (const float*)d_in[3];
  const float* w2  = (const float*)d_in[4];
  const float* g2  = (const float*)d_in[5];
  const float* b2_ = (const float*)d_in[6];
  const float* w3  = (const float*)d_in[7];
  const float* g3  = (const float*)d_in[8];
  const float* b3  = (const float*)d_in[9];
  const float* w4  = (const float*)d_in[10];
  const float* g4  = (const float*)d_in[11];
  const float* b4  = (const float*)d_in[12];
  // d_in[13..15] = w5/g5/b5 : unused by reference
  const float* qk  = (const float*)d_in[16];
  const float* sv  = (const float*)d_in[17];
  const float* svb = (const float*)d_in[18];
  const float* st  = (const float*)d_in[19];
  const float* stb = (const float*)d_in[20];
  const float* sg  = (const float*)d_in[21];
  const float* sb  = (const float*)d_in[22];
  const float* fw  = (const float*)d_in[23];
  const float* fg  = (const float*)d_in[24];
  const float* fb  = (const float*)d_in[25];

  float* ws = (float*)d_ws;
  // ---- layout: 5,063,040 floats = 19.3 MiB total ----
  float* H    = ws + 0;          // 2,097,152  residual stream [b,128,2048], in-place all 4 SA layers
  // SA-phase scratch:
  float* QXb  = ws + 2097152;    //   524,288
  float* XVb  = ws + 2621440;    // 2,097,152
  float* RMP  = ws + 4718592;    //    65,536
  float* RSP  = ws + 4784128;    //    65,536
  float* RMX  = ws + 4849664;    //    16,384
  float* RSM  = ws + 4866048;    //    16,384 (end 4,882,432)
  // phase-1 overlay on [2,097,152 .. 4,915,200) — dead before SA phase:
  float* XX   = ws + 2146304;    //    16,384
  int*   IDX  = (int*)(ws + 2162688); // 655,360 ints
  float* X1T  = ws + 2818048;    // 1,048,576
  float* X2T  = ws + 3866624;    // 1,048,576 (end 4,915,200)
  // transposed weights (after phase-1 overlay end):
  float* C0   = ws + 4915200;
  float* W1T = C0 + 0;           //     384
  float* W2T = C0 + 384;         //   4,096
  float* W3T = C0 + 4480;        //   8,192
  float* W4T = C0 + 12672;       //   4,096
  float* FWT = C0 + 16768;       // 131,072 (end C0+147,840 = 5,063,040)
  // d_out (16 MB fp32) is the fuse accumulator until k_fin finishes in-place.
  float* ACC = (float*)d_out;

  k_xx1<<<64,256,0,stream>>>(X, XX);
  k_prep_wt<<<578,256,0,stream>>>(w1,w2,w3,w4,fw, W1T,W2T,W3T,W4T,FWT);
  k_knn1<<<64,256,0,stream>>>(X, XX, IDX);
  k_ec1<<<16384,64,0,stream>>>(X, IDX, W1T, W2T, g1,b1,g2,b2_, X1T);
  k_xx2<<<64,256,0,stream>>>(X1T, XX);
  k_knn2<<<64,256,0,stream>>>(X1T, XX, IDX);
  k_ec2<<<16384,64,0,stream>>>(X1T, IDX, W3T, W4T, g3,b3,g4,b4, X2T);
  k_tr<<<256,256,0,stream>>>(X1T, H);
  k_tr<<<256,256,0,stream>>>(X2T, H + 64*Nn);

  for (int l=0;l<4;++l){
    k_sa_a<<<256,256,0,stream>>>(H, qk + l*4096, sv + l*16384, svb + l*128, QXb, XVb);
    k_sa_b<<<256,256,0,stream>>>(QXb, RMP, RSP);
    k_sa_b2<<<64,256,0,stream>>>(RMP, RSP, RMX, RSM);
    k_sa_c<<<256,256,0,stream>>>(H, QXb, XVb, RMX, RSM,
                                 st + l*16384, stb + l*128, sg + l*128, sb + l*128, H);
    k_fuse_part<<<256,256,0,stream>>>(H, FWT, ACC, l, (l==0)?1:0);
  }
  k_fin<<<16384,256,0,stream>>>(ACC, fg, fb);
}

// Round 5
// 6865.321 us; speedup vs baseline: 3.6121x; 3.6121x over previous
//
#include <hip/hip_runtime.h>

#define Bb 8
#define Nn 2048
#define Kk 40
#define HS (128*Nn)   // h stride per batch (channel-major [b,128,2048])

// monotone float->uint transform: a > b  <=>  f2o(a) > f2o(b)
__device__ __forceinline__ unsigned f2o(float f){
  unsigned u = __float_as_uint(f);
  return (u & 0x80000000u) ? ~u : (u | 0x80000000u);
}

// Wave-cooperative exact top-40 of 2048 candidates. Lane owns m = j*64+lane,
// distances in d[0..31] (registers, statically indexed only). Emits indices in
// jax.lax.top_k total order (value desc, index asc). ~40*(32 cmp + 6 shfl).
__device__ __forceinline__ void wave_top40(float* d, int lane, int* op){
  float bv = d[0]; int bj = 0;
  #pragma unroll
  for (int j=1;j<32;++j){ if (d[j] > bv){ bv = d[j]; bj = j; } }
  for (int t=0; t<Kk; ++t){
    int bm = bj*64 + lane;
    unsigned long long key = ((unsigned long long)f2o(bv) << 32) | (unsigned)(~bm);
    #pragma unroll
    for (int s=32;s>0;s>>=1){
      unsigned long long o = __shfl_xor(key, s, 64);
      if (o > key) key = o;
    }
    int wm = (int)(~(unsigned)key);     // winning m, known to all lanes
    if (lane == 0) op[t] = wm;
    // remove winner (static-index compare, no reg-array dynamic indexing) + rescan
    bool mine = ((wm & 63) == lane);
    int wj = wm >> 6;
    bv = -__builtin_inff(); bj = 0;
    #pragma unroll
    for (int j=0;j<32;++j){
      float v = d[j];
      if (mine && j == wj) v = -__builtin_inff();
      d[j] = v;
      if (v > bv){ bv = v; bj = j; }
    }
  }
}

// ---------------- prep ----------------
__global__ __launch_bounds__(256) void k_xx1(const float* __restrict__ x, float* __restrict__ XX){
  int e = blockIdx.x*256 + threadIdx.x;
  if (e >= Bb*Nn) return;
  float p0 = x[e*3+0], p1 = x[e*3+1], p2 = x[e*3+2];
  XX[e] = __fadd_rn(__fadd_rn(__fmul_rn(p0,p0), __fmul_rn(p1,p1)), __fmul_rn(p2,p2));
}

__global__ __launch_bounds__(256) void k_prep_wt(const float* __restrict__ w1, const float* __restrict__ w2,
                                                 const float* __restrict__ w3, const float* __restrict__ w4,
                                                 const float* __restrict__ fw,
                                                 float* __restrict__ W1T, float* __restrict__ W2T,
                                                 float* __restrict__ W3T, float* __restrict__ W4T,
                                                 float* __restrict__ FWT){
  int e = blockIdx.x*256 + threadIdx.x;
  if (e < 384)   { int i=e/64,  c=e%64;  W1T[e] = w1[c*6+i];    return; } e -= 384;
  if (e < 4096)  { int i=e/64,  c=e%64;  W2T[e] = w2[c*64+i];   return; } e -= 4096;
  if (e < 8192)  { int i=e/64,  c=e%64;  W3T[e] = w3[c*128+i];  return; } e -= 8192;
  if (e < 4096)  { int i=e/64,  c=e%64;  W4T[e] = w4[c*64+i];   return; } e -= 4096;
  if (e < 131072){ int i=e/256, o=e%256; FWT[e] = fw[o*512+i];  return; }
}

// ---------------- knn on 3-D points: 1 wave / query ----------------
// grid 4096: b = blk>>9, query n = (blk&511)*4 + wave. LDS-staged point cloud.
__global__ __launch_bounds__(256) void k_knn1(const float* __restrict__ P, const float* __restrict__ XX,
                                              int* __restrict__ IDX){
  int blk = blockIdx.x;
  int b = blk >> 9;
  int w = threadIdx.x >> 6, lane = threadIdx.x & 63;
  int n = (blk & 511)*4 + w;
  const float* Pb = P + b*Nn*3;
  const float* xb = XX + b*Nn;
  __shared__ float Pl[Nn*3];
  __shared__ float Xl[Nn];
  for (int e = threadIdx.x; e < Nn*3; e += 256) Pl[e] = Pb[e];
  for (int e = threadIdx.x; e < Nn; e += 256) Xl[e] = xb[e];
  __syncthreads();
  float c0 = Pl[n*3+0], c1 = Pl[n*3+1], c2 = Pl[n*3+2];
  float xn = Xl[n];
  float d[32];
  #pragma unroll
  for (int j=0;j<32;++j){
    int m = j*64 + lane;
    float a0 = Pl[m*3+0], a1 = Pl[m*3+1], a2 = Pl[m*3+2];
    float in_ = __fadd_rn(__fadd_rn(__fmul_rn(c0,a0), __fmul_rn(c1,a1)), __fmul_rn(c2,a2));
    d[j] = __fsub_rn(__fsub_rn(__fmul_rn(2.0f,in_), xn), Xl[m]);
  }
  wave_top40(d, lane, IDX + (b*Nn+n)*Kk);
}

// ---------------- edge conv 1+2 + maxpool (bit-exact _rn path) ----------------
__global__ __launch_bounds__(64) void k_ec1(const float* __restrict__ P, const int* __restrict__ IDX,
                                            const float* __restrict__ W1T, const float* __restrict__ W2T,
                                            const float* __restrict__ g1, const float* __restrict__ b1,
                                            const float* __restrict__ g2, const float* __restrict__ b2,
                                            float* __restrict__ X1T){
  int e = blockIdx.x;           // global point row 0..16383
  int b = e >> 11;
  int lane = threadIdx.x;
  __shared__ float dC[Kk*4];
  __shared__ __align__(16) float y1L[64*44];
  float c0 = P[e*3+0], c1 = P[e*3+1], c2 = P[e*3+2];
  if (lane < Kk) {
    int idx = IDX[e*Kk + lane] & (Nn-1);
    const float* pn = P + (b*Nn + idx)*3;
    dC[lane*4+0] = __fsub_rn(pn[0], c0);
    dC[lane*4+1] = __fsub_rn(pn[1], c1);
    dC[lane*4+2] = __fsub_rn(pn[2], c2);
  }
  __syncthreads();
  float w10 = W1T[0*64+lane], w11 = W1T[1*64+lane], w12 = W1T[2*64+lane];
  float w13 = W1T[3*64+lane], w14 = W1T[4*64+lane], w15 = W1T[5*64+lane];
  float p3 = __fmul_rn(w13,c0), p4 = __fmul_rn(w14,c1), p5 = __fmul_rn(w15,c2);
  float s1 = __fdiv_rn(g1[lane], __fsqrt_rn(1.0f + 1e-5f));
  float o1 = b1[lane];
  for (int k=0;k<Kk;++k){
    float t = __fmul_rn(w10, dC[k*4+0]);
    t = __fadd_rn(t, __fmul_rn(w11, dC[k*4+1]));
    t = __fadd_rn(t, __fmul_rn(w12, dC[k*4+2]));
    t = __fadd_rn(t, p3); t = __fadd_rn(t, p4); t = __fadd_rn(t, p5);
    float y = __fadd_rn(__fmul_rn(t, s1), o1);
    y = (y >= 0.0f) ? y : __fmul_rn(0.2f, y);
    y1L[lane*44+k] = y;
  }
  __syncthreads();
  float4 q[10];
  #pragma unroll
  for (int k4=0;k4<10;++k4) q[k4] = make_float4(0.f,0.f,0.f,0.f);
  for (int i=0;i<64;++i){
    float w = W2T[i*64+lane];
    const float4* yp = (const float4*)&y1L[i*44];
    #pragma unroll
    for (int k4=0;k4<10;++k4){
      float4 yv = yp[k4];
      q[k4].x = __fadd_rn(q[k4].x, __fmul_rn(w, yv.x));
      q[k4].y = __fadd_rn(q[k4].y, __fmul_rn(w, yv.y));
      q[k4].z = __fadd_rn(q[k4].z, __fmul_rn(w, yv.z));
      q[k4].w = __fadd_rn(q[k4].w, __fmul_rn(w, yv.w));
    }
  }
  float s2 = __fdiv_rn(g2[lane], __fsqrt_rn(1.0f + 1e-5f));
  float o2 = b2[lane];
  float mx = -__builtin_inff();
  #pragma unroll
  for (int k4=0;k4<10;++k4){
    float vs[4] = {q[k4].x, q[k4].y, q[k4].z, q[k4].w};
    #pragma unroll
    for (int j=0;j<4;++j){
      float y = __fadd_rn(__fmul_rn(vs[j], s2), o2);
      y = (y >= 0.0f) ? y : __fmul_rn(0.2f, y);
      mx = fmaxf(mx, y);
    }
  }
  X1T[e*64 + lane] = mx;
}

__global__ __launch_bounds__(256) void k_xx2(const float* __restrict__ X1T, float* __restrict__ XX2){
  int e = blockIdx.x*256 + threadIdx.x;
  const float* r = X1T + e*64;
  float a = 0.f;
  for (int c=0;c<64;++c) a = __fadd_rn(a, __fmul_rn(r[c], r[c]));
  XX2[e] = a;
}

// ---------------- knn on 64-D features: 1 wave / query ----------------
__global__ __launch_bounds__(256) void k_knn2(const float* __restrict__ X1T, const float* __restrict__ XX2,
                                              int* __restrict__ IDX){
  int blk = blockIdx.x;
  int b = blk >> 9;
  int w = threadIdx.x >> 6, lane = threadIdx.x & 63;
  int n = (blk & 511)*4 + w;
  const float* Xb = X1T + b*Nn*64;
  const float* xb = XX2 + b*Nn;
  float4 q[16];
  { const float4* qp = (const float4*)(Xb + n*64);
    #pragma unroll
    for (int c4=0;c4<16;++c4) q[c4] = qp[c4]; }
  float xn = xb[n];
  float d[32];
  #pragma unroll
  for (int j=0;j<32;++j){
    int m = j*64 + lane;
    const float4* rp = (const float4*)(Xb + m*64);
    float a = 0.f;
    #pragma unroll
    for (int c4=0;c4<16;++c4){
      float4 v = rp[c4];
      a = __fadd_rn(a, __fmul_rn(q[c4].x, v.x));
      a = __fadd_rn(a, __fmul_rn(q[c4].y, v.y));
      a = __fadd_rn(a, __fmul_rn(q[c4].z, v.z));
      a = __fadd_rn(a, __fmul_rn(q[c4].w, v.w));
    }
    d[j] = __fsub_rn(__fsub_rn(__fmul_rn(2.0f,a), xn), xb[m]);
  }
  wave_top40(d, lane, IDX + (b*Nn+n)*Kk);
}

// ---------------- edge conv 3+4 + maxpool (fma ok) ----------------
__global__ __launch_bounds__(64) void k_ec2(const float* __restrict__ X1T, const int* __restrict__ IDX,
                                            const float* __restrict__ W3T, const float* __restrict__ W4T,
                                            const float* __restrict__ g3, const float* __restrict__ b3,
                                            const float* __restrict__ g4, const float* __restrict__ b4,
                                            float* __restrict__ X2T){
  int e = blockIdx.x; int b = e >> 11; int lane = threadIdx.x;
  __shared__ __align__(16) float dL[64*44];
  __shared__ float ctrL[64];
  float ctr = X1T[e*64 + lane];
  ctrL[lane] = ctr;
  __syncthreads();
  for (int k=0;k<Kk;++k){
    int idx = IDX[e*Kk + k] & (Nn-1);
    dL[lane*44 + k] = X1T[(b*Nn+idx)*64 + lane] - ctr;
  }
  __syncthreads();
  float base = 0.f;
  for (int i=0;i<64;++i) base = fmaf(W3T[(64+i)*64 + lane], ctrL[i], base);
  float4 q[10];
  #pragma unroll
  for (int k4=0;k4<10;++k4) q[k4] = make_float4(base,base,base,base);
  for (int i=0;i<64;++i){
    float w = W3T[i*64 + lane];
    const float4* dp = (const float4*)&dL[i*44];
    #pragma unroll
    for (int k4=0;k4<10;++k4){
      float4 d = dp[k4];
      q[k4].x = fmaf(w, d.x, q[k4].x);
      q[k4].y = fmaf(w, d.y, q[k4].y);
      q[k4].z = fmaf(w, d.z, q[k4].z);
      q[k4].w = fmaf(w, d.w, q[k4].w);
    }
  }
  float s3 = g3[lane] / sqrtf(1.0f+1e-5f);
  float o3 = b3[lane];
  __syncthreads();
  #pragma unroll
  for (int k4=0;k4<10;++k4){
    float4 y;
    y.x = q[k4].x*s3 + o3; y.x = (y.x>=0.f)?y.x:0.2f*y.x;
    y.y = q[k4].y*s3 + o3; y.y = (y.y>=0.f)?y.y:0.2f*y.y;
    y.z = q[k4].z*s3 + o3; y.z = (y.z>=0.f)?y.z:0.2f*y.z;
    y.w = q[k4].w*s3 + o3; y.w = (y.w>=0.f)?y.w:0.2f*y.w;
    *(float4*)&dL[lane*44 + k4*4] = y;
  }
  __syncthreads();
  float4 p[10];
  #pragma unroll
  for (int k4=0;k4<10;++k4) p[k4] = make_float4(0.f,0.f,0.f,0.f);
  for (int i=0;i<64;++i){
    float w = W4T[i*64 + lane];
    const float4* yp = (const float4*)&dL[i*44];
    #pragma unroll
    for (int k4=0;k4<10;++k4){
      float4 yv = yp[k4];
      p[k4].x = fmaf(w, yv.x, p[k4].x);
      p[k4].y = fmaf(w, yv.y, p[k4].y);
      p[k4].z = fmaf(w, yv.z, p[k4].z);
      p[k4].w = fmaf(w, yv.w, p[k4].w);
    }
  }
  float s4 = g4[lane] / sqrtf(1.0f+1e-5f);
  float o4 = b4[lane];
  float mx = -__builtin_inff();
  #pragma unroll
  for (int k4=0;k4<10;++k4){
    float vs[4] = {p[k4].x, p[k4].y, p[k4].z, p[k4].w};
    #pragma unroll
    for (int j=0;j<4;++j){
      float y = vs[j]*s4 + o4;
      y = (y>=0.f)?y:0.2f*y;
      mx = fmaxf(mx, y);
    }
  }
  X2T[e*64 + lane] = mx;
}

// (b,n,64) -> (b,c,n); dst pre-offset by channel base; dst batch stride = HS
__global__ __launch_bounds__(256) void k_tr(const float* __restrict__ src, float* __restrict__ dst){
  int b = blockIdx.x >> 5; int n0 = (blockIdx.x & 31) << 6;
  __shared__ float t[64*65];
  for (int e=threadIdx.x; e<4096; e+=256){
    int r = e >> 6, c = e & 63;
    t[r*65+c] = src[(b*Nn + n0 + r)*64 + c];
  }
  __syncthreads();
  for (int e=threadIdx.x; e<4096; e+=256){
    int c = e >> 6, r = e & 63;
    dst[b*HS + c*Nn + n0 + r] = t[r*65+c];
  }
}

// ---------------- SA layer ----------------
__global__ __launch_bounds__(256) void k_sa_a(const float* __restrict__ IN,
                                              const float* __restrict__ QKw, const float* __restrict__ Vw,
                                              const float* __restrict__ Vb,
                                              float* __restrict__ QX, float* __restrict__ XV){
  int b = blockIdx.x >> 5; int n0 = (blockIdx.x & 31) << 6;
  int w = threadIdx.x >> 6, lane = threadIdx.x & 63;
  __shared__ float xl[128*64];
  for (int e=threadIdx.x; e<8192; e+=256){
    int c = e >> 6, j = e & 63;
    xl[e] = IN[b*HS + c*Nn + n0 + j];
  }
  __syncthreads();
  for (int jj=0;jj<8;++jj){
    int o = w*8 + jj;
    const float4* wp = (const float4*)(QKw + o*128);
    float a = 0.f;
    #pragma unroll
    for (int c4=0;c4<32;++c4){
      float4 wv = wp[c4];
      a = fmaf(wv.x, xl[(c4*4+0)*64 + lane], a);
      a = fmaf(wv.y, xl[(c4*4+1)*64 + lane], a);
      a = fmaf(wv.z, xl[(c4*4+2)*64 + lane], a);
      a = fmaf(wv.w, xl[(c4*4+3)*64 + lane], a);
    }
    QX[(b*32+o)*Nn + n0 + lane] = a;
  }
  for (int jj=0;jj<32;++jj){
    int o = w*32 + jj;
    const float4* wp = (const float4*)(Vw + o*128);
    float a = 0.f;
    #pragma unroll
    for (int c4=0;c4<32;++c4){
      float4 wv = wp[c4];
      a = fmaf(wv.x, xl[(c4*4+0)*64 + lane], a);
      a = fmaf(wv.y, xl[(c4*4+1)*64 + lane], a);
      a = fmaf(wv.z, xl[(c4*4+2)*64 + lane], a);
      a = fmaf(wv.w, xl[(c4*4+3)*64 + lane], a);
    }
    XV[(b*128+o)*Nn + n0 + lane] = a + Vb[o];
  }
}

__global__ __launch_bounds__(256) void k_sa_b(const float* __restrict__ QX,
                                              float* __restrict__ RMP, float* __restrict__ RSP){
  int blk = blockIdx.x;
  int b = blk >> 5, sub = blk & 31;
  int ncn = sub >> 2, mcn = sub & 3;
  int n = ncn*256 + threadIdx.x;
  float q[32];
  #pragma unroll
  for (int o=0;o<32;++o) q[o] = QX[(b*32+o)*Nn + n];
  __shared__ float qt[32*128];
  float mr = -__builtin_inff(), lr = 0.f;
  int m0 = mcn*512;
  for (int t=0;t<4;++t){
    for (int e=threadIdx.x; e<4096; e+=256){
      int o = e >> 7, mm = e & 127;
      qt[e] = QX[(b*32+o)*Nn + m0 + t*128 + mm];
    }
    __syncthreads();
    for (int mm=0;mm<128;mm+=2){
      float e0=0.f, e1=0.f;
      #pragma unroll
      for (int o=0;o<32;++o){ float qo=q[o]; e0=fmaf(qo, qt[o*128+mm], e0); e1=fmaf(qo, qt[o*128+mm+1], e1); }
      if (e0 > mr){ lr = lr*expf(mr-e0) + 1.f; mr = e0; } else lr += expf(e0-mr);
      if (e1 > mr){ lr = lr*expf(mr-e1) + 1.f; mr = e1; } else lr += expf(e1-mr);
    }
    __syncthreads();
  }
  RMP[(b*Nn+n)*4 + mcn] = mr;
  RSP[(b*Nn+n)*4 + mcn] = lr;
}

__global__ __launch_bounds__(256) void k_sa_b2(const float* __restrict__ RMP, const float* __restrict__ RSP,
                                               float* __restrict__ RMX, float* __restrict__ RSM){
  int e = blockIdx.x*256 + threadIdx.x;
  float m0 = RMP[e*4+0], m1 = RMP[e*4+1], m2 = RMP[e*4+2], m3 = RMP[e*4+3];
  float l0 = RSP[e*4+0], l1 = RSP[e*4+1], l2 = RSP[e*4+2], l3 = RSP[e*4+3];
  float M = fmaxf(fmaxf(m0,m1), fmaxf(m2,m3));
  float l = l0*expf(m0-M) + l1*expf(m1-M) + l2*expf(m2-M) + l3*expf(m3-M);
  RMX[e] = M; RSM[e] = l;
}

#define SM_QM 0
#define SM_QN 2048
#define SM_XV 3072
#define SM_SL 7296
#define SM_MX 9344
#define SM_RL 9376
#define SM_CS 9408
#define SM_DL 0

// In-place: IN and OUT alias the same h buffer (so NOT __restrict__).
__global__ __launch_bounds__(256) void k_sa_c(const float* IN,
                                              const float* __restrict__ QX, const float* __restrict__ XV,
                                              const float* __restrict__ RMAX, const float* __restrict__ RSUM,
                                              const float* __restrict__ Tw, const float* __restrict__ Tb,
                                              const float* __restrict__ Gs, const float* __restrict__ Bs,
                                              float* OUT){
  int b = blockIdx.x >> 5; int m0 = (blockIdx.x & 31) << 6;
  int tid = threadIdx.x;
  int tc = tid >> 3, tm8 = tid & 7;
  __shared__ __align__(16) float sm[9472];
  for (int e=tid; e<2048; e+=256){
    int o = e >> 6, mm = e & 63;
    sm[SM_QM + e] = QX[(b*32+o)*Nn + m0 + mm];
  }
  float acc[4][8];
  #pragma unroll
  for (int ci=0;ci<4;++ci){
    #pragma unroll
    for (int mi=0;mi<8;++mi) acc[ci][mi] = 0.f;
  }
  float csr = 0.f;
  for (int it=0; it<64; ++it){
    int nb = it*32;
    __syncthreads();
    for (int e=tid; e<1024; e+=256){ int o=e>>5, nn=e&31; sm[SM_QN+e] = QX[(b*32+o)*Nn + nb + nn]; }
    for (int e=tid; e<4096; e+=256){ int c=e>>5, nn=e&31; sm[SM_XV + c*33 + nn] = XV[(b*128+c)*Nn + nb + nn]; }
    if (tid < 32){ sm[SM_MX+tid] = RMAX[b*Nn + nb + tid]; sm[SM_RL+tid] = 1.0f / RSUM[b*Nn + nb + tid]; }
    __syncthreads();
    for (int e=tid; e<2048; e+=256){
      int nn = e >> 6, mm = e & 63;
      float en = 0.f;
      #pragma unroll
      for (int o=0;o<32;++o) en = fmaf(sm[SM_QN + o*32 + nn], sm[SM_QM + o*64 + mm], en);
      sm[SM_SL + nn*64 + mm] = expf(en - sm[SM_MX+nn]) * sm[SM_RL+nn];
    }
    __syncthreads();
    if (tid < 64){
      #pragma unroll
      for (int nn=0;nn<32;++nn) csr += sm[SM_SL + nn*64 + tid];
    }
    #pragma unroll 4
    for (int nn=0;nn<32;++nn){
      float4 s0 = *(const float4*)&sm[SM_SL + nn*64 + tm8*8];
      float4 s1 = *(const float4*)&sm[SM_SL + nn*64 + tm8*8 + 4];
      #pragma unroll
      for (int ci=0;ci<4;++ci){
        float xv = sm[SM_XV + (tc*4+ci)*33 + nn];
        acc[ci][0] = fmaf(xv, s0.x, acc[ci][0]);
        acc[ci][1] = fmaf(xv, s0.y, acc[ci][1]);
        acc[ci][2] = fmaf(xv, s0.z, acc[ci][2]);
        acc[ci][3] = fmaf(xv, s0.w, acc[ci][3]);
        acc[ci][4] = fmaf(xv, s1.x, acc[ci][4]);
        acc[ci][5] = fmaf(xv, s1.y, acc[ci][5]);
        acc[ci][6] = fmaf(xv, s1.z, acc[ci][6]);
        acc[ci][7] = fmaf(xv, s1.w, acc[ci][7]);
      }
    }
  }
  __syncthreads();
  if (tid < 64) sm[SM_CS + tid] = csr;
  __syncthreads();
  #pragma unroll
  for (int ci=0;ci<4;++ci){
    int c = tc*4 + ci;
    #pragma unroll
    for (int mi=0;mi<8;++mi){
      int ml = tm8*8 + mi;
      float cs = sm[SM_CS + ml];
      float xr = acc[ci][mi] / (1e-9f + cs);
      float dv = IN[b*HS + c*Nn + m0 + ml] - xr;
      sm[SM_DL + c*64 + ml] = dv;
    }
  }
  __syncthreads();
  int w = tid >> 6, lane = tid & 63;
  float sroot = sqrtf(1.0f + 1e-5f);
  for (int jj=0;jj<32;++jj){
    int o = w*32 + jj;
    const float4* tw = (const float4*)(Tw + o*128);
    float a = 0.f;
    #pragma unroll
    for (int c4=0;c4<32;++c4){
      float4 wv = tw[c4];
      a = fmaf(wv.x, sm[SM_DL + (c4*4+0)*64 + lane], a);
      a = fmaf(wv.y, sm[SM_DL + (c4*4+1)*64 + lane], a);
      a = fmaf(wv.z, sm[SM_DL + (c4*4+2)*64 + lane], a);
      a = fmaf(wv.w, sm[SM_DL + (c4*4+3)*64 + lane], a);
    }
    a += Tb[o];
    float y = a * (Gs[o] / sroot) + Bs[o];
    y = fmaxf(y, 0.f);
    OUT[b*HS + o*Nn + m0 + lane] = IN[b*HS + o*Nn + m0 + lane] + y;
  }
}

// ---------------- progressive fuse: ACC += FW[:, l*128:(l+1)*128] * h_l ----------------
__global__ __launch_bounds__(256) void k_fuse_part(const float* __restrict__ Hc, const float* __restrict__ FWT,
                                                   float* __restrict__ ACC, int l, int init){
  int b = blockIdx.x >> 5; int n0 = (blockIdx.x & 31) << 6;
  int w = threadIdx.x >> 6, lane = threadIdx.x & 63;
  __shared__ float xt[128*64];
  for (int e=threadIdx.x; e<8192; e+=256){
    int c = e >> 6, j = e & 63;
    xt[e] = Hc[(b*128 + c)*Nn + n0 + j];
  }
  __syncthreads();
  float4 a[16];
  #pragma unroll
  for (int j=0;j<16;++j) a[j] = make_float4(0.f,0.f,0.f,0.f);
  for (int c=0;c<128;++c){
    float xv = xt[c*64 + lane];
    const float4* wr = (const float4*)(FWT + (l*128+c)*256 + w*64);
    #pragma unroll
    for (int j4=0;j4<16;++j4){
      float4 wv = wr[j4];
      a[j4].x = fmaf(wv.x, xv, a[j4].x);
      a[j4].y = fmaf(wv.y, xv, a[j4].y);
      a[j4].z = fmaf(wv.z, xv, a[j4].z);
      a[j4].w = fmaf(wv.w, xv, a[j4].w);
    }
  }
  #pragma unroll
  for (int j4=0;j4<16;++j4){
    float vs[4] = {a[j4].x, a[j4].y, a[j4].z, a[j4].w};
    #pragma unroll
    for (int qq=0;qq<4;++qq){
      int o = w*64 + j4*4 + qq;
      int idx = (b*256 + o)*Nn + n0 + lane;
      if (init) ACC[idx] = vs[qq];
      else      ACC[idx] = ACC[idx] + vs[qq];
    }
  }
}

// ---------------- final epilogue: in-place BN + leaky-ReLU on d_out ----------------
__global__ __launch_bounds__(256) void k_fin(float* __restrict__ ACC,
                                             const float* __restrict__ FGF, const float* __restrict__ FBF){
  int e = blockIdx.x*256 + threadIdx.x;    // 4,194,304 entries
  int o = (e >> 11) & 255;
  float sroot = sqrtf(1.0f + 1e-5f);
  float y = ACC[e] * (FGF[o] / sroot) + FBF[o];
  y = (y >= 0.f) ? y : 0.2f*y;
  ACC[e] = y;
}

extern "C" void kernel_launch(void* const* d_in, const int* in_sizes, int n_in,
                              void* d_out, int out_size, void* d_ws, size_t ws_size,
                              hipStream_t stream) {
  const float* X   = (const float*)d_in[0];
  const float* w1  = (const float*)d_in[1];
  const float* g1  = (const float*)d_in[2];
  const float* b1  = (const float*)d_in[3];
  const float* w2  = (const float*)d_in[4];
  const float* g2  = (const float*)d_in[5];
  const float* b2_ = (const float*)d_in[6];
  const float* w3  = (const float*)d_in[7];
  const float* g3  = (const float*)d_in[8];
  const float* b3  = (const float*)d_in[9];
  const float* w4  = (const float*)d_in[10];
  const float* g4  = (const float*)d_in[11];
  const float* b4  = (const float*)d_in[12];
  // d_in[13..15] = w5/g5/b5 : unused by reference
  const float* qk  = (const float*)d_in[16];
  const float* sv  = (const float*)d_in[17];
  const float* svb = (const float*)d_in[18];
  const float* st  = (const float*)d_in[19];
  const float* stb = (const float*)d_in[20];
  const float* sg  = (const float*)d_in[21];
  const float* sb  = (const float*)d_in[22];
  const float* fw  = (const float*)d_in[23];
  const float* fg  = (const float*)d_in[24];
  const float* fb  = (const float*)d_in[25];

  float* ws = (float*)d_ws;
  float* H    = ws + 0;          // 2,097,152
  float* QXb  = ws + 2097152;    //   524,288
  float* XVb  = ws + 2621440;    // 2,097,152
  float* RMP  = ws + 4718592;    //    65,536
  float* RSP  = ws + 4784128;    //    65,536
  float* RMX  = ws + 4849664;    //    16,384
  float* RSM  = ws + 4866048;    //    16,384
  // phase-1 overlay on [2,097,152 .. 4,915,200) — dead before SA phase:
  float* XX   = ws + 2146304;
  int*   IDX  = (int*)(ws + 2162688);
  float* X1T  = ws + 2818048;
  float* X2T  = ws + 3866624;
  float* C0   = ws + 4915200;
  float* W1T = C0 + 0;
  float* W2T = C0 + 384;
  float* W3T = C0 + 4480;
  float* W4T = C0 + 12672;
  float* FWT = C0 + 16768;       // end C0+147,840 = 5,063,040 floats = 19.3 MiB
  float* ACC = (float*)d_out;

  k_xx1<<<64,256,0,stream>>>(X, XX);
  k_prep_wt<<<578,256,0,stream>>>(w1,w2,w3,w4,fw, W1T,W2T,W3T,W4T,FWT);
  k_knn1<<<4096,256,0,stream>>>(X, XX, IDX);
  k_ec1<<<16384,64,0,stream>>>(X, IDX, W1T, W2T, g1,b1,g2,b2_, X1T);
  k_xx2<<<64,256,0,stream>>>(X1T, XX);
  k_knn2<<<4096,256,0,stream>>>(X1T, XX, IDX);
  k_ec2<<<16384,64,0,stream>>>(X1T, IDX, W3T, W4T, g3,b3,g4,b4, X2T);
  k_tr<<<256,256,0,stream>>>(X1T, H);
  k_tr<<<256,256,0,stream>>>(X2T, H + 64*Nn);

  for (int l=0;l<4;++l){
    k_sa_a<<<256,256,0,stream>>>(H, qk + l*4096, sv + l*16384, svb + l*128, QXb, XVb);
    k_sa_b<<<256,256,0,stream>>>(QXb, RMP, RSP);
    k_sa_b2<<<64,256,0,stream>>>(RMP, RSP, RMX, RSM);
    k_sa_c<<<256,256,0,stream>>>(H, QXb, XVb, RMX, RSM,
                                 st + l*16384, stb + l*128, sg + l*128, sb + l*128, H);
    k_fuse_part<<<256,256,0,stream>>>(H, FWT, ACC, l, (l==0)?1:0);
  }
  k_fin<<<16384,256,0,stream>>>(ACC, fg, fb);
}

// Round 6
// 4773.841 us; speedup vs baseline: 5.1947x; 1.4381x over previous
//
#include <hip/hip_runtime.h>

#define Bb 8
#define Nn 2048
#define Kk 40
#define HS (128*Nn)   // h stride per batch (channel-major [b,128,2048])

// monotone float->uint transform: a > b  <=>  f2o(a) > f2o(b)
__device__ __forceinline__ unsigned f2o(float f){
  unsigned u = __float_as_uint(f);
  return (u & 0x80000000u) ? ~u : (u | 0x80000000u);
}

// Wave-cooperative exact top-40 of 2048. Lane owns m = j*64+lane (d[j]).
// Emits indices in jax.lax.top_k total order (value desc, index asc).
__device__ __forceinline__ void wave_top40(float* d, int lane, int* op){
  float bv = d[0]; int bj = 0;
  #pragma unroll
  for (int j=1;j<32;++j){ if (d[j] > bv){ bv = d[j]; bj = j; } }
  for (int t=0; t<Kk; ++t){
    int bm = bj*64 + lane;
    unsigned long long key = ((unsigned long long)f2o(bv) << 32) | (unsigned)(~bm);
    #pragma unroll
    for (int s=32;s>0;s>>=1){
      unsigned long long o = __shfl_xor(key, s, 64);
      if (o > key) key = o;
    }
    int wm = (int)(~(unsigned)key);
    if (lane == 0) op[t] = wm;
    bool mine = ((wm & 63) == lane);
    int wj = wm >> 6;
    bv = -__builtin_inff(); bj = 0;
    #pragma unroll
    for (int j=0;j<32;++j){
      float v = d[j];
      if (mine && j == wj) v = -__builtin_inff();
      d[j] = v;
      if (v > bv){ bv = v; bj = j; }
    }
  }
}

// Variant for mapping m = (s>>2)*256 + lane*4 + (s&3)  (coalesced float4 ownership).
__device__ __forceinline__ void wave_top40_g(float* d, int lane, int* op){
  float bv = d[0]; int bs = 0;
  #pragma unroll
  for (int s=1;s<32;++s){ if (d[s] > bv){ bv = d[s]; bs = s; } }
  for (int t=0; t<Kk; ++t){
    int bm = ((bs>>2)<<8) + lane*4 + (bs&3);
    unsigned long long key = ((unsigned long long)f2o(bv) << 32) | (unsigned)(~bm);
    #pragma unroll
    for (int s=32;s>0;s>>=1){
      unsigned long long o = __shfl_xor(key, s, 64);
      if (o > key) key = o;
    }
    int wm = (int)(~(unsigned)key);
    if (lane == 0) op[t] = wm;
    bool mine = (((wm>>2) & 63) == lane);
    int wsl = ((wm>>8)<<2) | (wm & 3);
    bv = -__builtin_inff(); bs = 0;
    #pragma unroll
    for (int s=0;s<32;++s){
      float v = d[s];
      if (mine && s == wsl) v = -__builtin_inff();
      d[s] = v;
      if (v > bv){ bv = v; bs = s; }
    }
  }
}

// ---------------- prep ----------------
__global__ __launch_bounds__(256) void k_xx1(const float* __restrict__ x, float* __restrict__ XX){
  int e = blockIdx.x*256 + threadIdx.x;
  if (e >= Bb*Nn) return;
  float p0 = x[e*3+0], p1 = x[e*3+1], p2 = x[e*3+2];
  XX[e] = __fadd_rn(__fadd_rn(__fmul_rn(p0,p0), __fmul_rn(p1,p1)), __fmul_rn(p2,p2));
}

__global__ __launch_bounds__(256) void k_prep_wt(const float* __restrict__ w1, const float* __restrict__ w2,
                                                 const float* __restrict__ w3, const float* __restrict__ w4,
                                                 const float* __restrict__ fw,
                                                 float* __restrict__ W1T, float* __restrict__ W2T,
                                                 float* __restrict__ W3T, float* __restrict__ W4T,
                                                 float* __restrict__ FWT){
  int e = blockIdx.x*256 + threadIdx.x;
  if (e < 384)   { int i=e/64,  c=e%64;  W1T[e] = w1[c*6+i];    return; } e -= 384;
  if (e < 4096)  { int i=e/64,  c=e%64;  W2T[e] = w2[c*64+i];   return; } e -= 4096;
  if (e < 8192)  { int i=e/64,  c=e%64;  W3T[e] = w3[c*128+i];  return; } e -= 8192;
  if (e < 4096)  { int i=e/64,  c=e%64;  W4T[e] = w4[c*64+i];   return; } e -= 4096;
  if (e < 131072){ int i=e/256, o=e%256; FWT[e] = fw[o*512+i];  return; }
}

// ---------------- knn on 3-D points: 1 wave / query, LDS-staged cloud ----------------
__global__ __launch_bounds__(256) void k_knn1(const float* __restrict__ P, const float* __restrict__ XX,
                                              int* __restrict__ IDX){
  int blk = blockIdx.x;
  int b = blk >> 9;
  int w = threadIdx.x >> 6, lane = threadIdx.x & 63;
  int n = (blk & 511)*4 + w;
  const float* Pb = P + b*Nn*3;
  const float* xb = XX + b*Nn;
  __shared__ float Pl[Nn*3];
  __shared__ float Xl[Nn];
  for (int e = threadIdx.x; e < Nn*3; e += 256) Pl[e] = Pb[e];
  for (int e = threadIdx.x; e < Nn; e += 256) Xl[e] = xb[e];
  __syncthreads();
  float c0 = Pl[n*3+0], c1 = Pl[n*3+1], c2 = Pl[n*3+2];
  float xn = Xl[n];
  float d[32];
  #pragma unroll
  for (int j=0;j<32;++j){
    int m = j*64 + lane;
    float a0 = Pl[m*3+0], a1 = Pl[m*3+1], a2 = Pl[m*3+2];
    float in_ = __fadd_rn(__fadd_rn(__fmul_rn(c0,a0), __fmul_rn(c1,a1)), __fmul_rn(c2,a2));
    d[j] = __fsub_rn(__fsub_rn(__fmul_rn(2.0f,in_), xn), Xl[m]);
  }
  wave_top40(d, lane, IDX + (b*Nn+n)*Kk);
}

// ---------------- edge conv 1+2 + maxpool (bit-exact _rn path) ----------------
__global__ __launch_bounds__(64) void k_ec1(const float* __restrict__ P, const int* __restrict__ IDX,
                                            const float* __restrict__ W1T, const float* __restrict__ W2T,
                                            const float* __restrict__ g1, const float* __restrict__ b1,
                                            const float* __restrict__ g2, const float* __restrict__ b2,
                                            float* __restrict__ X1T){
  int e = blockIdx.x;           // global point row 0..16383
  int b = e >> 11;
  int lane = threadIdx.x;
  __shared__ float dC[Kk*4];
  __shared__ __align__(16) float y1L[64*44];
  float c0 = P[e*3+0], c1 = P[e*3+1], c2 = P[e*3+2];
  if (lane < Kk) {
    int idx = IDX[e*Kk + lane] & (Nn-1);
    const float* pn = P + (b*Nn + idx)*3;
    dC[lane*4+0] = __fsub_rn(pn[0], c0);
    dC[lane*4+1] = __fsub_rn(pn[1], c1);
    dC[lane*4+2] = __fsub_rn(pn[2], c2);
  }
  __syncthreads();
  float w10 = W1T[0*64+lane], w11 = W1T[1*64+lane], w12 = W1T[2*64+lane];
  float w13 = W1T[3*64+lane], w14 = W1T[4*64+lane], w15 = W1T[5*64+lane];
  float p3 = __fmul_rn(w13,c0), p4 = __fmul_rn(w14,c1), p5 = __fmul_rn(w15,c2);
  float s1 = __fdiv_rn(g1[lane], __fsqrt_rn(1.0f + 1e-5f));
  float o1 = b1[lane];
  for (int k=0;k<Kk;++k){
    float t = __fmul_rn(w10, dC[k*4+0]);
    t = __fadd_rn(t, __fmul_rn(w11, dC[k*4+1]));
    t = __fadd_rn(t, __fmul_rn(w12, dC[k*4+2]));
    t = __fadd_rn(t, p3); t = __fadd_rn(t, p4); t = __fadd_rn(t, p5);
    float y = __fadd_rn(__fmul_rn(t, s1), o1);
    y = (y >= 0.0f) ? y : __fmul_rn(0.2f, y);
    y1L[lane*44+k] = y;
  }
  __syncthreads();
  float4 q[10];
  #pragma unroll
  for (int k4=0;k4<10;++k4) q[k4] = make_float4(0.f,0.f,0.f,0.f);
  for (int i=0;i<64;++i){
    float w = W2T[i*64+lane];
    const float4* yp = (const float4*)&y1L[i*44];
    #pragma unroll
    for (int k4=0;k4<10;++k4){
      float4 yv = yp[k4];
      q[k4].x = __fadd_rn(q[k4].x, __fmul_rn(w, yv.x));
      q[k4].y = __fadd_rn(q[k4].y, __fmul_rn(w, yv.y));
      q[k4].z = __fadd_rn(q[k4].z, __fmul_rn(w, yv.z));
      q[k4].w = __fadd_rn(q[k4].w, __fmul_rn(w, yv.w));
    }
  }
  float s2 = __fdiv_rn(g2[lane], __fsqrt_rn(1.0f + 1e-5f));
  float o2 = b2[lane];
  float mx = -__builtin_inff();
  #pragma unroll
  for (int k4=0;k4<10;++k4){
    float vs[4] = {q[k4].x, q[k4].y, q[k4].z, q[k4].w};
    #pragma unroll
    for (int j=0;j<4;++j){
      float y = __fadd_rn(__fmul_rn(vs[j], s2), o2);
      y = (y >= 0.0f) ? y : __fmul_rn(0.2f, y);
      mx = fmaxf(mx, y);
    }
  }
  X1T[e*64 + lane] = mx;
}

__global__ __launch_bounds__(256) void k_xx2(const float* __restrict__ X1T, float* __restrict__ XX2){
  int e = blockIdx.x*256 + threadIdx.x;
  const float* r = X1T + e*64;
  float a = 0.f;
  for (int c=0;c<64;++c) a = __fadd_rn(a, __fmul_rn(r[c], r[c]));
  XX2[e] = a;
}

// ---------------- knn on 64-D features: channel-major coalesced reads ----------------
// X1C = H channels 0..63 ([b][c][n], row stride Nn, batch stride HS).
// Lane owns m = j*256 + lane*4 + {0..3}; reads are contiguous 1KB/wave.
__global__ __launch_bounds__(256) void k_knn2(const float* __restrict__ X1C, const float* __restrict__ XX2,
                                              int* __restrict__ IDX){
  int blk = blockIdx.x;
  int b = blk >> 9;
  int w = threadIdx.x >> 6, lane = threadIdx.x & 63;
  int n = (blk & 511)*4 + w;
  __shared__ float qL[4*64];
  { int t = threadIdx.x; int ww = t >> 6, c = t & 63;
    int nn = (blk & 511)*4 + ww;
    qL[t] = X1C[b*HS + c*Nn + nn]; }
  __syncthreads();
  const float* xb = XX2 + b*Nn;
  float4 a4[8];
  #pragma unroll
  for (int j=0;j<8;++j) a4[j] = make_float4(0.f,0.f,0.f,0.f);
  for (int c=0;c<64;++c){
    float qc = qL[w*64 + c];
    const float4* row = (const float4*)(X1C + b*HS + c*Nn);
    #pragma unroll
    for (int j=0;j<8;++j){
      float4 v = row[j*64 + lane];
      a4[j].x = __fadd_rn(a4[j].x, __fmul_rn(qc, v.x));
      a4[j].y = __fadd_rn(a4[j].y, __fmul_rn(qc, v.y));
      a4[j].z = __fadd_rn(a4[j].z, __fmul_rn(qc, v.z));
      a4[j].w = __fadd_rn(a4[j].w, __fmul_rn(qc, v.w));
    }
  }
  float xn = xb[n];
  float d[32];
  #pragma unroll
  for (int j=0;j<8;++j){
    float4 xm = ((const float4*)xb)[j*64 + lane];
    d[j*4+0] = __fsub_rn(__fsub_rn(__fmul_rn(2.0f, a4[j].x), xn), xm.x);
    d[j*4+1] = __fsub_rn(__fsub_rn(__fmul_rn(2.0f, a4[j].y), xn), xm.y);
    d[j*4+2] = __fsub_rn(__fsub_rn(__fmul_rn(2.0f, a4[j].z), xn), xm.z);
    d[j*4+3] = __fsub_rn(__fsub_rn(__fmul_rn(2.0f, a4[j].w), xn), xm.w);
  }
  wave_top40_g(d, lane, IDX + (b*Nn+n)*Kk);
}

// ---------------- edge conv 3+4 + maxpool (fma ok) ----------------
__global__ __launch_bounds__(64) void k_ec2(const float* __restrict__ X1T, const int* __restrict__ IDX,
                                            const float* __restrict__ W3T, const float* __restrict__ W4T,
                                            const float* __restrict__ g3, const float* __restrict__ b3,
                                            const float* __restrict__ g4, const float* __restrict__ b4,
                                            float* __restrict__ X2T){
  int e = blockIdx.x; int b = e >> 11; int lane = threadIdx.x;
  __shared__ __align__(16) float dL[64*44];
  __shared__ float ctrL[64];
  float ctr = X1T[e*64 + lane];
  ctrL[lane] = ctr;
  __syncthreads();
  for (int k=0;k<Kk;++k){
    int idx = IDX[e*Kk + k] & (Nn-1);
    dL[lane*44 + k] = X1T[(b*Nn+idx)*64 + lane] - ctr;
  }
  __syncthreads();
  float base = 0.f;
  for (int i=0;i<64;++i) base = fmaf(W3T[(64+i)*64 + lane], ctrL[i], base);
  float4 q[10];
  #pragma unroll
  for (int k4=0;k4<10;++k4) q[k4] = make_float4(base,base,base,base);
  for (int i=0;i<64;++i){
    float w = W3T[i*64 + lane];
    const float4* dp = (const float4*)&dL[i*44];
    #pragma unroll
    for (int k4=0;k4<10;++k4){
      float4 d = dp[k4];
      q[k4].x = fmaf(w, d.x, q[k4].x);
      q[k4].y = fmaf(w, d.y, q[k4].y);
      q[k4].z = fmaf(w, d.z, q[k4].z);
      q[k4].w = fmaf(w, d.w, q[k4].w);
    }
  }
  float s3 = g3[lane] / sqrtf(1.0f+1e-5f);
  float o3 = b3[lane];
  __syncthreads();
  #pragma unroll
  for (int k4=0;k4<10;++k4){
    float4 y;
    y.x = q[k4].x*s3 + o3; y.x = (y.x>=0.f)?y.x:0.2f*y.x;
    y.y = q[k4].y*s3 + o3; y.y = (y.y>=0.f)?y.y:0.2f*y.y;
    y.z = q[k4].z*s3 + o3; y.z = (y.z>=0.f)?y.z:0.2f*y.z;
    y.w = q[k4].w*s3 + o3; y.w = (y.w>=0.f)?y.w:0.2f*y.w;
    *(float4*)&dL[lane*44 + k4*4] = y;
  }
  __syncthreads();
  float4 p[10];
  #pragma unroll
  for (int k4=0;k4<10;++k4) p[k4] = make_float4(0.f,0.f,0.f,0.f);
  for (int i=0;i<64;++i){
    float w = W4T[i*64 + lane];
    const float4* yp = (const float4*)&dL[i*44];
    #pragma unroll
    for (int k4=0;k4<10;++k4){
      float4 yv = yp[k4];
      p[k4].x = fmaf(w, yv.x, p[k4].x);
      p[k4].y = fmaf(w, yv.y, p[k4].y);
      p[k4].z = fmaf(w, yv.z, p[k4].z);
      p[k4].w = fmaf(w, yv.w, p[k4].w);
    }
  }
  float s4 = g4[lane] / sqrtf(1.0f+1e-5f);
  float o4 = b4[lane];
  float mx = -__builtin_inff();
  #pragma unroll
  for (int k4=0;k4<10;++k4){
    float vs[4] = {p[k4].x, p[k4].y, p[k4].z, p[k4].w};
    #pragma unroll
    for (int j=0;j<4;++j){
      float y = vs[j]*s4 + o4;
      y = (y>=0.f)?y:0.2f*y;
      mx = fmaxf(mx, y);
    }
  }
  X2T[e*64 + lane] = mx;
}

// (b,n,64) -> (b,c,n); dst pre-offset by channel base; dst batch stride = HS
__global__ __launch_bounds__(256) void k_tr(const float* __restrict__ src, float* __restrict__ dst){
  int b = blockIdx.x >> 5; int n0 = (blockIdx.x & 31) << 6;
  __shared__ float t[64*65];
  for (int e=threadIdx.x; e<4096; e+=256){
    int r = e >> 6, c = e & 63;
    t[r*65+c] = src[(b*Nn + n0 + r)*64 + c];
  }
  __syncthreads();
  for (int e=threadIdx.x; e<4096; e+=256){
    int c = e >> 6, r = e & 63;
    dst[b*HS + c*Nn + n0 + r] = t[r*65+c];
  }
}

// ---------------- SA layer ----------------
__global__ __launch_bounds__(256) void k_sa_a(const float* __restrict__ IN,
                                              const float* __restrict__ QKw, const float* __restrict__ Vw,
                                              const float* __restrict__ Vb,
                                              float* __restrict__ QX, float* __restrict__ XV){
  int b = blockIdx.x >> 5; int n0 = (blockIdx.x & 31) << 6;
  int w = threadIdx.x >> 6, lane = threadIdx.x & 63;
  __shared__ float xl[128*64];
  for (int e=threadIdx.x; e<8192; e+=256){
    int c = e >> 6, j = e & 63;
    xl[e] = IN[b*HS + c*Nn + n0 + j];
  }
  __syncthreads();
  for (int jj=0;jj<8;++jj){
    int o = w*8 + jj;
    const float4* wp = (const float4*)(QKw + o*128);
    float a = 0.f;
    #pragma unroll
    for (int c4=0;c4<32;++c4){
      float4 wv = wp[c4];
      a = fmaf(wv.x, xl[(c4*4+0)*64 + lane], a);
      a = fmaf(wv.y, xl[(c4*4+1)*64 + lane], a);
      a = fmaf(wv.z, xl[(c4*4+2)*64 + lane], a);
      a = fmaf(wv.w, xl[(c4*4+3)*64 + lane], a);
    }
    QX[(b*32+o)*Nn + n0 + lane] = a;
  }
  for (int jj=0;jj<32;++jj){
    int o = w*32 + jj;
    const float4* wp = (const float4*)(Vw + o*128);
    float a = 0.f;
    #pragma unroll
    for (int c4=0;c4<32;++c4){
      float4 wv = wp[c4];
      a = fmaf(wv.x, xl[(c4*4+0)*64 + lane], a);
      a = fmaf(wv.y, xl[(c4*4+1)*64 + lane], a);
      a = fmaf(wv.z, xl[(c4*4+2)*64 + lane], a);
      a = fmaf(wv.w, xl[(c4*4+3)*64 + lane], a);
    }
    XV[(b*128+o)*Nn + n0 + lane] = a + Vb[o];
  }
}

__global__ __launch_bounds__(256) void k_sa_b(const float* __restrict__ QX,
                                              float* __restrict__ RMP, float* __restrict__ RSP){
  int blk = blockIdx.x;
  int b = blk >> 5, sub = blk & 31;
  int ncn = sub >> 2, mcn = sub & 3;
  int n = ncn*256 + threadIdx.x;
  float q[32];
  #pragma unroll
  for (int o=0;o<32;++o) q[o] = QX[(b*32+o)*Nn + n];
  __shared__ float qt[32*128];
  float mr = -__builtin_inff(), lr = 0.f;
  int m0 = mcn*512;
  for (int t=0;t<4;++t){
    for (int e=threadIdx.x; e<4096; e+=256){
      int o = e >> 7, mm = e & 127;
      qt[e] = QX[(b*32+o)*Nn + m0 + t*128 + mm];
    }
    __syncthreads();
    for (int mm=0;mm<128;mm+=2){
      float e0=0.f, e1=0.f;
      #pragma unroll
      for (int o=0;o<32;++o){ float qo=q[o]; e0=fmaf(qo, qt[o*128+mm], e0); e1=fmaf(qo, qt[o*128+mm+1], e1); }
      if (e0 > mr){ lr = lr*expf(mr-e0) + 1.f; mr = e0; } else lr += expf(e0-mr);
      if (e1 > mr){ lr = lr*expf(mr-e1) + 1.f; mr = e1; } else lr += expf(e1-mr);
    }
    __syncthreads();
  }
  RMP[(b*Nn+n)*4 + mcn] = mr;
  RSP[(b*Nn+n)*4 + mcn] = lr;
}

__global__ __launch_bounds__(256) void k_sa_b2(const float* __restrict__ RMP, const float* __restrict__ RSP,
                                               float* __restrict__ RMX, float* __restrict__ RSM){
  int e = blockIdx.x*256 + threadIdx.x;
  float m0 = RMP[e*4+0], m1 = RMP[e*4+1], m2 = RMP[e*4+2], m3 = RMP[e*4+3];
  float l0 = RSP[e*4+0], l1 = RSP[e*4+1], l2 = RSP[e*4+2], l3 = RSP[e*4+3];
  float M = fmaxf(fmaxf(m0,m1), fmaxf(m2,m3));
  float l = l0*expf(m0-M) + l1*expf(m1-M) + l2*expf(m2-M) + l3*expf(m3-M);
  RMX[e] = M; RSM[e] = l;
}

#define SM_QM 0
#define SM_QN 2048
#define SM_XV 3072
#define SM_SL 7296
#define SM_MX 9344
#define SM_RL 9376
#define SM_CS 9408
#define SM_DL 0

// In-place: IN and OUT alias the same h buffer (so NOT __restrict__).
__global__ __launch_bounds__(256) void k_sa_c(const float* IN,
                                              const float* __restrict__ QX, const float* __restrict__ XV,
                                              const float* __restrict__ RMAX, const float* __restrict__ RSUM,
                                              const float* __restrict__ Tw, const float* __restrict__ Tb,
                                              const float* __restrict__ Gs, const float* __restrict__ Bs,
                                              float* OUT){
  int b = blockIdx.x >> 5; int m0 = (blockIdx.x & 31) << 6;
  int tid = threadIdx.x;
  int tc = tid >> 3, tm8 = tid & 7;
  __shared__ __align__(16) float sm[9472];
  for (int e=tid; e<2048; e+=256){
    int o = e >> 6, mm = e & 63;
    sm[SM_QM + e] = QX[(b*32+o)*Nn + m0 + mm];
  }
  float acc[4][8];
  #pragma unroll
  for (int ci=0;ci<4;++ci){
    #pragma unroll
    for (int mi=0;mi<8;++mi) acc[ci][mi] = 0.f;
  }
  float csr = 0.f;
  for (int it=0; it<64; ++it){
    int nb = it*32;
    __syncthreads();
    for (int e=tid; e<1024; e+=256){ int o=e>>5, nn=e&31; sm[SM_QN+e] = QX[(b*32+o)*Nn + nb + nn]; }
    for (int e=tid; e<4096; e+=256){ int c=e>>5, nn=e&31; sm[SM_XV + c*33 + nn] = XV[(b*128+c)*Nn + nb + nn]; }
    if (tid < 32){ sm[SM_MX+tid] = RMAX[b*Nn + nb + tid]; sm[SM_RL+tid] = 1.0f / RSUM[b*Nn + nb + tid]; }
    __syncthreads();
    for (int e=tid; e<2048; e+=256){
      int nn = e >> 6, mm = e & 63;
      float en = 0.f;
      #pragma unroll
      for (int o=0;o<32;++o) en = fmaf(sm[SM_QN + o*32 + nn], sm[SM_QM + o*64 + mm], en);
      sm[SM_SL + nn*64 + mm] = expf(en - sm[SM_MX+nn]) * sm[SM_RL+nn];
    }
    __syncthreads();
    if (tid < 64){
      #pragma unroll
      for (int nn=0;nn<32;++nn) csr += sm[SM_SL + nn*64 + tid];
    }
    #pragma unroll 4
    for (int nn=0;nn<32;++nn){
      float4 s0 = *(const float4*)&sm[SM_SL + nn*64 + tm8*8];
      float4 s1 = *(const float4*)&sm[SM_SL + nn*64 + tm8*8 + 4];
      #pragma unroll
      for (int ci=0;ci<4;++ci){
        float xv = sm[SM_XV + (tc*4+ci)*33 + nn];
        acc[ci][0] = fmaf(xv, s0.x, acc[ci][0]);
        acc[ci][1] = fmaf(xv, s0.y, acc[ci][1]);
        acc[ci][2] = fmaf(xv, s0.z, acc[ci][2]);
        acc[ci][3] = fmaf(xv, s0.w, acc[ci][3]);
        acc[ci][4] = fmaf(xv, s1.x, acc[ci][4]);
        acc[ci][5] = fmaf(xv, s1.y, acc[ci][5]);
        acc[ci][6] = fmaf(xv, s1.z, acc[ci][6]);
        acc[ci][7] = fmaf(xv, s1.w, acc[ci][7]);
      }
    }
  }
  __syncthreads();
  if (tid < 64) sm[SM_CS + tid] = csr;
  __syncthreads();
  #pragma unroll
  for (int ci=0;ci<4;++ci){
    int c = tc*4 + ci;
    #pragma unroll
    for (int mi=0;mi<8;++mi){
      int ml = tm8*8 + mi;
      float cs = sm[SM_CS + ml];
      float xr = acc[ci][mi] / (1e-9f + cs);
      float dv = IN[b*HS + c*Nn + m0 + ml] - xr;
      sm[SM_DL + c*64 + ml] = dv;
    }
  }
  __syncthreads();
  int w = tid >> 6, lane = tid & 63;
  float sroot = sqrtf(1.0f + 1e-5f);
  for (int jj=0;jj<32;++jj){
    int o = w*32 + jj;
    const float4* tw = (const float4*)(Tw + o*128);
    float a = 0.f;
    #pragma unroll
    for (int c4=0;c4<32;++c4){
      float4 wv = tw[c4];
      a = fmaf(wv.x, sm[SM_DL + (c4*4+0)*64 + lane], a);
      a = fmaf(wv.y, sm[SM_DL + (c4*4+1)*64 + lane], a);
      a = fmaf(wv.z, sm[SM_DL + (c4*4+2)*64 + lane], a);
      a = fmaf(wv.w, sm[SM_DL + (c4*4+3)*64 + lane], a);
    }
    a += Tb[o];
    float y = a * (Gs[o] / sroot) + Bs[o];
    y = fmaxf(y, 0.f);
    OUT[b*HS + o*Nn + m0 + lane] = IN[b*HS + o*Nn + m0 + lane] + y;
  }
}

// ---------------- progressive fuse: ACC += FW[:, l*128:(l+1)*128] * h_l ----------------
__global__ __launch_bounds__(256) void k_fuse_part(const float* __restrict__ Hc, const float* __restrict__ FWT,
                                                   float* __restrict__ ACC, int l, int init){
  int b = blockIdx.x >> 5; int n0 = (blockIdx.x & 31) << 6;
  int w = threadIdx.x >> 6, lane = threadIdx.x & 63;
  __shared__ float xt[128*64];
  for (int e=threadIdx.x; e<8192; e+=256){
    int c = e >> 6, j = e & 63;
    xt[e] = Hc[(b*128 + c)*Nn + n0 + j];
  }
  __syncthreads();
  float4 a[16];
  #pragma unroll
  for (int j=0;j<16;++j) a[j] = make_float4(0.f,0.f,0.f,0.f);
  for (int c=0;c<128;++c){
    float xv = xt[c*64 + lane];
    const float4* wr = (const float4*)(FWT + (l*128+c)*256 + w*64);
    #pragma unroll
    for (int j4=0;j4<16;++j4){
      float4 wv = wr[j4];
      a[j4].x = fmaf(wv.x, xv, a[j4].x);
      a[j4].y = fmaf(wv.y, xv, a[j4].y);
      a[j4].z = fmaf(wv.z, xv, a[j4].z);
      a[j4].w = fmaf(wv.w, xv, a[j4].w);
    }
  }
  #pragma unroll
  for (int j4=0;j4<16;++j4){
    float vs[4] = {a[j4].x, a[j4].y, a[j4].z, a[j4].w};
    #pragma unroll
    for (int qq=0;qq<4;++qq){
      int o = w*64 + j4*4 + qq;
      int idx = (b*256 + o)*Nn + n0 + lane;
      if (init) ACC[idx] = vs[qq];
      else      ACC[idx] = ACC[idx] + vs[qq];
    }
  }
}

// ---------------- final epilogue: in-place BN + leaky-ReLU on d_out ----------------
__global__ __launch_bounds__(256) void k_fin(float* __restrict__ ACC,
                                             const float* __restrict__ FGF, const float* __restrict__ FBF){
  int e = blockIdx.x*256 + threadIdx.x;    // 4,194,304 entries
  int o = (e >> 11) & 255;
  float sroot = sqrtf(1.0f + 1e-5f);
  float y = ACC[e] * (FGF[o] / sroot) + FBF[o];
  y = (y >= 0.f) ? y : 0.2f*y;
  ACC[e] = y;
}

extern "C" void kernel_launch(void* const* d_in, const int* in_sizes, int n_in,
                              void* d_out, int out_size, void* d_ws, size_t ws_size,
                              hipStream_t stream) {
  const float* X   = (const float*)d_in[0];
  const float* w1  = (const float*)d_in[1];
  const float* g1  = (const float*)d_in[2];
  const float* b1  = (const float*)d_in[3];
  const float* w2  = (const float*)d_in[4];
  const float* g2  = (const float*)d_in[5];
  const float* b2_ = (const float*)d_in[6];
  const float* w3  = (const float*)d_in[7];
  const float* g3  = (const float*)d_in[8];
  const float* b3  = (const float*)d_in[9];
  const float* w4  = (const float*)d_in[10];
  const float* g4  = (const float*)d_in[11];
  const float* b4  = (const float*)d_in[12];
  // d_in[13..15] = w5/g5/b5 : unused by reference
  const float* qk  = (const float*)d_in[16];
  const float* sv  = (const float*)d_in[17];
  const float* svb = (const float*)d_in[18];
  const float* st  = (const float*)d_in[19];
  const float* stb = (const float*)d_in[20];
  const float* sg  = (const float*)d_in[21];
  const float* sb  = (const float*)d_in[22];
  const float* fw  = (const float*)d_in[23];
  const float* fg  = (const float*)d_in[24];
  const float* fb  = (const float*)d_in[25];

  float* ws = (float*)d_ws;
  float* H    = ws + 0;          // 2,097,152
  float* QXb  = ws + 2097152;    //   524,288
  float* XVb  = ws + 2621440;    // 2,097,152
  float* RMP  = ws + 4718592;    //    65,536
  float* RSP  = ws + 4784128;    //    65,536
  float* RMX  = ws + 4849664;    //    16,384
  float* RSM  = ws + 4866048;    //    16,384
  // phase-1 overlay on [2,097,152 .. 4,915,200) — dead before SA phase:
  float* XX   = ws + 2146304;
  int*   IDX  = (int*)(ws + 2162688);
  float* X1T  = ws + 2818048;
  float* X2T  = ws + 3866624;
  float* C0   = ws + 4915200;
  float* W1T = C0 + 0;
  float* W2T = C0 + 384;
  float* W3T = C0 + 4480;
  float* W4T = C0 + 12672;
  float* FWT = C0 + 16768;       // end C0+147,840 = 5,063,040 floats = 19.3 MiB
  float* ACC = (float*)d_out;

  k_xx1<<<64,256,0,stream>>>(X, XX);
  k_prep_wt<<<578,256,0,stream>>>(w1,w2,w3,w4,fw, W1T,W2T,W3T,W4T,FWT);
  k_knn1<<<4096,256,0,stream>>>(X, XX, IDX);
  k_ec1<<<16384,64,0,stream>>>(X, IDX, W1T, W2T, g1,b1,g2,b2_, X1T);
  k_xx2<<<64,256,0,stream>>>(X1T, XX);
  k_tr<<<256,256,0,stream>>>(X1T, H);                  // X1 -> channel-major (H ch 0..63), BEFORE knn2
  k_knn2<<<4096,256,0,stream>>>(H, XX, IDX);           // coalesced channel-major reads
  k_ec2<<<16384,64,0,stream>>>(X1T, IDX, W3T, W4T, g3,b3,g4,b4, X2T);
  k_tr<<<256,256,0,stream>>>(X2T, H + 64*Nn);

  for (int l=0;l<4;++l){
    k_sa_a<<<256,256,0,stream>>>(H, qk + l*4096, sv + l*16384, svb + l*128, QXb, XVb);
    k_sa_b<<<256,256,0,stream>>>(QXb, RMP, RSP);
    k_sa_b2<<<64,256,0,stream>>>(RMP, RSP, RMX, RSM);
    k_sa_c<<<256,256,0,stream>>>(H, QXb, XVb, RMX, RSM,
                                 st + l*16384, stb + l*128, sg + l*128, sb + l*128, H);
    k_fuse_part<<<256,256,0,stream>>>(H, FWT, ACC, l, (l==0)?1:0);
  }
  k_fin<<<16384,256,0,stream>>>(ACC, fg, fb);
}

// Round 7
// 3834.508 us; speedup vs baseline: 6.4672x; 1.2450x over previous
//
#include <hip/hip_runtime.h>

#define Bb 8
#define Nn 2048
#define Kk 40
#define HS (128*Nn)   // h stride per batch (channel-major [b,128,2048])

// monotone float->uint transform: a > b  <=>  f2o(a) > f2o(b)
__device__ __forceinline__ unsigned f2o(float f){
  unsigned u = __float_as_uint(f);
  return (u & 0x80000000u) ? ~u : (u | 0x80000000u);
}

// Wave-cooperative exact top-40 of 2048. Lane owns m = j*64+lane (d[j]).
// Emits indices in jax.lax.top_k total order (value desc, index asc).
__device__ __forceinline__ void wave_top40(float* d, int lane, int* op){
  float bv = d[0]; int bj = 0;
  #pragma unroll
  for (int j=1;j<32;++j){ if (d[j] > bv){ bv = d[j]; bj = j; } }
  for (int t=0; t<Kk; ++t){
    int bm = bj*64 + lane;
    unsigned long long key = ((unsigned long long)f2o(bv) << 32) | (unsigned)(~bm);
    #pragma unroll
    for (int s=32;s>0;s>>=1){
      unsigned long long o = __shfl_xor(key, s, 64);
      if (o > key) key = o;
    }
    int wm = (int)(~(unsigned)key);
    if (lane == 0) op[t] = wm;
    bool mine = ((wm & 63) == lane);
    int wj = wm >> 6;
    bv = -__builtin_inff(); bj = 0;
    #pragma unroll
    for (int j=0;j<32;++j){
      float v = d[j];
      if (mine && j == wj) v = -__builtin_inff();
      d[j] = v;
      if (v > bv){ bv = v; bj = j; }
    }
  }
}

// Variant for mapping m = (s>>2)*256 + lane*4 + (s&3)  (coalesced float4 ownership).
__device__ __forceinline__ void wave_top40_g(float* d, int lane, int* op){
  float bv = d[0]; int bs = 0;
  #pragma unroll
  for (int s=1;s<32;++s){ if (d[s] > bv){ bv = d[s]; bs = s; } }
  for (int t=0; t<Kk; ++t){
    int bm = ((bs>>2)<<8) + lane*4 + (bs&3);
    unsigned long long key = ((unsigned long long)f2o(bv) << 32) | (unsigned)(~bm);
    #pragma unroll
    for (int s=32;s>0;s>>=1){
      unsigned long long o = __shfl_xor(key, s, 64);
      if (o > key) key = o;
    }
    int wm = (int)(~(unsigned)key);
    if (lane == 0) op[t] = wm;
    bool mine = (((wm>>2) & 63) == lane);
    int wsl = ((wm>>8)<<2) | (wm & 3);
    bv = -__builtin_inff(); bs = 0;
    #pragma unroll
    for (int s=0;s<32;++s){
      float v = d[s];
      if (mine && s == wsl) v = -__builtin_inff();
      d[s] = v;
      if (v > bv){ bv = v; bs = s; }
    }
  }
}

// ---------------- prep ----------------
__global__ __launch_bounds__(256) void k_xx1(const float* __restrict__ x, float* __restrict__ XX){
  int e = blockIdx.x*256 + threadIdx.x;
  if (e >= Bb*Nn) return;
  float p0 = x[e*3+0], p1 = x[e*3+1], p2 = x[e*3+2];
  XX[e] = __fadd_rn(__fadd_rn(__fmul_rn(p0,p0), __fmul_rn(p1,p1)), __fmul_rn(p2,p2));
}

__global__ __launch_bounds__(256) void k_prep_wt(const float* __restrict__ w1, const float* __restrict__ w2,
                                                 const float* __restrict__ w3, const float* __restrict__ w4,
                                                 const float* __restrict__ fw,
                                                 float* __restrict__ W1T, float* __restrict__ W2T,
                                                 float* __restrict__ W3T, float* __restrict__ W4T,
                                                 float* __restrict__ FWT){
  int e = blockIdx.x*256 + threadIdx.x;
  if (e < 384)   { int i=e/64,  c=e%64;  W1T[e] = w1[c*6+i];    return; } e -= 384;
  if (e < 4096)  { int i=e/64,  c=e%64;  W2T[e] = w2[c*64+i];   return; } e -= 4096;
  if (e < 8192)  { int i=e/64,  c=e%64;  W3T[e] = w3[c*128+i];  return; } e -= 8192;
  if (e < 4096)  { int i=e/64,  c=e%64;  W4T[e] = w4[c*64+i];   return; } e -= 4096;
  if (e < 131072){ int i=e/256, o=e%256; FWT[e] = fw[o*512+i];  return; }
}

// ---------------- knn on 3-D points: 1 wave / query, LDS-staged cloud ----------------
__global__ __launch_bounds__(256) void k_knn1(const float* __restrict__ P, const float* __restrict__ XX,
                                              int* __restrict__ IDX){
  int blk = blockIdx.x;
  int b = blk >> 9;
  int w = threadIdx.x >> 6, lane = threadIdx.x & 63;
  int n = (blk & 511)*4 + w;
  const float* Pb = P + b*Nn*3;
  const float* xb = XX + b*Nn;
  __shared__ float Pl[Nn*3];
  __shared__ float Xl[Nn];
  for (int e = threadIdx.x; e < Nn*3; e += 256) Pl[e] = Pb[e];
  for (int e = threadIdx.x; e < Nn; e += 256) Xl[e] = xb[e];
  __syncthreads();
  float c0 = Pl[n*3+0], c1 = Pl[n*3+1], c2 = Pl[n*3+2];
  float xn = Xl[n];
  float d[32];
  #pragma unroll
  for (int j=0;j<32;++j){
    int m = j*64 + lane;
    float a0 = Pl[m*3+0], a1 = Pl[m*3+1], a2 = Pl[m*3+2];
    float in_ = __fadd_rn(__fadd_rn(__fmul_rn(c0,a0), __fmul_rn(c1,a1)), __fmul_rn(c2,a2));
    d[j] = __fsub_rn(__fsub_rn(__fmul_rn(2.0f,in_), xn), Xl[m]);
  }
  wave_top40(d, lane, IDX + (b*Nn+n)*Kk);
}

// ---------------- edge conv 1+2 + maxpool (bit-exact _rn path) ----------------
__global__ __launch_bounds__(64) void k_ec1(const float* __restrict__ P, const int* __restrict__ IDX,
                                            const float* __restrict__ W1T, const float* __restrict__ W2T,
                                            const float* __restrict__ g1, const float* __restrict__ b1,
                                            const float* __restrict__ g2, const float* __restrict__ b2,
                                            float* __restrict__ X1T){
  int e = blockIdx.x;           // global point row 0..16383
  int b = e >> 11;
  int lane = threadIdx.x;
  __shared__ float dC[Kk*4];
  __shared__ __align__(16) float y1L[64*44];
  float c0 = P[e*3+0], c1 = P[e*3+1], c2 = P[e*3+2];
  if (lane < Kk) {
    int idx = IDX[e*Kk + lane] & (Nn-1);
    const float* pn = P + (b*Nn + idx)*3;
    dC[lane*4+0] = __fsub_rn(pn[0], c0);
    dC[lane*4+1] = __fsub_rn(pn[1], c1);
    dC[lane*4+2] = __fsub_rn(pn[2], c2);
  }
  __syncthreads();
  float w10 = W1T[0*64+lane], w11 = W1T[1*64+lane], w12 = W1T[2*64+lane];
  float w13 = W1T[3*64+lane], w14 = W1T[4*64+lane], w15 = W1T[5*64+lane];
  float p3 = __fmul_rn(w13,c0), p4 = __fmul_rn(w14,c1), p5 = __fmul_rn(w15,c2);
  float s1 = __fdiv_rn(g1[lane], __fsqrt_rn(1.0f + 1e-5f));
  float o1 = b1[lane];
  for (int k=0;k<Kk;++k){
    float t = __fmul_rn(w10, dC[k*4+0]);
    t = __fadd_rn(t, __fmul_rn(w11, dC[k*4+1]));
    t = __fadd_rn(t, __fmul_rn(w12, dC[k*4+2]));
    t = __fadd_rn(t, p3); t = __fadd_rn(t, p4); t = __fadd_rn(t, p5);
    float y = __fadd_rn(__fmul_rn(t, s1), o1);
    y = (y >= 0.0f) ? y : __fmul_rn(0.2f, y);
    y1L[lane*44+k] = y;
  }
  __syncthreads();
  float4 q[10];
  #pragma unroll
  for (int k4=0;k4<10;++k4) q[k4] = make_float4(0.f,0.f,0.f,0.f);
  for (int i=0;i<64;++i){
    float w = W2T[i*64+lane];
    const float4* yp = (const float4*)&y1L[i*44];
    #pragma unroll
    for (int k4=0;k4<10;++k4){
      float4 yv = yp[k4];
      q[k4].x = __fadd_rn(q[k4].x, __fmul_rn(w, yv.x));
      q[k4].y = __fadd_rn(q[k4].y, __fmul_rn(w, yv.y));
      q[k4].z = __fadd_rn(q[k4].z, __fmul_rn(w, yv.z));
      q[k4].w = __fadd_rn(q[k4].w, __fmul_rn(w, yv.w));
    }
  }
  float s2 = __fdiv_rn(g2[lane], __fsqrt_rn(1.0f + 1e-5f));
  float o2 = b2[lane];
  float mx = -__builtin_inff();
  #pragma unroll
  for (int k4=0;k4<10;++k4){
    float vs[4] = {q[k4].x, q[k4].y, q[k4].z, q[k4].w};
    #pragma unroll
    for (int j=0;j<4;++j){
      float y = __fadd_rn(__fmul_rn(vs[j], s2), o2);
      y = (y >= 0.0f) ? y : __fmul_rn(0.2f, y);
      mx = fmaxf(mx, y);
    }
  }
  X1T[e*64 + lane] = mx;
}

__global__ __launch_bounds__(256) void k_xx2(const float* __restrict__ X1T, float* __restrict__ XX2){
  int e = blockIdx.x*256 + threadIdx.x;
  const float* r = X1T + e*64;
  float a = 0.f;
  for (int c=0;c<64;++c) a = __fadd_rn(a, __fmul_rn(r[c], r[c]));
  XX2[e] = a;
}

// ---------------- knn on 64-D features: channel-major coalesced reads ----------------
__global__ __launch_bounds__(256) void k_knn2(const float* __restrict__ X1C, const float* __restrict__ XX2,
                                              int* __restrict__ IDX){
  int blk = blockIdx.x;
  int b = blk >> 9;
  int w = threadIdx.x >> 6, lane = threadIdx.x & 63;
  int n = (blk & 511)*4 + w;
  __shared__ float qL[4*64];
  { int t = threadIdx.x; int ww = t >> 6, c = t & 63;
    int nn = (blk & 511)*4 + ww;
    qL[t] = X1C[b*HS + c*Nn + nn]; }
  __syncthreads();
  const float* xb = XX2 + b*Nn;
  float4 a4[8];
  #pragma unroll
  for (int j=0;j<8;++j) a4[j] = make_float4(0.f,0.f,0.f,0.f);
  for (int c=0;c<64;++c){
    float qc = qL[w*64 + c];
    const float4* row = (const float4*)(X1C + b*HS + c*Nn);
    #pragma unroll
    for (int j=0;j<8;++j){
      float4 v = row[j*64 + lane];
      a4[j].x = __fadd_rn(a4[j].x, __fmul_rn(qc, v.x));
      a4[j].y = __fadd_rn(a4[j].y, __fmul_rn(qc, v.y));
      a4[j].z = __fadd_rn(a4[j].z, __fmul_rn(qc, v.z));
      a4[j].w = __fadd_rn(a4[j].w, __fmul_rn(qc, v.w));
    }
  }
  float xn = xb[n];
  float d[32];
  #pragma unroll
  for (int j=0;j<8;++j){
    float4 xm = ((const float4*)xb)[j*64 + lane];
    d[j*4+0] = __fsub_rn(__fsub_rn(__fmul_rn(2.0f, a4[j].x), xn), xm.x);
    d[j*4+1] = __fsub_rn(__fsub_rn(__fmul_rn(2.0f, a4[j].y), xn), xm.y);
    d[j*4+2] = __fsub_rn(__fsub_rn(__fmul_rn(2.0f, a4[j].z), xn), xm.z);
    d[j*4+3] = __fsub_rn(__fsub_rn(__fmul_rn(2.0f, a4[j].w), xn), xm.w);
  }
  wave_top40_g(d, lane, IDX + (b*Nn+n)*Kk);
}

// ---------------- edge conv 3+4 + maxpool (fma ok) ----------------
__global__ __launch_bounds__(64) void k_ec2(const float* __restrict__ X1T, const int* __restrict__ IDX,
                                            const float* __restrict__ W3T, const float* __restrict__ W4T,
                                            const float* __restrict__ g3, const float* __restrict__ b3,
                                            const float* __restrict__ g4, const float* __restrict__ b4,
                                            float* __restrict__ X2T){
  int e = blockIdx.x; int b = e >> 11; int lane = threadIdx.x;
  __shared__ __align__(16) float dL[64*44];
  __shared__ float ctrL[64];
  float ctr = X1T[e*64 + lane];
  ctrL[lane] = ctr;
  __syncthreads();
  for (int k=0;k<Kk;++k){
    int idx = IDX[e*Kk + k] & (Nn-1);
    dL[lane*44 + k] = X1T[(b*Nn+idx)*64 + lane] - ctr;
  }
  __syncthreads();
  float base = 0.f;
  for (int i=0;i<64;++i) base = fmaf(W3T[(64+i)*64 + lane], ctrL[i], base);
  float4 q[10];
  #pragma unroll
  for (int k4=0;k4<10;++k4) q[k4] = make_float4(base,base,base,base);
  for (int i=0;i<64;++i){
    float w = W3T[i*64 + lane];
    const float4* dp = (const float4*)&dL[i*44];
    #pragma unroll
    for (int k4=0;k4<10;++k4){
      float4 d = dp[k4];
      q[k4].x = fmaf(w, d.x, q[k4].x);
      q[k4].y = fmaf(w, d.y, q[k4].y);
      q[k4].z = fmaf(w, d.z, q[k4].z);
      q[k4].w = fmaf(w, d.w, q[k4].w);
    }
  }
  float s3 = g3[lane] / sqrtf(1.0f+1e-5f);
  float o3 = b3[lane];
  __syncthreads();
  #pragma unroll
  for (int k4=0;k4<10;++k4){
    float4 y;
    y.x = q[k4].x*s3 + o3; y.x = (y.x>=0.f)?y.x:0.2f*y.x;
    y.y = q[k4].y*s3 + o3; y.y = (y.y>=0.f)?y.y:0.2f*y.y;
    y.z = q[k4].z*s3 + o3; y.z = (y.z>=0.f)?y.z:0.2f*y.z;
    y.w = q[k4].w*s3 + o3; y.w = (y.w>=0.f)?y.w:0.2f*y.w;
    *(float4*)&dL[lane*44 + k4*4] = y;
  }
  __syncthreads();
  float4 p[10];
  #pragma unroll
  for (int k4=0;k4<10;++k4) p[k4] = make_float4(0.f,0.f,0.f,0.f);
  for (int i=0;i<64;++i){
    float w = W4T[i*64 + lane];
    const float4* yp = (const float4*)&dL[i*44];
    #pragma unroll
    for (int k4=0;k4<10;++k4){
      float4 yv = yp[k4];
      p[k4].x = fmaf(w, yv.x, p[k4].x);
      p[k4].y = fmaf(w, yv.y, p[k4].y);
      p[k4].z = fmaf(w, yv.z, p[k4].z);
      p[k4].w = fmaf(w, yv.w, p[k4].w);
    }
  }
  float s4 = g4[lane] / sqrtf(1.0f+1e-5f);
  float o4 = b4[lane];
  float mx = -__builtin_inff();
  #pragma unroll
  for (int k4=0;k4<10;++k4){
    float vs[4] = {p[k4].x, p[k4].y, p[k4].z, p[k4].w};
    #pragma unroll
    for (int j=0;j<4;++j){
      float y = vs[j]*s4 + o4;
      y = (y>=0.f)?y:0.2f*y;
      mx = fmaxf(mx, y);
    }
  }
  X2T[e*64 + lane] = mx;
}

// (b,n,64) -> (b,c,n); dst pre-offset by channel base; dst batch stride = HS
__global__ __launch_bounds__(256) void k_tr(const float* __restrict__ src, float* __restrict__ dst){
  int b = blockIdx.x >> 5; int n0 = (blockIdx.x & 31) << 6;
  __shared__ float t[64*65];
  for (int e=threadIdx.x; e<4096; e+=256){
    int r = e >> 6, c = e & 63;
    t[r*65+c] = src[(b*Nn + n0 + r)*64 + c];
  }
  __syncthreads();
  for (int e=threadIdx.x; e<4096; e+=256){
    int c = e >> 6, r = e & 63;
    dst[b*HS + c*Nn + n0 + r] = t[r*65+c];
  }
}

// ---------------- SA layer ----------------
__global__ __launch_bounds__(256) void k_sa_a(const float* __restrict__ IN,
                                              const float* __restrict__ QKw, const float* __restrict__ Vw,
                                              const float* __restrict__ Vb,
                                              float* __restrict__ QX, float* __restrict__ XV){
  int b = blockIdx.x >> 5; int n0 = (blockIdx.x & 31) << 6;
  int w = threadIdx.x >> 6, lane = threadIdx.x & 63;
  __shared__ float xl[128*64];
  for (int e=threadIdx.x; e<8192; e+=256){
    int c = e >> 6, j = e & 63;
    xl[e] = IN[b*HS + c*Nn + n0 + j];
  }
  __syncthreads();
  for (int jj=0;jj<8;++jj){
    int o = w*8 + jj;
    const float4* wp = (const float4*)(QKw + o*128);
    float a = 0.f;
    #pragma unroll
    for (int c4=0;c4<32;++c4){
      float4 wv = wp[c4];
      a = fmaf(wv.x, xl[(c4*4+0)*64 + lane], a);
      a = fmaf(wv.y, xl[(c4*4+1)*64 + lane], a);
      a = fmaf(wv.z, xl[(c4*4+2)*64 + lane], a);
      a = fmaf(wv.w, xl[(c4*4+3)*64 + lane], a);
    }
    QX[(b*32+o)*Nn + n0 + lane] = a;
  }
  for (int jj=0;jj<32;++jj){
    int o = w*32 + jj;
    const float4* wp = (const float4*)(Vw + o*128);
    float a = 0.f;
    #pragma unroll
    for (int c4=0;c4<32;++c4){
      float4 wv = wp[c4];
      a = fmaf(wv.x, xl[(c4*4+0)*64 + lane], a);
      a = fmaf(wv.y, xl[(c4*4+1)*64 + lane], a);
      a = fmaf(wv.z, xl[(c4*4+2)*64 + lane], a);
      a = fmaf(wv.w, xl[(c4*4+3)*64 + lane], a);
    }
    XV[(b*128+o)*Nn + n0 + lane] = a + Vb[o];
  }
}

__global__ __launch_bounds__(256) void k_sa_b(const float* __restrict__ QX,
                                              float* __restrict__ RMP, float* __restrict__ RSP){
  int blk = blockIdx.x;
  int b = blk >> 5, sub = blk & 31;
  int ncn = sub >> 2, mcn = sub & 3;
  int n = ncn*256 + threadIdx.x;
  float q[32];
  #pragma unroll
  for (int o=0;o<32;++o) q[o] = QX[(b*32+o)*Nn + n];
  __shared__ float qt[32*128];
  float mr = -__builtin_inff(), lr = 0.f;
  int m0 = mcn*512;
  for (int t=0;t<4;++t){
    for (int e=threadIdx.x; e<4096; e+=256){
      int o = e >> 7, mm = e & 127;
      qt[e] = QX[(b*32+o)*Nn + m0 + t*128 + mm];
    }
    __syncthreads();
    for (int mm=0;mm<128;mm+=2){
      float e0=0.f, e1=0.f;
      #pragma unroll
      for (int o=0;o<32;++o){ float qo=q[o]; e0=fmaf(qo, qt[o*128+mm], e0); e1=fmaf(qo, qt[o*128+mm+1], e1); }
      if (e0 > mr){ lr = lr*expf(mr-e0) + 1.f; mr = e0; } else lr += expf(e0-mr);
      if (e1 > mr){ lr = lr*expf(mr-e1) + 1.f; mr = e1; } else lr += expf(e1-mr);
    }
    __syncthreads();
  }
  RMP[(b*Nn+n)*4 + mcn] = mr;
  RSP[(b*Nn+n)*4 + mcn] = lr;
}

__global__ __launch_bounds__(256) void k_sa_b2(const float* __restrict__ RMP, const float* __restrict__ RSP,
                                               float* __restrict__ RMX, float* __restrict__ RSM){
  int e = blockIdx.x*256 + threadIdx.x;
  float m0 = RMP[e*4+0], m1 = RMP[e*4+1], m2 = RMP[e*4+2], m3 = RMP[e*4+3];
  float l0 = RSP[e*4+0], l1 = RSP[e*4+1], l2 = RSP[e*4+2], l3 = RSP[e*4+3];
  float M = fmaxf(fmaxf(m0,m1), fmaxf(m2,m3));
  float l = l0*expf(m0-M) + l1*expf(m1-M) + l2*expf(m2-M) + l3*expf(m3-M);
  RMX[e] = M; RSM[e] = l;
}

// LDS map (floats): QM[32o][32m]=1024 @0, QN[32o][32n]=1024 @1024,
// XVt[32n][132]=4224 @2048, SL[32n][32m]=1024 @6272, MX@7296, RL@7328, CS@7360.
// DL[128c][32m]=4096 @0 (reuses dead QM/QN/XVt after the main loop).
#define SM_QM 0
#define SM_QN 1024
#define SM_XV 2048
#define SM_SL 6272
#define SM_MX 7296
#define SM_RL 7328
#define SM_CS 7360
#define SM_DL 0

// m-tile=32, grid 512 (2 blocks/CU). In-place: IN/OUT alias the h buffer.
// Accumulation orders identical to the m=64 version (o asc, nn asc, it asc, c asc)
// -> bit-identical output.
__global__ __launch_bounds__(256) void k_sa_c(const float* IN,
                                              const float* __restrict__ QX, const float* __restrict__ XV,
                                              const float* __restrict__ RMAX, const float* __restrict__ RSUM,
                                              const float* __restrict__ Tw, const float* __restrict__ Tb,
                                              const float* __restrict__ Gs, const float* __restrict__ Bs,
                                              float* OUT){
  int b = blockIdx.x >> 6; int m0 = (blockIdx.x & 63) << 5;
  int tid = threadIdx.x;
  int nnp = tid >> 4, mmp = tid & 15;      // 2x2 S-microtile owner
  int tc = tid >> 3, tm8 = tid & 7;        // PV owner: c=tc*4+ci, m=tm8*4+mi
  __shared__ __align__(16) float sm[7392];
  for (int e=tid; e<1024; e+=256){
    int o = e >> 5, mm = e & 31;
    sm[SM_QM + e] = QX[(b*32+o)*Nn + m0 + mm];
  }
  float acc[4][4];
  #pragma unroll
  for (int ci=0;ci<4;++ci){
    #pragma unroll
    for (int mi=0;mi<4;++mi) acc[ci][mi] = 0.f;
  }
  float csr = 0.f;
  for (int it=0; it<64; ++it){
    int nb = it*32;
    __syncthreads();
    for (int e=tid; e<1024; e+=256){ int o=e>>5, nn=e&31; sm[SM_QN+e] = QX[(b*32+o)*Nn + nb + nn]; }
    for (int e=tid; e<4096; e+=256){ int c=e>>5, nn=e&31; sm[SM_XV + nn*132 + c] = XV[(b*128+c)*Nn + nb + nn]; }
    if (tid < 32){ sm[SM_MX+tid] = RMAX[b*Nn + nb + tid]; sm[SM_RL+tid] = 1.0f / RSUM[b*Nn + nb + tid]; }
    __syncthreads();
    // energy 2x2 microtile: float2 reads, 4 independent fma chains
    float e00=0.f, e01=0.f, e10=0.f, e11=0.f;
    #pragma unroll
    for (int o=0;o<32;++o){
      float2 qn = *(const float2*)&sm[SM_QN + o*32 + nnp*2];
      float2 qm = *(const float2*)&sm[SM_QM + o*32 + mmp*2];
      e00 = fmaf(qn.x, qm.x, e00);
      e01 = fmaf(qn.x, qm.y, e01);
      e10 = fmaf(qn.y, qm.x, e10);
      e11 = fmaf(qn.y, qm.y, e11);
    }
    float mx0 = sm[SM_MX + nnp*2],   rl0 = sm[SM_RL + nnp*2];
    float mx1 = sm[SM_MX + nnp*2+1], rl1 = sm[SM_RL + nnp*2+1];
    float2 s0; s0.x = expf(e00-mx0)*rl0; s0.y = expf(e01-mx0)*rl0;
    float2 s1; s1.x = expf(e10-mx1)*rl1; s1.y = expf(e11-mx1)*rl1;
    *(float2*)&sm[SM_SL + (nnp*2  )*32 + mmp*2] = s0;
    *(float2*)&sm[SM_SL + (nnp*2+1)*32 + mmp*2] = s1;
    __syncthreads();
    if (tid < 32){
      #pragma unroll
      for (int nn=0;nn<32;++nn) csr += sm[SM_SL + nn*32 + tid];
    }
    #pragma unroll 8
    for (int nn=0;nn<32;++nn){
      float4 xv4 = *(const float4*)&sm[SM_XV + nn*132 + tc*4];
      float4 s4  = *(const float4*)&sm[SM_SL + nn*32  + tm8*4];
      acc[0][0] = fmaf(xv4.x, s4.x, acc[0][0]);
      acc[0][1] = fmaf(xv4.x, s4.y, acc[0][1]);
      acc[0][2] = fmaf(xv4.x, s4.z, acc[0][2]);
      acc[0][3] = fmaf(xv4.x, s4.w, acc[0][3]);
      acc[1][0] = fmaf(xv4.y, s4.x, acc[1][0]);
      acc[1][1] = fmaf(xv4.y, s4.y, acc[1][1]);
      acc[1][2] = fmaf(xv4.y, s4.z, acc[1][2]);
      acc[1][3] = fmaf(xv4.y, s4.w, acc[1][3]);
      acc[2][0] = fmaf(xv4.z, s4.x, acc[2][0]);
      acc[2][1] = fmaf(xv4.z, s4.y, acc[2][1]);
      acc[2][2] = fmaf(xv4.z, s4.z, acc[2][2]);
      acc[2][3] = fmaf(xv4.z, s4.w, acc[2][3]);
      acc[3][0] = fmaf(xv4.w, s4.x, acc[3][0]);
      acc[3][1] = fmaf(xv4.w, s4.y, acc[3][1]);
      acc[3][2] = fmaf(xv4.w, s4.z, acc[3][2]);
      acc[3][3] = fmaf(xv4.w, s4.w, acc[3][3]);
    }
  }
  __syncthreads();
  if (tid < 32) sm[SM_CS + tid] = csr;
  __syncthreads();
  #pragma unroll
  for (int ci=0;ci<4;++ci){
    int c = tc*4 + ci;
    #pragma unroll
    for (int mi=0;mi<4;++mi){
      int ml = tm8*4 + mi;
      float cs = sm[SM_CS + ml];
      float xr = acc[ci][mi] / (1e-9f + cs);
      float dv = IN[b*HS + c*Nn + m0 + ml] - xr;
      sm[SM_DL + c*32 + ml] = dv;
    }
  }
  __syncthreads();
  int hw = tid >> 5, m = tid & 31;
  float sroot = sqrtf(1.0f + 1e-5f);
  for (int oo=0; oo<16; ++oo){
    int o = oo*8 + hw;
    const float4* twp = (const float4*)(Tw + o*128);
    float a = 0.f;
    #pragma unroll
    for (int c4=0;c4<32;++c4){
      float4 wv = twp[c4];
      a = fmaf(wv.x, sm[SM_DL + (c4*4+0)*32 + m], a);
      a = fmaf(wv.y, sm[SM_DL + (c4*4+1)*32 + m], a);
      a = fmaf(wv.z, sm[SM_DL + (c4*4+2)*32 + m], a);
      a = fmaf(wv.w, sm[SM_DL + (c4*4+3)*32 + m], a);
    }
    a += Tb[o];
    float y = a * (Gs[o] / sroot) + Bs[o];
    y = fmaxf(y, 0.f);
    OUT[b*HS + o*Nn + m0 + m] = IN[b*HS + o*Nn + m0 + m] + y;
  }
}

// ---------------- progressive fuse: ACC += FW[:, l*128:(l+1)*128] * h_l ----------------
__global__ __launch_bounds__(256) void k_fuse_part(const float* __restrict__ Hc, const float* __restrict__ FWT,
                                                   float* __restrict__ ACC, int l, int init){
  int b = blockIdx.x >> 5; int n0 = (blockIdx.x & 31) << 6;
  int w = threadIdx.x >> 6, lane = threadIdx.x & 63;
  __shared__ float xt[128*64];
  for (int e=threadIdx.x; e<8192; e+=256){
    int c = e >> 6, j = e & 63;
    xt[e] = Hc[(b*128 + c)*Nn + n0 + j];
  }
  __syncthreads();
  float4 a[16];
  #pragma unroll
  for (int j=0;j<16;++j) a[j] = make_float4(0.f,0.f,0.f,0.f);
  for (int c=0;c<128;++c){
    float xv = xt[c*64 + lane];
    const float4* wr = (const float4*)(FWT + (l*128+c)*256 + w*64);
    #pragma unroll
    for (int j4=0;j4<16;++j4){
      float4 wv = wr[j4];
      a[j4].x = fmaf(wv.x, xv, a[j4].x);
      a[j4].y = fmaf(wv.y, xv, a[j4].y);
      a[j4].z = fmaf(wv.z, xv, a[j4].z);
      a[j4].w = fmaf(wv.w, xv, a[j4].w);
    }
  }
  #pragma unroll
  for (int j4=0;j4<16;++j4){
    float vs[4] = {a[j4].x, a[j4].y, a[j4].z, a[j4].w};
    #pragma unroll
    for (int qq=0;qq<4;++qq){
      int o = w*64 + j4*4 + qq;
      int idx = (b*256 + o)*Nn + n0 + lane;
      if (init) ACC[idx] = vs[qq];
      else      ACC[idx] = ACC[idx] + vs[qq];
    }
  }
}

// ---------------- final epilogue: in-place BN + leaky-ReLU on d_out ----------------
__global__ __launch_bounds__(256) void k_fin(float* __restrict__ ACC,
                                             const float* __restrict__ FGF, const float* __restrict__ FBF){
  int e = blockIdx.x*256 + threadIdx.x;    // 4,194,304 entries
  int o = (e >> 11) & 255;
  float sroot = sqrtf(1.0f + 1e-5f);
  float y = ACC[e] * (FGF[o] / sroot) + FBF[o];
  y = (y >= 0.f) ? y : 0.2f*y;
  ACC[e] = y;
}

extern "C" void kernel_launch(void* const* d_in, const int* in_sizes, int n_in,
                              void* d_out, int out_size, void* d_ws, size_t ws_size,
                              hipStream_t stream) {
  const float* X   = (const float*)d_in[0];
  const float* w1  = (const float*)d_in[1];
  const float* g1  = (const float*)d_in[2];
  const float* b1  = (const float*)d_in[3];
  const float* w2  = (const float*)d_in[4];
  const float* g2  = (const float*)d_in[5];
  const float* b2_ = (const float*)d_in[6];
  const float* w3  = (const float*)d_in[7];
  const float* g3  = (const float*)d_in[8];
  const float* b3  = (const float*)d_in[9];
  const float* w4  = (const float*)d_in[10];
  const float* g4  = (const float*)d_in[11];
  const float* b4  = (const float*)d_in[12];
  // d_in[13..15] = w5/g5/b5 : unused by reference
  const float* qk  = (const float*)d_in[16];
  const float* sv  = (const float*)d_in[17];
  const float* svb = (const float*)d_in[18];
  const float* st  = (const float*)d_in[19];
  const float* stb = (const float*)d_in[20];
  const float* sg  = (const float*)d_in[21];
  const float* sb  = (const float*)d_in[22];
  const float* fw  = (const float*)d_in[23];
  const float* fg  = (const float*)d_in[24];
  const float* fb  = (const float*)d_in[25];

  float* ws = (float*)d_ws;
  float* H    = ws + 0;          // 2,097,152
  float* QXb  = ws + 2097152;    //   524,288
  float* XVb  = ws + 2621440;    // 2,097,152
  float* RMP  = ws + 4718592;    //    65,536
  float* RSP  = ws + 4784128;    //    65,536
  float* RMX  = ws + 4849664;    //    16,384
  float* RSM  = ws + 4866048;    //    16,384
  // phase-1 overlay on [2,097,152 .. 4,915,200) — dead before SA phase:
  float* XX   = ws + 2146304;
  int*   IDX  = (int*)(ws + 2162688);
  float* X1T  = ws + 2818048;
  float* X2T  = ws + 3866624;
  float* C0   = ws + 4915200;
  float* W1T = C0 + 0;
  float* W2T = C0 + 384;
  float* W3T = C0 + 4480;
  float* W4T = C0 + 12672;
  float* FWT = C0 + 16768;       // end C0+147,840 = 5,063,040 floats = 19.3 MiB
  float* ACC = (float*)d_out;

  k_xx1<<<64,256,0,stream>>>(X, XX);
  k_prep_wt<<<578,256,0,stream>>>(w1,w2,w3,w4,fw, W1T,W2T,W3T,W4T,FWT);
  k_knn1<<<4096,256,0,stream>>>(X, XX, IDX);
  k_ec1<<<16384,64,0,stream>>>(X, IDX, W1T, W2T, g1,b1,g2,b2_, X1T);
  k_xx2<<<64,256,0,stream>>>(X1T, XX);
  k_tr<<<256,256,0,stream>>>(X1T, H);                  // X1 -> channel-major (H ch 0..63), BEFORE knn2
  k_knn2<<<4096,256,0,stream>>>(H, XX, IDX);           // coalesced channel-major reads
  k_ec2<<<16384,64,0,stream>>>(X1T, IDX, W3T, W4T, g3,b3,g4,b4, X2T);
  k_tr<<<256,256,0,stream>>>(X2T, H + 64*Nn);

  for (int l=0;l<4;++l){
    k_sa_a<<<256,256,0,stream>>>(H, qk + l*4096, sv + l*16384, svb + l*128, QXb, XVb);
    k_sa_b<<<256,256,0,stream>>>(QXb, RMP, RSP);
    k_sa_b2<<<64,256,0,stream>>>(RMP, RSP, RMX, RSM);
    k_sa_c<<<512,256,0,stream>>>(H, QXb, XVb, RMX, RSM,
                                 st + l*16384, stb + l*128, sg + l*128, sb + l*128, H);
    k_fuse_part<<<256,256,0,stream>>>(H, FWT, ACC, l, (l==0)?1:0);
  }
  k_fin<<<16384,256,0,stream>>>(ACC, fg, fb);
}

// Round 8
// 3041.708 us; speedup vs baseline: 8.1528x; 1.2606x over previous
//
#include <hip/hip_runtime.h>

#define Bb 8
#define Nn 2048
#define Kk 40
#define HS (128*Nn)   // h stride per batch (channel-major [b,128,2048])

// monotone float->uint transform: a > b  <=>  f2o(a) > f2o(b)
__device__ __forceinline__ unsigned f2o(float f){
  unsigned u = __float_as_uint(f);
  return (u & 0x80000000u) ? ~u : (u | 0x80000000u);
}

// Wave-cooperative exact top-40 of 2048. Lane owns m = j*64+lane (d[j]).
// Emits indices in jax.lax.top_k total order (value desc, index asc).
__device__ __forceinline__ void wave_top40(float* d, int lane, int* op){
  float bv = d[0]; int bj = 0;
  #pragma unroll
  for (int j=1;j<32;++j){ if (d[j] > bv){ bv = d[j]; bj = j; } }
  for (int t=0; t<Kk; ++t){
    int bm = bj*64 + lane;
    unsigned long long key = ((unsigned long long)f2o(bv) << 32) | (unsigned)(~bm);
    #pragma unroll
    for (int s=32;s>0;s>>=1){
      unsigned long long o = __shfl_xor(key, s, 64);
      if (o > key) key = o;
    }
    int wm = (int)(~(unsigned)key);
    if (lane == 0) op[t] = wm;
    bool mine = ((wm & 63) == lane);
    int wj = wm >> 6;
    bv = -__builtin_inff(); bj = 0;
    #pragma unroll
    for (int j=0;j<32;++j){
      float v = d[j];
      if (mine && j == wj) v = -__builtin_inff();
      d[j] = v;
      if (v > bv){ bv = v; bj = j; }
    }
  }
}

// Variant for mapping m = (s>>2)*256 + lane*4 + (s&3)  (coalesced float4 ownership).
__device__ __forceinline__ void wave_top40_g(float* d, int lane, int* op){
  float bv = d[0]; int bs = 0;
  #pragma unroll
  for (int s=1;s<32;++s){ if (d[s] > bv){ bv = d[s]; bs = s; } }
  for (int t=0; t<Kk; ++t){
    int bm = ((bs>>2)<<8) + lane*4 + (bs&3);
    unsigned long long key = ((unsigned long long)f2o(bv) << 32) | (unsigned)(~bm);
    #pragma unroll
    for (int s=32;s>0;s>>=1){
      unsigned long long o = __shfl_xor(key, s, 64);
      if (o > key) key = o;
    }
    int wm = (int)(~(unsigned)key);
    if (lane == 0) op[t] = wm;
    bool mine = (((wm>>2) & 63) == lane);
    int wsl = ((wm>>8)<<2) | (wm & 3);
    bv = -__builtin_inff(); bs = 0;
    #pragma unroll
    for (int s=0;s<32;++s){
      float v = d[s];
      if (mine && s == wsl) v = -__builtin_inff();
      d[s] = v;
      if (v > bv){ bv = v; bs = s; }
    }
  }
}

// ---------------- prep ----------------
__global__ __launch_bounds__(256) void k_xx1(const float* __restrict__ x, float* __restrict__ XX){
  int e = blockIdx.x*256 + threadIdx.x;
  if (e >= Bb*Nn) return;
  float p0 = x[e*3+0], p1 = x[e*3+1], p2 = x[e*3+2];
  XX[e] = __fadd_rn(__fadd_rn(__fmul_rn(p0,p0), __fmul_rn(p1,p1)), __fmul_rn(p2,p2));
}

__global__ __launch_bounds__(256) void k_prep_wt(const float* __restrict__ w1, const float* __restrict__ w2,
                                                 const float* __restrict__ w3, const float* __restrict__ w4,
                                                 const float* __restrict__ fw,
                                                 float* __restrict__ W1T, float* __restrict__ W2T,
                                                 float* __restrict__ W3T, float* __restrict__ W4T,
                                                 float* __restrict__ FWT){
  int e = blockIdx.x*256 + threadIdx.x;
  if (e < 384)   { int i=e/64,  c=e%64;  W1T[e] = w1[c*6+i];    return; } e -= 384;
  if (e < 4096)  { int i=e/64,  c=e%64;  W2T[e] = w2[c*64+i];   return; } e -= 4096;
  if (e < 8192)  { int i=e/64,  c=e%64;  W3T[e] = w3[c*128+i];  return; } e -= 8192;
  if (e < 4096)  { int i=e/64,  c=e%64;  W4T[e] = w4[c*64+i];   return; } e -= 4096;
  if (e < 131072){ int i=e/256, o=e%256; FWT[e] = fw[o*512+i];  return; }
}

// ---------------- knn on 3-D points: 1 wave / query, LDS-staged cloud ----------------
__global__ __launch_bounds__(256) void k_knn1(const float* __restrict__ P, const float* __restrict__ XX,
                                              int* __restrict__ IDX){
  int blk = blockIdx.x;
  int b = blk >> 9;
  int w = threadIdx.x >> 6, lane = threadIdx.x & 63;
  int n = (blk & 511)*4 + w;
  const float* Pb = P + b*Nn*3;
  const float* xb = XX + b*Nn;
  __shared__ float Pl[Nn*3];
  __shared__ float Xl[Nn];
  for (int e = threadIdx.x; e < Nn*3; e += 256) Pl[e] = Pb[e];
  for (int e = threadIdx.x; e < Nn; e += 256) Xl[e] = xb[e];
  __syncthreads();
  float c0 = Pl[n*3+0], c1 = Pl[n*3+1], c2 = Pl[n*3+2];
  float xn = Xl[n];
  float d[32];
  #pragma unroll
  for (int j=0;j<32;++j){
    int m = j*64 + lane;
    float a0 = Pl[m*3+0], a1 = Pl[m*3+1], a2 = Pl[m*3+2];
    float in_ = __fadd_rn(__fadd_rn(__fmul_rn(c0,a0), __fmul_rn(c1,a1)), __fmul_rn(c2,a2));
    d[j] = __fsub_rn(__fsub_rn(__fmul_rn(2.0f,in_), xn), Xl[m]);
  }
  wave_top40(d, lane, IDX + (b*Nn+n)*Kk);
}

// ---------------- edge conv 1+2 + maxpool (bit-exact _rn path) ----------------
__global__ __launch_bounds__(64) void k_ec1(const float* __restrict__ P, const int* __restrict__ IDX,
                                            const float* __restrict__ W1T, const float* __restrict__ W2T,
                                            const float* __restrict__ g1, const float* __restrict__ b1,
                                            const float* __restrict__ g2, const float* __restrict__ b2,
                                            float* __restrict__ X1T){
  int e = blockIdx.x;           // global point row 0..16383
  int b = e >> 11;
  int lane = threadIdx.x;
  __shared__ float dC[Kk*4];
  __shared__ __align__(16) float y1L[64*44];
  float c0 = P[e*3+0], c1 = P[e*3+1], c2 = P[e*3+2];
  if (lane < Kk) {
    int idx = IDX[e*Kk + lane] & (Nn-1);
    const float* pn = P + (b*Nn + idx)*3;
    dC[lane*4+0] = __fsub_rn(pn[0], c0);
    dC[lane*4+1] = __fsub_rn(pn[1], c1);
    dC[lane*4+2] = __fsub_rn(pn[2], c2);
  }
  __syncthreads();
  float w10 = W1T[0*64+lane], w11 = W1T[1*64+lane], w12 = W1T[2*64+lane];
  float w13 = W1T[3*64+lane], w14 = W1T[4*64+lane], w15 = W1T[5*64+lane];
  float p3 = __fmul_rn(w13,c0), p4 = __fmul_rn(w14,c1), p5 = __fmul_rn(w15,c2);
  float s1 = __fdiv_rn(g1[lane], __fsqrt_rn(1.0f + 1e-5f));
  float o1 = b1[lane];
  for (int k=0;k<Kk;++k){
    float t = __fmul_rn(w10, dC[k*4+0]);
    t = __fadd_rn(t, __fmul_rn(w11, dC[k*4+1]));
    t = __fadd_rn(t, __fmul_rn(w12, dC[k*4+2]));
    t = __fadd_rn(t, p3); t = __fadd_rn(t, p4); t = __fadd_rn(t, p5);
    float y = __fadd_rn(__fmul_rn(t, s1), o1);
    y = (y >= 0.0f) ? y : __fmul_rn(0.2f, y);
    y1L[lane*44+k] = y;
  }
  __syncthreads();
  float4 q[10];
  #pragma unroll
  for (int k4=0;k4<10;++k4) q[k4] = make_float4(0.f,0.f,0.f,0.f);
  for (int i=0;i<64;++i){
    float w = W2T[i*64+lane];
    const float4* yp = (const float4*)&y1L[i*44];
    #pragma unroll
    for (int k4=0;k4<10;++k4){
      float4 yv = yp[k4];
      q[k4].x = __fadd_rn(q[k4].x, __fmul_rn(w, yv.x));
      q[k4].y = __fadd_rn(q[k4].y, __fmul_rn(w, yv.y));
      q[k4].z = __fadd_rn(q[k4].z, __fmul_rn(w, yv.z));
      q[k4].w = __fadd_rn(q[k4].w, __fmul_rn(w, yv.w));
    }
  }
  float s2 = __fdiv_rn(g2[lane], __fsqrt_rn(1.0f + 1e-5f));
  float o2 = b2[lane];
  float mx = -__builtin_inff();
  #pragma unroll
  for (int k4=0;k4<10;++k4){
    float vs[4] = {q[k4].x, q[k4].y, q[k4].z, q[k4].w};
    #pragma unroll
    for (int j=0;j<4;++j){
      float y = __fadd_rn(__fmul_rn(vs[j], s2), o2);
      y = (y >= 0.0f) ? y : __fmul_rn(0.2f, y);
      mx = fmaxf(mx, y);
    }
  }
  X1T[e*64 + lane] = mx;
}

__global__ __launch_bounds__(256) void k_xx2(const float* __restrict__ X1T, float* __restrict__ XX2){
  int e = blockIdx.x*256 + threadIdx.x;
  const float* r = X1T + e*64;
  float a = 0.f;
  for (int c=0;c<64;++c) a = __fadd_rn(a, __fmul_rn(r[c], r[c]));
  XX2[e] = a;
}

// ---------------- knn on 64-D features: channel-major coalesced reads ----------------
__global__ __launch_bounds__(256) void k_knn2(const float* __restrict__ X1C, const float* __restrict__ XX2,
                                              int* __restrict__ IDX){
  int blk = blockIdx.x;
  int b = blk >> 9;
  int w = threadIdx.x >> 6, lane = threadIdx.x & 63;
  int n = (blk & 511)*4 + w;
  __shared__ float qL[4*64];
  { int t = threadIdx.x; int ww = t >> 6, c = t & 63;
    int nn = (blk & 511)*4 + ww;
    qL[t] = X1C[b*HS + c*Nn + nn]; }
  __syncthreads();
  const float* xb = XX2 + b*Nn;
  float4 a4[8];
  #pragma unroll
  for (int j=0;j<8;++j) a4[j] = make_float4(0.f,0.f,0.f,0.f);
  for (int c=0;c<64;++c){
    float qc = qL[w*64 + c];
    const float4* row = (const float4*)(X1C + b*HS + c*Nn);
    #pragma unroll
    for (int j=0;j<8;++j){
      float4 v = row[j*64 + lane];
      a4[j].x = __fadd_rn(a4[j].x, __fmul_rn(qc, v.x));
      a4[j].y = __fadd_rn(a4[j].y, __fmul_rn(qc, v.y));
      a4[j].z = __fadd_rn(a4[j].z, __fmul_rn(qc, v.z));
      a4[j].w = __fadd_rn(a4[j].w, __fmul_rn(qc, v.w));
    }
  }
  float xn = xb[n];
  float d[32];
  #pragma unroll
  for (int j=0;j<8;++j){
    float4 xm = ((const float4*)xb)[j*64 + lane];
    d[j*4+0] = __fsub_rn(__fsub_rn(__fmul_rn(2.0f, a4[j].x), xn), xm.x);
    d[j*4+1] = __fsub_rn(__fsub_rn(__fmul_rn(2.0f, a4[j].y), xn), xm.y);
    d[j*4+2] = __fsub_rn(__fsub_rn(__fmul_rn(2.0f, a4[j].z), xn), xm.z);
    d[j*4+3] = __fsub_rn(__fsub_rn(__fmul_rn(2.0f, a4[j].w), xn), xm.w);
  }
  wave_top40_g(d, lane, IDX + (b*Nn+n)*Kk);
}

// ---------------- edge conv 3+4 + maxpool (fma ok) ----------------
__global__ __launch_bounds__(64) void k_ec2(const float* __restrict__ X1T, const int* __restrict__ IDX,
                                            const float* __restrict__ W3T, const float* __restrict__ W4T,
                                            const float* __restrict__ g3, const float* __restrict__ b3,
                                            const float* __restrict__ g4, const float* __restrict__ b4,
                                            float* __restrict__ X2T){
  int e = blockIdx.x; int b = e >> 11; int lane = threadIdx.x;
  __shared__ __align__(16) float dL[64*44];
  __shared__ float ctrL[64];
  float ctr = X1T[e*64 + lane];
  ctrL[lane] = ctr;
  __syncthreads();
  for (int k=0;k<Kk;++k){
    int idx = IDX[e*Kk + k] & (Nn-1);
    dL[lane*44 + k] = X1T[(b*Nn+idx)*64 + lane] - ctr;
  }
  __syncthreads();
  float base = 0.f;
  for (int i=0;i<64;++i) base = fmaf(W3T[(64+i)*64 + lane], ctrL[i], base);
  float4 q[10];
  #pragma unroll
  for (int k4=0;k4<10;++k4) q[k4] = make_float4(base,base,base,base);
  for (int i=0;i<64;++i){
    float w = W3T[i*64 + lane];
    const float4* dp = (const float4*)&dL[i*44];
    #pragma unroll
    for (int k4=0;k4<10;++k4){
      float4 d = dp[k4];
      q[k4].x = fmaf(w, d.x, q[k4].x);
      q[k4].y = fmaf(w, d.y, q[k4].y);
      q[k4].z = fmaf(w, d.z, q[k4].z);
      q[k4].w = fmaf(w, d.w, q[k4].w);
    }
  }
  float s3 = g3[lane] / sqrtf(1.0f+1e-5f);
  float o3 = b3[lane];
  __syncthreads();
  #pragma unroll
  for (int k4=0;k4<10;++k4){
    float4 y;
    y.x = q[k4].x*s3 + o3; y.x = (y.x>=0.f)?y.x:0.2f*y.x;
    y.y = q[k4].y*s3 + o3; y.y = (y.y>=0.f)?y.y:0.2f*y.y;
    y.z = q[k4].z*s3 + o3; y.z = (y.z>=0.f)?y.z:0.2f*y.z;
    y.w = q[k4].w*s3 + o3; y.w = (y.w>=0.f)?y.w:0.2f*y.w;
    *(float4*)&dL[lane*44 + k4*4] = y;
  }
  __syncthreads();
  float4 p[10];
  #pragma unroll
  for (int k4=0;k4<10;++k4) p[k4] = make_float4(0.f,0.f,0.f,0.f);
  for (int i=0;i<64;++i){
    float w = W4T[i*64 + lane];
    const float4* yp = (const float4*)&dL[i*44];
    #pragma unroll
    for (int k4=0;k4<10;++k4){
      float4 yv = yp[k4];
      p[k4].x = fmaf(w, yv.x, p[k4].x);
      p[k4].y = fmaf(w, yv.y, p[k4].y);
      p[k4].z = fmaf(w, yv.z, p[k4].z);
      p[k4].w = fmaf(w, yv.w, p[k4].w);
    }
  }
  float s4 = g4[lane] / sqrtf(1.0f+1e-5f);
  float o4 = b4[lane];
  float mx = -__builtin_inff();
  #pragma unroll
  for (int k4=0;k4<10;++k4){
    float vs[4] = {p[k4].x, p[k4].y, p[k4].z, p[k4].w};
    #pragma unroll
    for (int j=0;j<4;++j){
      float y = vs[j]*s4 + o4;
      y = (y>=0.f)?y:0.2f*y;
      mx = fmaxf(mx, y);
    }
  }
  X2T[e*64 + lane] = mx;
}

// (b,n,64) -> (b,c,n); dst pre-offset by channel base; dst batch stride = HS
__global__ __launch_bounds__(256) void k_tr(const float* __restrict__ src, float* __restrict__ dst){
  int b = blockIdx.x >> 5; int n0 = (blockIdx.x & 31) << 6;
  __shared__ float t[64*65];
  for (int e=threadIdx.x; e<4096; e+=256){
    int r = e >> 6, c = e & 63;
    t[r*65+c] = src[(b*Nn + n0 + r)*64 + c];
  }
  __syncthreads();
  for (int e=threadIdx.x; e<4096; e+=256){
    int c = e >> 6, r = e & 63;
    dst[b*HS + c*Nn + n0 + r] = t[r*65+c];
  }
}

// ---------------- SA layer ----------------
__global__ __launch_bounds__(256) void k_sa_a(const float* __restrict__ IN,
                                              const float* __restrict__ QKw, const float* __restrict__ Vw,
                                              const float* __restrict__ Vb,
                                              float* __restrict__ QX, float* __restrict__ XV){
  int b = blockIdx.x >> 5; int n0 = (blockIdx.x & 31) << 6;
  int w = threadIdx.x >> 6, lane = threadIdx.x & 63;
  __shared__ float xl[128*64];
  for (int e=threadIdx.x; e<8192; e+=256){
    int c = e >> 6, j = e & 63;
    xl[e] = IN[b*HS + c*Nn + n0 + j];
  }
  __syncthreads();
  for (int jj=0;jj<8;++jj){
    int o = w*8 + jj;
    const float4* wp = (const float4*)(QKw + o*128);
    float a = 0.f;
    #pragma unroll
    for (int c4=0;c4<32;++c4){
      float4 wv = wp[c4];
      a = fmaf(wv.x, xl[(c4*4+0)*64 + lane], a);
      a = fmaf(wv.y, xl[(c4*4+1)*64 + lane], a);
      a = fmaf(wv.z, xl[(c4*4+2)*64 + lane], a);
      a = fmaf(wv.w, xl[(c4*4+3)*64 + lane], a);
    }
    QX[(b*32+o)*Nn + n0 + lane] = a;
  }
  for (int jj=0;jj<32;++jj){
    int o = w*32 + jj;
    const float4* wp = (const float4*)(Vw + o*128);
    float a = 0.f;
    #pragma unroll
    for (int c4=0;c4<32;++c4){
      float4 wv = wp[c4];
      a = fmaf(wv.x, xl[(c4*4+0)*64 + lane], a);
      a = fmaf(wv.y, xl[(c4*4+1)*64 + lane], a);
      a = fmaf(wv.z, xl[(c4*4+2)*64 + lane], a);
      a = fmaf(wv.w, xl[(c4*4+3)*64 + lane], a);
    }
    XV[(b*128+o)*Nn + n0 + lane] = a + Vb[o];
  }
}

// m-split x8: grid 512 = b(8) x nc(8) x mc(8)
__global__ __launch_bounds__(256) void k_sa_b(const float* __restrict__ QX,
                                              float* __restrict__ RMP, float* __restrict__ RSP){
  int blk = blockIdx.x;
  int b = blk >> 6, sub = blk & 63;
  int ncn = sub >> 3, mcn = sub & 7;
  int n = ncn*256 + threadIdx.x;
  float q[32];
  #pragma unroll
  for (int o=0;o<32;++o) q[o] = QX[(b*32+o)*Nn + n];
  __shared__ float qt[32*128];
  float mr = -__builtin_inff(), lr = 0.f;
  int m0 = mcn*256;
  for (int t=0;t<2;++t){
    for (int e=threadIdx.x; e<4096; e+=256){
      int o = e >> 7, mm = e & 127;
      qt[e] = QX[(b*32+o)*Nn + m0 + t*128 + mm];
    }
    __syncthreads();
    for (int mm=0;mm<128;mm+=2){
      float e0=0.f, e1=0.f;
      #pragma unroll
      for (int o=0;o<32;++o){ float qo=q[o]; e0=fmaf(qo, qt[o*128+mm], e0); e1=fmaf(qo, qt[o*128+mm+1], e1); }
      if (e0 > mr){ lr = lr*expf(mr-e0) + 1.f; mr = e0; } else lr += expf(e0-mr);
      if (e1 > mr){ lr = lr*expf(mr-e1) + 1.f; mr = e1; } else lr += expf(e1-mr);
    }
    __syncthreads();
  }
  RMP[(b*Nn+n)*8 + mcn] = mr;
  RSP[(b*Nn+n)*8 + mcn] = lr;
}

__global__ __launch_bounds__(256) void k_sa_b2(const float* __restrict__ RMP, const float* __restrict__ RSP,
                                               float* __restrict__ RMX, float* __restrict__ RSM){
  int e = blockIdx.x*256 + threadIdx.x;
  float M = -__builtin_inff();
  #pragma unroll
  for (int i=0;i<8;++i) M = fmaxf(M, RMP[e*8+i]);
  float l = 0.f;
  #pragma unroll
  for (int i=0;i<8;++i) l += RSP[e*8+i]*expf(RMP[e*8+i]-M);
  RMX[e] = M; RSM[e] = l;
}

// LDS map (floats): QM[32o][32m]=1024 @0, QN[32o][32n]=1024 @1024,
// XVt[32n][132]=4224 @2048, SL[32n][32m]=1024 @6272, MX@7296, RL@7328.
#define SM_QM 0
#define SM_QN 1024
#define SM_XV 2048
#define SM_SL 6272
#define SM_MX 7296
#define SM_RL 7328

// main: grid 1024 = b(8) x mt(64) x part(2); n-range split in 2; writes PV and
// column-sum partials to PP/CSP. (p0+p1 recombined in k_sa_cc; fp add is
// commutative so result is deterministic.)
__global__ __launch_bounds__(256) void k_sa_cm(const float* __restrict__ QX, const float* __restrict__ XV,
                                               const float* __restrict__ RMAX, const float* __restrict__ RSUM,
                                               float* __restrict__ PP, float* __restrict__ CSP){
  int blk = blockIdx.x;
  int part = blk & 1, mt = (blk >> 1) & 63, b = blk >> 7;
  int m0 = mt << 5;
  int tid = threadIdx.x;
  int nnp = tid >> 4, mmp = tid & 15;      // 2x2 S-microtile owner
  int tc = tid >> 3, tm8 = tid & 7;        // PV owner: c=tc*4+ci, m=tm8*4+mi
  __shared__ __align__(16) float sm[7360];
  for (int e=tid; e<1024; e+=256){
    int o = e >> 5, mm = e & 31;
    sm[SM_QM + e] = QX[(b*32+o)*Nn + m0 + mm];
  }
  float acc[4][4];
  #pragma unroll
  for (int ci=0;ci<4;++ci){
    #pragma unroll
    for (int mi=0;mi<4;++mi) acc[ci][mi] = 0.f;
  }
  float csr = 0.f;
  int it0 = part*32;
  for (int it=it0; it<it0+32; ++it){
    int nb = it*32;
    __syncthreads();
    for (int e=tid; e<1024; e+=256){ int o=e>>5, nn=e&31; sm[SM_QN+e] = QX[(b*32+o)*Nn + nb + nn]; }
    for (int e=tid; e<4096; e+=256){ int c=e>>5, nn=e&31; sm[SM_XV + nn*132 + c] = XV[(b*128+c)*Nn + nb + nn]; }
    if (tid < 32){ sm[SM_MX+tid] = RMAX[b*Nn + nb + tid]; sm[SM_RL+tid] = 1.0f / RSUM[b*Nn + nb + tid]; }
    __syncthreads();
    float e00=0.f, e01=0.f, e10=0.f, e11=0.f;
    #pragma unroll
    for (int o=0;o<32;++o){
      float2 qn = *(const float2*)&sm[SM_QN + o*32 + nnp*2];
      float2 qm = *(const float2*)&sm[SM_QM + o*32 + mmp*2];
      e00 = fmaf(qn.x, qm.x, e00);
      e01 = fmaf(qn.x, qm.y, e01);
      e10 = fmaf(qn.y, qm.x, e10);
      e11 = fmaf(qn.y, qm.y, e11);
    }
    float mx0 = sm[SM_MX + nnp*2],   rl0 = sm[SM_RL + nnp*2];
    float mx1 = sm[SM_MX + nnp*2+1], rl1 = sm[SM_RL + nnp*2+1];
    float2 s0; s0.x = expf(e00-mx0)*rl0; s0.y = expf(e01-mx0)*rl0;
    float2 s1; s1.x = expf(e10-mx1)*rl1; s1.y = expf(e11-mx1)*rl1;
    *(float2*)&sm[SM_SL + (nnp*2  )*32 + mmp*2] = s0;
    *(float2*)&sm[SM_SL + (nnp*2+1)*32 + mmp*2] = s1;
    __syncthreads();
    if (tid < 32){
      #pragma unroll
      for (int nn=0;nn<32;++nn) csr += sm[SM_SL + nn*32 + tid];
    }
    #pragma unroll 8
    for (int nn=0;nn<32;++nn){
      float4 xv4 = *(const float4*)&sm[SM_XV + nn*132 + tc*4];
      float4 s4  = *(const float4*)&sm[SM_SL + nn*32  + tm8*4];
      acc[0][0] = fmaf(xv4.x, s4.x, acc[0][0]);
      acc[0][1] = fmaf(xv4.x, s4.y, acc[0][1]);
      acc[0][2] = fmaf(xv4.x, s4.z, acc[0][2]);
      acc[0][3] = fmaf(xv4.x, s4.w, acc[0][3]);
      acc[1][0] = fmaf(xv4.y, s4.x, acc[1][0]);
      acc[1][1] = fmaf(xv4.y, s4.y, acc[1][1]);
      acc[1][2] = fmaf(xv4.y, s4.z, acc[1][2]);
      acc[1][3] = fmaf(xv4.y, s4.w, acc[1][3]);
      acc[2][0] = fmaf(xv4.z, s4.x, acc[2][0]);
      acc[2][1] = fmaf(xv4.z, s4.y, acc[2][1]);
      acc[2][2] = fmaf(xv4.z, s4.z, acc[2][2]);
      acc[2][3] = fmaf(xv4.z, s4.w, acc[2][3]);
      acc[3][0] = fmaf(xv4.w, s4.x, acc[3][0]);
      acc[3][1] = fmaf(xv4.w, s4.y, acc[3][1]);
      acc[3][2] = fmaf(xv4.w, s4.z, acc[3][2]);
      acc[3][3] = fmaf(xv4.w, s4.w, acc[3][3]);
    }
  }
  int slot = (b*64 + mt)*2 + part;
  #pragma unroll
  for (int ci=0;ci<4;++ci){
    int c = tc*4 + ci;
    *(float4*)&PP[slot*4096 + c*32 + tm8*4] =
      make_float4(acc[ci][0], acc[ci][1], acc[ci][2], acc[ci][3]);
  }
  if (tid < 32) CSP[slot*32 + tid] = csr;
}

// combine + transform epilogue: grid 512 = b(8) x mt(64). In-place on h.
__global__ __launch_bounds__(256) void k_sa_cc(const float* IN,
                                               const float* __restrict__ PP, const float* __restrict__ CSP,
                                               const float* __restrict__ Tw, const float* __restrict__ Tb,
                                               const float* __restrict__ Gs, const float* __restrict__ Bs,
                                               float* OUT){
  int blk = blockIdx.x;
  int mt = blk & 63, b = blk >> 6;
  int m0 = mt << 5;
  int tid = threadIdx.x;
  int tc = tid >> 3, tm8 = tid & 7;
  __shared__ __align__(16) float sm[4128];   // DL[128][32] @0, CS[32] @4096
  int s0 = (b*64 + mt)*2, s1 = s0 + 1;
  if (tid < 32) sm[4096 + tid] = CSP[s0*32 + tid] + CSP[s1*32 + tid];
  __syncthreads();
  #pragma unroll
  for (int ci=0;ci<4;++ci){
    int c = tc*4 + ci;
    float4 p0 = *(const float4*)&PP[s0*4096 + c*32 + tm8*4];
    float4 p1 = *(const float4*)&PP[s1*4096 + c*32 + tm8*4];
    float am[4] = {p0.x+p1.x, p0.y+p1.y, p0.z+p1.z, p0.w+p1.w};
    #pragma unroll
    for (int mi=0;mi<4;++mi){
      int ml = tm8*4 + mi;
      float cs = sm[4096 + ml];
      float xr = am[mi] / (1e-9f + cs);
      sm[c*32 + ml] = IN[b*HS + c*Nn + m0 + ml] - xr;
    }
  }
  __syncthreads();
  int hw = tid >> 5, m = tid & 31;
  float sroot = sqrtf(1.0f + 1e-5f);
  for (int oo=0; oo<16; ++oo){
    int o = oo*8 + hw;
    const float4* twp = (const float4*)(Tw + o*128);
    float a = 0.f;
    #pragma unroll
    for (int c4=0;c4<32;++c4){
      float4 wv = twp[c4];
      a = fmaf(wv.x, sm[(c4*4+0)*32 + m], a);
      a = fmaf(wv.y, sm[(c4*4+1)*32 + m], a);
      a = fmaf(wv.z, sm[(c4*4+2)*32 + m], a);
      a = fmaf(wv.w, sm[(c4*4+3)*32 + m], a);
    }
    a += Tb[o];
    float y = a * (Gs[o] / sroot) + Bs[o];
    y = fmaxf(y, 0.f);
    OUT[b*HS + o*Nn + m0 + m] = IN[b*HS + o*Nn + m0 + m] + y;
  }
}

// ---------------- progressive fuse: ACC += FW[:, l*128:(l+1)*128] * h_l ----------------
__global__ __launch_bounds__(256) void k_fuse_part(const float* __restrict__ Hc, const float* __restrict__ FWT,
                                                   float* __restrict__ ACC, int l, int init){
  int b = blockIdx.x >> 5; int n0 = (blockIdx.x & 31) << 6;
  int w = threadIdx.x >> 6, lane = threadIdx.x & 63;
  __shared__ float xt[128*64];
  for (int e=threadIdx.x; e<8192; e+=256){
    int c = e >> 6, j = e & 63;
    xt[e] = Hc[(b*128 + c)*Nn + n0 + j];
  }
  __syncthreads();
  float4 a[16];
  #pragma unroll
  for (int j=0;j<16;++j) a[j] = make_float4(0.f,0.f,0.f,0.f);
  for (int c=0;c<128;++c){
    float xv = xt[c*64 + lane];
    const float4* wr = (const float4*)(FWT + (l*128+c)*256 + w*64);
    #pragma unroll
    for (int j4=0;j4<16;++j4){
      float4 wv = wr[j4];
      a[j4].x = fmaf(wv.x, xv, a[j4].x);
      a[j4].y = fmaf(wv.y, xv, a[j4].y);
      a[j4].z = fmaf(wv.z, xv, a[j4].z);
      a[j4].w = fmaf(wv.w, xv, a[j4].w);
    }
  }
  #pragma unroll
  for (int j4=0;j4<16;++j4){
    float vs[4] = {a[j4].x, a[j4].y, a[j4].z, a[j4].w};
    #pragma unroll
    for (int qq=0;qq<4;++qq){
      int o = w*64 + j4*4 + qq;
      int idx = (b*256 + o)*Nn + n0 + lane;
      if (init) ACC[idx] = vs[qq];
      else      ACC[idx] = ACC[idx] + vs[qq];
    }
  }
}

// ---------------- final epilogue: in-place BN + leaky-ReLU on d_out ----------------
__global__ __launch_bounds__(256) void k_fin(float* __restrict__ ACC,
                                             const float* __restrict__ FGF, const float* __restrict__ FBF){
  int e = blockIdx.x*256 + threadIdx.x;    // 4,194,304 entries
  int o = (e >> 11) & 255;
  float sroot = sqrtf(1.0f + 1e-5f);
  float y = ACC[e] * (FGF[o] / sroot) + FBF[o];
  y = (y >= 0.f) ? y : 0.2f*y;
  ACC[e] = y;
}

extern "C" void kernel_launch(void* const* d_in, const int* in_sizes, int n_in,
                              void* d_out, int out_size, void* d_ws, size_t ws_size,
                              hipStream_t stream) {
  const float* X   = (const float*)d_in[0];
  const float* w1  = (const float*)d_in[1];
  const float* g1  = (const float*)d_in[2];
  const float* b1  = (const float*)d_in[3];
  const float* w2  = (const float*)d_in[4];
  const float* g2  = (const float*)d_in[5];
  const float* b2_ = (const float*)d_in[6];
  const float* w3  = (const float*)d_in[7];
  const float* g3  = (const float*)d_in[8];
  const float* b3  = (const float*)d_in[9];
  const float* w4  = (const float*)d_in[10];
  const float* g4  = (const float*)d_in[11];
  const float* b4  = (const float*)d_in[12];
  // d_in[13..15] = w5/g5/b5 : unused by reference
  const float* qk  = (const float*)d_in[16];
  const float* sv  = (const float*)d_in[17];
  const float* svb = (const float*)d_in[18];
  const float* st  = (const float*)d_in[19];
  const float* stb = (const float*)d_in[20];
  const float* sg  = (const float*)d_in[21];
  const float* sb  = (const float*)d_in[22];
  const float* fw  = (const float*)d_in[23];
  const float* fg  = (const float*)d_in[24];
  const float* fb  = (const float*)d_in[25];

  float* ws = (float*)d_ws;
  float* H    = ws + 0;          // 2,097,152
  float* QXb  = ws + 2097152;    //   524,288
  float* XVb  = ws + 2621440;    // 2,097,152 (ends 4,718,592)
  float* RMP  = ws + 4718592;    //   131,072
  float* RSP  = ws + 4849664;    //   131,072
  float* RMX  = ws + 4980736;    //    16,384
  float* RSM  = ws + 4997120;    //    16,384 (ends 5,013,504)
  // phase-1 overlay on [2,097,152 .. 4,915,200) — dead before SA phase:
  float* XX   = ws + 2146304;
  int*   IDX  = (int*)(ws + 2162688);
  float* X1T  = ws + 2818048;
  float* X2T  = ws + 3866624;    // ends 4,915,200 (< 5,013,504, no clash with C0)
  float* C0   = ws + 5013504;
  float* W1T = C0 + 0;
  float* W2T = C0 + 384;
  float* W3T = C0 + 4480;
  float* W4T = C0 + 12672;
  float* FWT = C0 + 16768;       // C0 ends 5,161,344
  float* PP  = ws + 5161344;     // 4,194,304 (PV partials: 1024 slots x 4096)
  float* CSP = ws + 9355648;     //    32,768 (col-sum partials) — total 9,388,416 fl = 35.8 MiB
  float* ACC = (float*)d_out;

  k_xx1<<<64,256,0,stream>>>(X, XX);
  k_prep_wt<<<578,256,0,stream>>>(w1,w2,w3,w4,fw, W1T,W2T,W3T,W4T,FWT);
  k_knn1<<<4096,256,0,stream>>>(X, XX, IDX);
  k_ec1<<<16384,64,0,stream>>>(X, IDX, W1T, W2T, g1,b1,g2,b2_, X1T);
  k_xx2<<<64,256,0,stream>>>(X1T, XX);
  k_tr<<<256,256,0,stream>>>(X1T, H);                  // X1 -> channel-major (H ch 0..63), BEFORE knn2
  k_knn2<<<4096,256,0,stream>>>(H, XX, IDX);           // coalesced channel-major reads
  k_ec2<<<16384,64,0,stream>>>(X1T, IDX, W3T, W4T, g3,b3,g4,b4, X2T);
  k_tr<<<256,256,0,stream>>>(X2T, H + 64*Nn);

  for (int l=0;l<4;++l){
    k_sa_a<<<256,256,0,stream>>>(H, qk + l*4096, sv + l*16384, svb + l*128, QXb, XVb);
    k_sa_b<<<512,256,0,stream>>>(QXb, RMP, RSP);
    k_sa_b2<<<64,256,0,stream>>>(RMP, RSP, RMX, RSM);
    k_sa_cm<<<1024,256,0,stream>>>(QXb, XVb, RMX, RSM, PP, CSP);
    k_sa_cc<<<512,256,0,stream>>>(H, PP, CSP,
                                  st + l*16384, stb + l*128, sg + l*128, sb + l*128, H);
    k_fuse_part<<<256,256,0,stream>>>(H, FWT, ACC, l, (l==0)?1:0);
  }
  k_fin<<<16384,256,0,stream>>>(ACC, fg, fb);
}

// Round 9
// 2682.054 us; speedup vs baseline: 9.2461x; 1.1341x over previous
//
#include <hip/hip_runtime.h>

#define Bb 8
#define Nn 2048
#define Kk 40
#define HS (128*Nn)   // h stride per batch (channel-major [b,128,2048])

// monotone float->uint transform: a > b  <=>  f2o(a) > f2o(b)
__device__ __forceinline__ unsigned f2o(float f){
  unsigned u = __float_as_uint(f);
  return (u & 0x80000000u) ? ~u : (u | 0x80000000u);
}

// Wave-cooperative exact top-40 of 2048, grouped rescan (4 groups of 8 slots).
// Lane owns m = slot*64+lane. Per round only the winner lane rescans its group;
// selection order identical to a full linear scan (value desc, index asc).
__device__ __forceinline__ void wave_top40(float* d, int lane, int* op){
  float gv[4]; int gs[4];
  #pragma unroll
  for (int g=0; g<4; ++g){
    float bv = d[g*8]; int bs = g*8;
    #pragma unroll
    for (int j=1;j<8;++j){
      float v = d[g*8+j];
      if (v > bv){ bv = v; bs = g*8+j; }
    }
    gv[g]=bv; gs[g]=bs;
  }
  for (int t=0; t<Kk; ++t){
    float bv = gv[0]; int bs = gs[0];
    if (gv[1] > bv){ bv=gv[1]; bs=gs[1]; }
    if (gv[2] > bv){ bv=gv[2]; bs=gs[2]; }
    if (gv[3] > bv){ bv=gv[3]; bs=gs[3]; }
    int bm = bs*64 + lane;
    unsigned long long key = ((unsigned long long)f2o(bv) << 32) | (unsigned)(~bm);
    #pragma unroll
    for (int s=32;s>0;s>>=1){
      unsigned long long o = __shfl_xor(key, s, 64);
      if (o > key) key = o;
    }
    int wm = (int)(~(unsigned)key);
    if (lane == 0) op[t] = wm;
    bool mine = ((wm & 63) == lane);
    int wsl = wm >> 6;
    if (mine){
      int G = wsl >> 3;
      #pragma unroll
      for (int g=0; g<4; ++g){
        if (g == G){
          float nv = -__builtin_inff(); int ns = g*8;
          #pragma unroll
          for (int j=0;j<8;++j){
            float v = d[g*8+j];
            if (g*8+j == wsl) v = -__builtin_inff();
            d[g*8+j] = v;
            if (v > nv){ nv=v; ns=g*8+j; }
          }
          gv[g]=nv; gs[g]=ns;
        }
      }
    }
  }
}

// Variant for mapping m = (s>>2)*256 + lane*4 + (s&3) (coalesced float4 ownership).
// Within a lane m is increasing in s, so the same grouped tie-break is exact.
__device__ __forceinline__ void wave_top40_g(float* d, int lane, int* op){
  float gv[4]; int gs[4];
  #pragma unroll
  for (int g=0; g<4; ++g){
    float bv = d[g*8]; int bs = g*8;
    #pragma unroll
    for (int j=1;j<8;++j){
      float v = d[g*8+j];
      if (v > bv){ bv = v; bs = g*8+j; }
    }
    gv[g]=bv; gs[g]=bs;
  }
  for (int t=0; t<Kk; ++t){
    float bv = gv[0]; int bs = gs[0];
    if (gv[1] > bv){ bv=gv[1]; bs=gs[1]; }
    if (gv[2] > bv){ bv=gv[2]; bs=gs[2]; }
    if (gv[3] > bv){ bv=gv[3]; bs=gs[3]; }
    int bm = ((bs>>2)<<8) + lane*4 + (bs&3);
    unsigned long long key = ((unsigned long long)f2o(bv) << 32) | (unsigned)(~bm);
    #pragma unroll
    for (int s=32;s>0;s>>=1){
      unsigned long long o = __shfl_xor(key, s, 64);
      if (o > key) key = o;
    }
    int wm = (int)(~(unsigned)key);
    if (lane == 0) op[t] = wm;
    bool mine = (((wm>>2) & 63) == lane);
    int wsl = ((wm>>8)<<2) | (wm & 3);
    if (mine){
      int G = wsl >> 3;
      #pragma unroll
      for (int g=0; g<4; ++g){
        if (g == G){
          float nv = -__builtin_inff(); int ns = g*8;
          #pragma unroll
          for (int j=0;j<8;++j){
            float v = d[g*8+j];
            if (g*8+j == wsl) v = -__builtin_inff();
            d[g*8+j] = v;
            if (v > nv){ nv=v; ns=g*8+j; }
          }
          gv[g]=nv; gs[g]=ns;
        }
      }
    }
  }
}

// ---------------- prep ----------------
__global__ __launch_bounds__(256) void k_xx1(const float* __restrict__ x, float* __restrict__ XX){
  int e = blockIdx.x*256 + threadIdx.x;
  if (e >= Bb*Nn) return;
  float p0 = x[e*3+0], p1 = x[e*3+1], p2 = x[e*3+2];
  XX[e] = __fadd_rn(__fadd_rn(__fmul_rn(p0,p0), __fmul_rn(p1,p1)), __fmul_rn(p2,p2));
}

__global__ __launch_bounds__(256) void k_prep_wt(const float* __restrict__ w1, const float* __restrict__ w2,
                                                 const float* __restrict__ w3, const float* __restrict__ w4,
                                                 const float* __restrict__ fw,
                                                 float* __restrict__ W1T, float* __restrict__ W2T,
                                                 float* __restrict__ W3T, float* __restrict__ W4T,
                                                 float* __restrict__ FWT){
  int e = blockIdx.x*256 + threadIdx.x;
  if (e < 384)   { int i=e/64,  c=e%64;  W1T[e] = w1[c*6+i];    return; } e -= 384;
  if (e < 4096)  { int i=e/64,  c=e%64;  W2T[e] = w2[c*64+i];   return; } e -= 4096;
  if (e < 8192)  { int i=e/64,  c=e%64;  W3T[e] = w3[c*128+i];  return; } e -= 8192;
  if (e < 4096)  { int i=e/64,  c=e%64;  W4T[e] = w4[c*64+i];   return; } e -= 4096;
  if (e < 131072){ int i=e/256, o=e%256; FWT[e] = fw[o*512+i];  return; }
}

// ---------------- knn on 3-D points: 1 wave / query, LDS-staged cloud ----------------
__global__ __launch_bounds__(256) void k_knn1(const float* __restrict__ P, const float* __restrict__ XX,
                                              int* __restrict__ IDX){
  int blk = blockIdx.x;
  int b = blk >> 9;
  int w = threadIdx.x >> 6, lane = threadIdx.x & 63;
  int n = (blk & 511)*4 + w;
  const float* Pb = P + b*Nn*3;
  const float* xb = XX + b*Nn;
  __shared__ float Pl[Nn*3];
  __shared__ float Xl[Nn];
  for (int e = threadIdx.x; e < Nn*3; e += 256) Pl[e] = Pb[e];
  for (int e = threadIdx.x; e < Nn; e += 256) Xl[e] = xb[e];
  __syncthreads();
  float c0 = Pl[n*3+0], c1 = Pl[n*3+1], c2 = Pl[n*3+2];
  float xn = Xl[n];
  float d[32];
  #pragma unroll
  for (int j=0;j<32;++j){
    int m = j*64 + lane;
    float a0 = Pl[m*3+0], a1 = Pl[m*3+1], a2 = Pl[m*3+2];
    float in_ = __fadd_rn(__fadd_rn(__fmul_rn(c0,a0), __fmul_rn(c1,a1)), __fmul_rn(c2,a2));
    d[j] = __fsub_rn(__fsub_rn(__fmul_rn(2.0f,in_), xn), Xl[m]);
  }
  wave_top40(d, lane, IDX + (b*Nn+n)*Kk);
}

// ---------------- edge conv 1+2 + maxpool (bit-exact _rn path) ----------------
__global__ __launch_bounds__(64) void k_ec1(const float* __restrict__ P, const int* __restrict__ IDX,
                                            const float* __restrict__ W1T, const float* __restrict__ W2T,
                                            const float* __restrict__ g1, const float* __restrict__ b1,
                                            const float* __restrict__ g2, const float* __restrict__ b2,
                                            float* __restrict__ X1T){
  int e = blockIdx.x;           // global point row 0..16383
  int b = e >> 11;
  int lane = threadIdx.x;
  __shared__ float dC[Kk*4];
  __shared__ __align__(16) float y1L[64*44];
  float c0 = P[e*3+0], c1 = P[e*3+1], c2 = P[e*3+2];
  if (lane < Kk) {
    int idx = IDX[e*Kk + lane] & (Nn-1);
    const float* pn = P + (b*Nn + idx)*3;
    dC[lane*4+0] = __fsub_rn(pn[0], c0);
    dC[lane*4+1] = __fsub_rn(pn[1], c1);
    dC[lane*4+2] = __fsub_rn(pn[2], c2);
  }
  __syncthreads();
  float w10 = W1T[0*64+lane], w11 = W1T[1*64+lane], w12 = W1T[2*64+lane];
  float w13 = W1T[3*64+lane], w14 = W1T[4*64+lane], w15 = W1T[5*64+lane];
  float p3 = __fmul_rn(w13,c0), p4 = __fmul_rn(w14,c1), p5 = __fmul_rn(w15,c2);
  float s1 = __fdiv_rn(g1[lane], __fsqrt_rn(1.0f + 1e-5f));
  float o1 = b1[lane];
  for (int k=0;k<Kk;++k){
    float t = __fmul_rn(w10, dC[k*4+0]);
    t = __fadd_rn(t, __fmul_rn(w11, dC[k*4+1]));
    t = __fadd_rn(t, __fmul_rn(w12, dC[k*4+2]));
    t = __fadd_rn(t, p3); t = __fadd_rn(t, p4); t = __fadd_rn(t, p5);
    float y = __fadd_rn(__fmul_rn(t, s1), o1);
    y = (y >= 0.0f) ? y : __fmul_rn(0.2f, y);
    y1L[lane*44+k] = y;
  }
  __syncthreads();
  float4 q[10];
  #pragma unroll
  for (int k4=0;k4<10;++k4) q[k4] = make_float4(0.f,0.f,0.f,0.f);
  for (int i=0;i<64;++i){
    float w = W2T[i*64+lane];
    const float4* yp = (const float4*)&y1L[i*44];
    #pragma unroll
    for (int k4=0;k4<10;++k4){
      float4 yv = yp[k4];
      q[k4].x = __fadd_rn(q[k4].x, __fmul_rn(w, yv.x));
      q[k4].y = __fadd_rn(q[k4].y, __fmul_rn(w, yv.y));
      q[k4].z = __fadd_rn(q[k4].z, __fmul_rn(w, yv.z));
      q[k4].w = __fadd_rn(q[k4].w, __fmul_rn(w, yv.w));
    }
  }
  float s2 = __fdiv_rn(g2[lane], __fsqrt_rn(1.0f + 1e-5f));
  float o2 = b2[lane];
  float mx = -__builtin_inff();
  #pragma unroll
  for (int k4=0;k4<10;++k4){
    float vs[4] = {q[k4].x, q[k4].y, q[k4].z, q[k4].w};
    #pragma unroll
    for (int j=0;j<4;++j){
      float y = __fadd_rn(__fmul_rn(vs[j], s2), o2);
      y = (y >= 0.0f) ? y : __fmul_rn(0.2f, y);
      mx = fmaxf(mx, y);
    }
  }
  X1T[e*64 + lane] = mx;
}

__global__ __launch_bounds__(256) void k_xx2(const float* __restrict__ X1T, float* __restrict__ XX2){
  int e = blockIdx.x*256 + threadIdx.x;
  const float* r = X1T + e*64;
  float a = 0.f;
  for (int c=0;c<64;++c) a = __fadd_rn(a, __fmul_rn(r[c], r[c]));
  XX2[e] = a;
}

// ---------------- knn on 64-D features: channel-major coalesced reads ----------------
__global__ __launch_bounds__(256) void k_knn2(const float* __restrict__ X1C, const float* __restrict__ XX2,
                                              int* __restrict__ IDX){
  int blk = blockIdx.x;
  int b = blk >> 9;
  int w = threadIdx.x >> 6, lane = threadIdx.x & 63;
  int n = (blk & 511)*4 + w;
  __shared__ float qL[4*64];
  { int t = threadIdx.x; int ww = t >> 6, c = t & 63;
    int nn = (blk & 511)*4 + ww;
    qL[t] = X1C[b*HS + c*Nn + nn]; }
  __syncthreads();
  const float* xb = XX2 + b*Nn;
  float4 a4[8];
  #pragma unroll
  for (int j=0;j<8;++j) a4[j] = make_float4(0.f,0.f,0.f,0.f);
  for (int c=0;c<64;++c){
    float qc = qL[w*64 + c];
    const float4* row = (const float4*)(X1C + b*HS + c*Nn);
    #pragma unroll
    for (int j=0;j<8;++j){
      float4 v = row[j*64 + lane];
      a4[j].x = __fadd_rn(a4[j].x, __fmul_rn(qc, v.x));
      a4[j].y = __fadd_rn(a4[j].y, __fmul_rn(qc, v.y));
      a4[j].z = __fadd_rn(a4[j].z, __fmul_rn(qc, v.z));
      a4[j].w = __fadd_rn(a4[j].w, __fmul_rn(qc, v.w));
    }
  }
  float xn = xb[n];
  float d[32];
  #pragma unroll
  for (int j=0;j<8;++j){
    float4 xm = ((const float4*)xb)[j*64 + lane];
    d[j*4+0] = __fsub_rn(__fsub_rn(__fmul_rn(2.0f, a4[j].x), xn), xm.x);
    d[j*4+1] = __fsub_rn(__fsub_rn(__fmul_rn(2.0f, a4[j].y), xn), xm.y);
    d[j*4+2] = __fsub_rn(__fsub_rn(__fmul_rn(2.0f, a4[j].z), xn), xm.z);
    d[j*4+3] = __fsub_rn(__fsub_rn(__fmul_rn(2.0f, a4[j].w), xn), xm.w);
  }
  wave_top40_g(d, lane, IDX + (b*Nn+n)*Kk);
}

// ---------------- edge conv 3+4 + maxpool (fma ok) ----------------
__global__ __launch_bounds__(64) void k_ec2(const float* __restrict__ X1T, const int* __restrict__ IDX,
                                            const float* __restrict__ W3T, const float* __restrict__ W4T,
                                            const float* __restrict__ g3, const float* __restrict__ b3,
                                            const float* __restrict__ g4, const float* __restrict__ b4,
                                            float* __restrict__ X2T){
  int e = blockIdx.x; int b = e >> 11; int lane = threadIdx.x;
  __shared__ __align__(16) float dL[64*44];
  __shared__ float ctrL[64];
  float ctr = X1T[e*64 + lane];
  ctrL[lane] = ctr;
  __syncthreads();
  for (int k=0;k<Kk;++k){
    int idx = IDX[e*Kk + k] & (Nn-1);
    dL[lane*44 + k] = X1T[(b*Nn+idx)*64 + lane] - ctr;
  }
  __syncthreads();
  float base = 0.f;
  for (int i=0;i<64;++i) base = fmaf(W3T[(64+i)*64 + lane], ctrL[i], base);
  float4 q[10];
  #pragma unroll
  for (int k4=0;k4<10;++k4) q[k4] = make_float4(base,base,base,base);
  for (int i=0;i<64;++i){
    float w = W3T[i*64 + lane];
    const float4* dp = (const float4*)&dL[i*44];
    #pragma unroll
    for (int k4=0;k4<10;++k4){
      float4 d = dp[k4];
      q[k4].x = fmaf(w, d.x, q[k4].x);
      q[k4].y = fmaf(w, d.y, q[k4].y);
      q[k4].z = fmaf(w, d.z, q[k4].z);
      q[k4].w = fmaf(w, d.w, q[k4].w);
    }
  }
  float s3 = g3[lane] / sqrtf(1.0f+1e-5f);
  float o3 = b3[lane];
  __syncthreads();
  #pragma unroll
  for (int k4=0;k4<10;++k4){
    float4 y;
    y.x = q[k4].x*s3 + o3; y.x = (y.x>=0.f)?y.x:0.2f*y.x;
    y.y = q[k4].y*s3 + o3; y.y = (y.y>=0.f)?y.y:0.2f*y.y;
    y.z = q[k4].z*s3 + o3; y.z = (y.z>=0.f)?y.z:0.2f*y.z;
    y.w = q[k4].w*s3 + o3; y.w = (y.w>=0.f)?y.w:0.2f*y.w;
    *(float4*)&dL[lane*44 + k4*4] = y;
  }
  __syncthreads();
  float4 p[10];
  #pragma unroll
  for (int k4=0;k4<10;++k4) p[k4] = make_float4(0.f,0.f,0.f,0.f);
  for (int i=0;i<64;++i){
    float w = W4T[i*64 + lane];
    const float4* yp = (const float4*)&dL[i*44];
    #pragma unroll
    for (int k4=0;k4<10;++k4){
      float4 yv = yp[k4];
      p[k4].x = fmaf(w, yv.x, p[k4].x);
      p[k4].y = fmaf(w, yv.y, p[k4].y);
      p[k4].z = fmaf(w, yv.z, p[k4].z);
      p[k4].w = fmaf(w, yv.w, p[k4].w);
    }
  }
  float s4 = g4[lane] / sqrtf(1.0f+1e-5f);
  float o4 = b4[lane];
  float mx = -__builtin_inff();
  #pragma unroll
  for (int k4=0;k4<10;++k4){
    float vs[4] = {p[k4].x, p[k4].y, p[k4].z, p[k4].w};
    #pragma unroll
    for (int j=0;j<4;++j){
      float y = vs[j]*s4 + o4;
      y = (y>=0.f)?y:0.2f*y;
      mx = fmaxf(mx, y);
    }
  }
  X2T[e*64 + lane] = mx;
}

// (b,n,64) -> (b,c,n); dst pre-offset by channel base; dst batch stride = HS
__global__ __launch_bounds__(256) void k_tr(const float* __restrict__ src, float* __restrict__ dst){
  int b = blockIdx.x >> 5; int n0 = (blockIdx.x & 31) << 6;
  __shared__ float t[64*65];
  for (int e=threadIdx.x; e<4096; e+=256){
    int r = e >> 6, c = e & 63;
    t[r*65+c] = src[(b*Nn + n0 + r)*64 + c];
  }
  __syncthreads();
  for (int e=threadIdx.x; e<4096; e+=256){
    int c = e >> 6, r = e & 63;
    dst[b*HS + c*Nn + n0 + r] = t[r*65+c];
  }
}

// ---------------- SA layer ----------------
// grid 512 = b(8) x nt(32) x part(2); unified rows: r<32 -> QX row r, else XV row r-32.
__global__ __launch_bounds__(256) void k_sa_a(const float* __restrict__ IN,
                                              const float* __restrict__ QKw, const float* __restrict__ Vw,
                                              const float* __restrict__ Vb,
                                              float* __restrict__ QX, float* __restrict__ XV){
  int blk = blockIdx.x;
  int part = blk & 1; int nt = (blk >> 1) & 31; int b = blk >> 6;
  int n0 = nt << 6;
  int w = threadIdx.x >> 6, lane = threadIdx.x & 63;
  __shared__ float xl[128*64];
  for (int e=threadIdx.x; e<8192; e+=256){
    int c = e >> 6, j = e & 63;
    xl[e] = IN[b*HS + c*Nn + n0 + j];
  }
  __syncthreads();
  for (int i=0;i<20;++i){
    int r = part*80 + w*20 + i;
    const float4* wp4;
    if (r < 32) wp4 = (const float4*)(QKw + r*128);
    else        wp4 = (const float4*)(Vw + (r-32)*128);
    float a = 0.f;
    #pragma unroll
    for (int c4=0;c4<32;++c4){
      float4 wv = wp4[c4];
      a = fmaf(wv.x, xl[(c4*4+0)*64 + lane], a);
      a = fmaf(wv.y, xl[(c4*4+1)*64 + lane], a);
      a = fmaf(wv.z, xl[(c4*4+2)*64 + lane], a);
      a = fmaf(wv.w, xl[(c4*4+3)*64 + lane], a);
    }
    if (r < 32) QX[(b*32+r)*Nn + n0 + lane] = a;
    else { int o = r-32; XV[(b*128+o)*Nn + n0 + lane] = a + Vb[o]; }
  }
}

// m-split x8: grid 512 = b(8) x nc(8) x mc(8)
__global__ __launch_bounds__(256) void k_sa_b(const float* __restrict__ QX,
                                              float* __restrict__ RMP, float* __restrict__ RSP){
  int blk = blockIdx.x;
  int b = blk >> 6, sub = blk & 63;
  int ncn = sub >> 3, mcn = sub & 7;
  int n = ncn*256 + threadIdx.x;
  float q[32];
  #pragma unroll
  for (int o=0;o<32;++o) q[o] = QX[(b*32+o)*Nn + n];
  __shared__ float qt[32*128];
  float mr = -__builtin_inff(), lr = 0.f;
  int m0 = mcn*256;
  for (int t=0;t<2;++t){
    for (int e=threadIdx.x; e<4096; e+=256){
      int o = e >> 7, mm = e & 127;
      qt[e] = QX[(b*32+o)*Nn + m0 + t*128 + mm];
    }
    __syncthreads();
    for (int mm=0;mm<128;mm+=2){
      float e0=0.f, e1=0.f;
      #pragma unroll
      for (int o=0;o<32;++o){ float qo=q[o]; e0=fmaf(qo, qt[o*128+mm], e0); e1=fmaf(qo, qt[o*128+mm+1], e1); }
      if (e0 > mr){ lr = lr*expf(mr-e0) + 1.f; mr = e0; } else lr += expf(e0-mr);
      if (e1 > mr){ lr = lr*expf(mr-e1) + 1.f; mr = e1; } else lr += expf(e1-mr);
    }
    __syncthreads();
  }
  RMP[(b*Nn+n)*8 + mcn] = mr;
  RSP[(b*Nn+n)*8 + mcn] = lr;
}

__global__ __launch_bounds__(256) void k_sa_b2(const float* __restrict__ RMP, const float* __restrict__ RSP,
                                               float* __restrict__ RMX, float* __restrict__ RSM){
  int e = blockIdx.x*256 + threadIdx.x;
  float M = -__builtin_inff();
  #pragma unroll
  for (int i=0;i<8;++i) M = fmaxf(M, RMP[e*8+i]);
  float l = 0.f;
  #pragma unroll
  for (int i=0;i<8;++i) l += RSP[e*8+i]*expf(RMP[e*8+i]-M);
  RMX[e] = M; RSM[e] = l;
}

// LDS map (floats): QM[32o][32m]=1024 @0, QN[32o][32n]=1024 @1024,
// XVt[32n][132]=4224 @2048, SL[32n][32m]=1024 @6272, MX@7296, RL@7328.
#define SM_QM 0
#define SM_QN 1024
#define SM_XV 2048
#define SM_SL 6272
#define SM_MX 7296
#define SM_RL 7328

// main: grid 1024 = b(8) x mt(64) x part(2); n-range split in 2; writes PV and
// column-sum partials to PP/CSP.
__global__ __launch_bounds__(256) void k_sa_cm(const float* __restrict__ QX, const float* __restrict__ XV,
                                               const float* __restrict__ RMAX, const float* __restrict__ RSUM,
                                               float* __restrict__ PP, float* __restrict__ CSP){
  int blk = blockIdx.x;
  int part = blk & 1, mt = (blk >> 1) & 63, b = blk >> 7;
  int m0 = mt << 5;
  int tid = threadIdx.x;
  int nnp = tid >> 4, mmp = tid & 15;      // 2x2 S-microtile owner
  int tc = tid >> 3, tm8 = tid & 7;        // PV owner: c=tc*4+ci, m=tm8*4+mi
  __shared__ __align__(16) float sm[7360];
  for (int e=tid; e<1024; e+=256){
    int o = e >> 5, mm = e & 31;
    sm[SM_QM + e] = QX[(b*32+o)*Nn + m0 + mm];
  }
  float acc[4][4];
  #pragma unroll
  for (int ci=0;ci<4;++ci){
    #pragma unroll
    for (int mi=0;mi<4;++mi) acc[ci][mi] = 0.f;
  }
  float csr = 0.f;
  int it0 = part*32;
  for (int it=it0; it<it0+32; ++it){
    int nb = it*32;
    __syncthreads();
    for (int e=tid; e<1024; e+=256){ int o=e>>5, nn=e&31; sm[SM_QN+e] = QX[(b*32+o)*Nn + nb + nn]; }
    for (int e=tid; e<4096; e+=256){ int c=e>>5, nn=e&31; sm[SM_XV + nn*132 + c] = XV[(b*128+c)*Nn + nb + nn]; }
    if (tid < 32){ sm[SM_MX+tid] = RMAX[b*Nn + nb + tid]; sm[SM_RL+tid] = 1.0f / RSUM[b*Nn + nb + tid]; }
    __syncthreads();
    float e00=0.f, e01=0.f, e10=0.f, e11=0.f;
    #pragma unroll
    for (int o=0;o<32;++o){
      float2 qn = *(const float2*)&sm[SM_QN + o*32 + nnp*2];
      float2 qm = *(const float2*)&sm[SM_QM + o*32 + mmp*2];
      e00 = fmaf(qn.x, qm.x, e00);
      e01 = fmaf(qn.x, qm.y, e01);
      e10 = fmaf(qn.y, qm.x, e10);
      e11 = fmaf(qn.y, qm.y, e11);
    }
    float mx0 = sm[SM_MX + nnp*2],   rl0 = sm[SM_RL + nnp*2];
    float mx1 = sm[SM_MX + nnp*2+1], rl1 = sm[SM_RL + nnp*2+1];
    float2 s0; s0.x = expf(e00-mx0)*rl0; s0.y = expf(e01-mx0)*rl0;
    float2 s1; s1.x = expf(e10-mx1)*rl1; s1.y = expf(e11-mx1)*rl1;
    *(float2*)&sm[SM_SL + (nnp*2  )*32 + mmp*2] = s0;
    *(float2*)&sm[SM_SL + (nnp*2+1)*32 + mmp*2] = s1;
    __syncthreads();
    if (tid < 32){
      #pragma unroll
      for (int nn=0;nn<32;++nn) csr += sm[SM_SL + nn*32 + tid];
    }
    #pragma unroll 8
    for (int nn=0;nn<32;++nn){
      float4 xv4 = *(const float4*)&sm[SM_XV + nn*132 + tc*4];
      float4 s4  = *(const float4*)&sm[SM_SL + nn*32  + tm8*4];
      acc[0][0] = fmaf(xv4.x, s4.x, acc[0][0]);
      acc[0][1] = fmaf(xv4.x, s4.y, acc[0][1]);
      acc[0][2] = fmaf(xv4.x, s4.z, acc[0][2]);
      acc[0][3] = fmaf(xv4.x, s4.w, acc[0][3]);
      acc[1][0] = fmaf(xv4.y, s4.x, acc[1][0]);
      acc[1][1] = fmaf(xv4.y, s4.y, acc[1][1]);
      acc[1][2] = fmaf(xv4.y, s4.z, acc[1][2]);
      acc[1][3] = fmaf(xv4.y, s4.w, acc[1][3]);
      acc[2][0] = fmaf(xv4.z, s4.x, acc[2][0]);
      acc[2][1] = fmaf(xv4.z, s4.y, acc[2][1]);
      acc[2][2] = fmaf(xv4.z, s4.z, acc[2][2]);
      acc[2][3] = fmaf(xv4.z, s4.w, acc[2][3]);
      acc[3][0] = fmaf(xv4.w, s4.x, acc[3][0]);
      acc[3][1] = fmaf(xv4.w, s4.y, acc[3][1]);
      acc[3][2] = fmaf(xv4.w, s4.z, acc[3][2]);
      acc[3][3] = fmaf(xv4.w, s4.w, acc[3][3]);
    }
  }
  int slot = (b*64 + mt)*2 + part;
  #pragma unroll
  for (int ci=0;ci<4;++ci){
    int c = tc*4 + ci;
    *(float4*)&PP[slot*4096 + c*32 + tm8*4] =
      make_float4(acc[ci][0], acc[ci][1], acc[ci][2], acc[ci][3]);
  }
  if (tid < 32) CSP[slot*32 + tid] = csr;
}

// combine + transform epilogue: grid 512 = b(8) x mt(64). In-place on h.
__global__ __launch_bounds__(256) void k_sa_cc(const float* IN,
                                               const float* __restrict__ PP, const float* __restrict__ CSP,
                                               const float* __restrict__ Tw, const float* __restrict__ Tb,
                                               const float* __restrict__ Gs, const float* __restrict__ Bs,
                                               float* OUT){
  int blk = blockIdx.x;
  int mt = blk & 63, b = blk >> 6;
  int m0 = mt << 5;
  int tid = threadIdx.x;
  int tc = tid >> 3, tm8 = tid & 7;
  __shared__ __align__(16) float sm[4128];   // DL[128][32] @0, CS[32] @4096
  int s0 = (b*64 + mt)*2, s1 = s0 + 1;
  if (tid < 32) sm[4096 + tid] = CSP[s0*32 + tid] + CSP[s1*32 + tid];
  __syncthreads();
  #pragma unroll
  for (int ci=0;ci<4;++ci){
    int c = tc*4 + ci;
    float4 p0 = *(const float4*)&PP[s0*4096 + c*32 + tm8*4];
    float4 p1 = *(const float4*)&PP[s1*4096 + c*32 + tm8*4];
    float am[4] = {p0.x+p1.x, p0.y+p1.y, p0.z+p1.z, p0.w+p1.w};
    #pragma unroll
    for (int mi=0;mi<4;++mi){
      int ml = tm8*4 + mi;
      float cs = sm[4096 + ml];
      float xr = am[mi] / (1e-9f + cs);
      sm[c*32 + ml] = IN[b*HS + c*Nn + m0 + ml] - xr;
    }
  }
  __syncthreads();
  int hw = tid >> 5, m = tid & 31;
  float sroot = sqrtf(1.0f + 1e-5f);
  for (int oo=0; oo<16; ++oo){
    int o = oo*8 + hw;
    const float4* twp = (const float4*)(Tw + o*128);
    float a = 0.f;
    #pragma unroll
    for (int c4=0;c4<32;++c4){
      float4 wv = twp[c4];
      a = fmaf(wv.x, sm[(c4*4+0)*32 + m], a);
      a = fmaf(wv.y, sm[(c4*4+1)*32 + m], a);
      a = fmaf(wv.z, sm[(c4*4+2)*32 + m], a);
      a = fmaf(wv.w, sm[(c4*4+3)*32 + m], a);
    }
    a += Tb[o];
    float y = a * (Gs[o] / sroot) + Bs[o];
    y = fmaxf(y, 0.f);
    OUT[b*HS + o*Nn + m0 + m] = IN[b*HS + o*Nn + m0 + m] + y;
  }
}

// ---------------- progressive fuse: ACC += FW[:, l*128:(l+1)*128] * h_l ----------------
// grid 512 = b(8) x nt(32) x half(2); wave w covers o = hf*128 + w*32 + [0,32).
// fin: apply final BN + leaky-ReLU on the last layer's write (replaces k_fin).
__global__ __launch_bounds__(256) void k_fuse_part(const float* __restrict__ Hc, const float* __restrict__ FWT,
                                                   float* __restrict__ ACC, int l, int init, int fin,
                                                   const float* __restrict__ FGF, const float* __restrict__ FBF){
  int blk = blockIdx.x;
  int hf = blk & 1; int nt = (blk >> 1) & 31; int b = blk >> 6;
  int n0 = nt << 6;
  int w = threadIdx.x >> 6, lane = threadIdx.x & 63;
  __shared__ float xt[128*64];
  for (int e=threadIdx.x; e<8192; e+=256){
    int c = e >> 6, j = e & 63;
    xt[e] = Hc[(b*128 + c)*Nn + n0 + j];
  }
  __syncthreads();
  float4 a[8];
  #pragma unroll
  for (int j=0;j<8;++j) a[j] = make_float4(0.f,0.f,0.f,0.f);
  int ob = hf*128 + w*32;
  for (int c=0;c<128;++c){
    float xv = xt[c*64 + lane];
    const float4* wr = (const float4*)(FWT + (l*128+c)*256 + ob);
    #pragma unroll
    for (int j4=0;j4<8;++j4){
      float4 wv = wr[j4];
      a[j4].x = fmaf(wv.x, xv, a[j4].x);
      a[j4].y = fmaf(wv.y, xv, a[j4].y);
      a[j4].z = fmaf(wv.z, xv, a[j4].z);
      a[j4].w = fmaf(wv.w, xv, a[j4].w);
    }
  }
  float sroot = sqrtf(1.0f + 1e-5f);
  #pragma unroll
  for (int j4=0;j4<8;++j4){
    float vs[4] = {a[j4].x, a[j4].y, a[j4].z, a[j4].w};
    #pragma unroll
    for (int qq=0;qq<4;++qq){
      int o = ob + j4*4 + qq;
      int idx = (b*256 + o)*Nn + n0 + lane;
      float v = init ? vs[qq] : (ACC[idx] + vs[qq]);
      if (fin){
        float y = v * (FGF[o] / sroot) + FBF[o];
        y = (y >= 0.f) ? y : 0.2f*y;
        ACC[idx] = y;
      } else {
        ACC[idx] = v;
      }
    }
  }
}

extern "C" void kernel_launch(void* const* d_in, const int* in_sizes, int n_in,
                              void* d_out, int out_size, void* d_ws, size_t ws_size,
                              hipStream_t stream) {
  const float* X   = (const float*)d_in[0];
  const float* w1  = (const float*)d_in[1];
  const float* g1  = (const float*)d_in[2];
  const float* b1  = (const float*)d_in[3];
  const float* w2  = (const float*)d_in[4];
  const float* g2  = (const float*)d_in[5];
  const float* b2_ = (const float*)d_in[6];
  const float* w3  = (const float*)d_in[7];
  const float* g3  = (const float*)d_in[8];
  const float* b3  = (const float*)d_in[9];
  const float* w4  = (const float*)d_in[10];
  const float* g4  = (const float*)d_in[11];
  const float* b4  = (const float*)d_in[12];
  // d_in[13..15] = w5/g5/b5 : unused by reference
  const float* qk  = (const float*)d_in[16];
  const float* sv  = (const float*)d_in[17];
  const float* svb = (const float*)d_in[18];
  const float* st  = (const float*)d_in[19];
  const float* stb = (const float*)d_in[20];
  const float* sg  = (const float*)d_in[21];
  const float* sb  = (const float*)d_in[22];
  const float* fw  = (const float*)d_in[23];
  const float* fg  = (const float*)d_in[24];
  const float* fb  = (const float*)d_in[25];

  float* ws = (float*)d_ws;
  float* H    = ws + 0;          // 2,097,152
  float* QXb  = ws + 2097152;    //   524,288
  float* XVb  = ws + 2621440;    // 2,097,152 (ends 4,718,592)
  float* RMP  = ws + 4718592;    //   131,072
  float* RSP  = ws + 4849664;    //   131,072
  float* RMX  = ws + 4980736;    //    16,384
  float* RSM  = ws + 4997120;    //    16,384 (ends 5,013,504)
  // phase-1 overlay on [2,097,152 .. 4,915,200) — dead before SA phase:
  float* XX   = ws + 2146304;
  int*   IDX  = (int*)(ws + 2162688);
  float* X1T  = ws + 2818048;
  float* X2T  = ws + 3866624;    // ends 4,915,200
  float* C0   = ws + 5013504;
  float* W1T = C0 + 0;
  float* W2T = C0 + 384;
  float* W3T = C0 + 4480;
  float* W4T = C0 + 12672;
  float* FWT = C0 + 16768;       // C0 ends 5,161,344
  float* PP  = ws + 5161344;     // 4,194,304 (PV partials: 1024 slots x 4096)
  float* CSP = ws + 9355648;     //    32,768 — total 9,388,416 floats = 35.8 MiB
  float* ACC = (float*)d_out;

  k_xx1<<<64,256,0,stream>>>(X, XX);
  k_prep_wt<<<578,256,0,stream>>>(w1,w2,w3,w4,fw, W1T,W2T,W3T,W4T,FWT);
  k_knn1<<<4096,256,0,stream>>>(X, XX, IDX);
  k_ec1<<<16384,64,0,stream>>>(X, IDX, W1T, W2T, g1,b1,g2,b2_, X1T);
  k_xx2<<<64,256,0,stream>>>(X1T, XX);
  k_tr<<<256,256,0,stream>>>(X1T, H);                  // X1 -> channel-major (H ch 0..63), BEFORE knn2
  k_knn2<<<4096,256,0,stream>>>(H, XX, IDX);           // coalesced channel-major reads
  k_ec2<<<16384,64,0,stream>>>(X1T, IDX, W3T, W4T, g3,b3,g4,b4, X2T);
  k_tr<<<256,256,0,stream>>>(X2T, H + 64*Nn);

  for (int l=0;l<4;++l){
    k_sa_a<<<512,256,0,stream>>>(H, qk + l*4096, sv + l*16384, svb + l*128, QXb, XVb);
    k_sa_b<<<512,256,0,stream>>>(QXb, RMP, RSP);
    k_sa_b2<<<64,256,0,stream>>>(RMP, RSP, RMX, RSM);
    k_sa_cm<<<1024,256,0,stream>>>(QXb, XVb, RMX, RSM, PP, CSP);
    k_sa_cc<<<512,256,0,stream>>>(H, PP, CSP,
                                  st + l*16384, stb + l*128, sg + l*128, sb + l*128, H);
    k_fuse_part<<<512,256,0,stream>>>(H, FWT, ACC, l, (l==0)?1:0, (l==3)?1:0, fg, fb);
  }
}